// Round 10
// baseline (485.850 us; speedup 1.0000x reference)
//
#include <hip/hip_runtime.h>
#include <cstdint>
#include <cstddef>

#define N_NODE 50000
#define NEDGE  500000
#define NL     100000
#define FDIM   128
#define HIDD   128
#define OUTD   64
#define NBSC   98        // ceil(N_NODE / 512) for rowptr scan
#define NB     49        // buckets = ceil(50000 / 1024), bucket = dst >> 10
#define BCH    8192      // edges per partition block
#define NBP1   62        // ceil(NEDGE / BCH)

typedef unsigned int uint32;
typedef unsigned short ushort16;

__device__ __forceinline__ float leakyf(float x) { return x > 0.f ? x : 0.2f * x; }

// round-to-nearest-even f32 -> bf16 (values are finite/sane here)
__device__ __forceinline__ uint32 bf16r(float x) {
    uint32 u = __float_as_uint(x);
    return (u + 0x7fffu + ((u >> 16) & 1u)) >> 16;
}
__device__ __forceinline__ float bf_lo(uint32 u) { return __uint_as_float(u << 16); }
__device__ __forceinline__ float bf_hi(uint32 u) { return __uint_as_float(u & 0xffff0000u); }

// ---------------- fold Wd @ a_d -> per-relation length-128 vectors ----------------
__global__ void fold_wd(const float* __restrict__ W1d, const float* __restrict__ a1d,
                        const float* __restrict__ W2d, const float* __restrict__ a2d,
                        float* __restrict__ wd1, float* __restrict__ wd2) {
    int r = blockIdx.x;          // 3 relations
    int f = threadIdx.x;         // 128
    const float* w  = W1d + ((size_t)r * FDIM + f) * HIDD;
    const float* a  = a1d + r * HIDD;
    float s = 0.f;
    for (int h = 0; h < HIDD; ++h) s += w[h] * a[h];
    wd1[r * FDIM + f] = s;
    const float* w2 = W2d + ((size_t)r * HIDD + f) * OUTD;
    const float* a2 = a2d + r * OUTD;
    float s2 = 0.f;
    for (int o = 0; o < OUTD; ++o) s2 += w2[o] * a2[o];
    wd2[r * HIDD + f] = s2;
}

// ================= CSR build: two-level bucket partition (write-locality) =================

// --- p1a: per-block bucket histogram. grid (NBP1, 3) x 256 ---
__global__ __launch_bounds__(256) void part_hist(const int* __restrict__ e0,
                                                 const int* __restrict__ e1,
                                                 const int* __restrict__ e2,
                                                 int* __restrict__ bh) {
    int r = blockIdx.y, t = threadIdx.x;
    const int* ei  = (r == 0) ? e0 : (r == 1) ? e1 : e2;
    const int* dst = ei + NEDGE;
    __shared__ int lh[NB];
    if (t < NB) lh[t] = 0;
    __syncthreads();
    int base = blockIdx.x * BCH;
    int lim  = base + BCH; if (lim > NEDGE) lim = NEDGE;
    for (int i = base + t; i < lim; i += 256)
        atomicAdd(&lh[dst[i] >> 10], 1);
    __syncthreads();
    if (t < NB) bh[((size_t)r * NB + t) * NBP1 + blockIdx.x] = lh[t];
}

// --- p1b: per-relation exclusive scan of bh + bucket bases ---
__global__ __launch_bounds__(256) void part_scan(int* __restrict__ bh,
                                                 int* __restrict__ bkbase) {
    int r = blockIdx.x, t = threadIdx.x;
    int* a = bh + (size_t)r * NB * NBP1;
    const int n = NB * NBP1;                 // 3038
    const int per = (n + 255) / 256;         // 12
    int lo = t * per, hi = lo + per; if (hi > n) hi = n;
    int s = 0;
    for (int i = lo; i < hi; ++i) s += a[i];
    __shared__ int sm[256];
    sm[t] = s;
    __syncthreads();
    for (int off = 1; off < 256; off <<= 1) {
        int x = (t >= off) ? sm[t - off] : 0;
        __syncthreads();
        sm[t] += x;
        __syncthreads();
    }
    int run = sm[t] - s;
    for (int i = lo; i < hi; ++i) { int c = a[i]; a[i] = run; run += c; }
    __syncthreads();
    if (t < NB) bkbase[r * (NB + 1) + t] = a[t * NBP1];
    if (t == NB) bkbase[r * (NB + 1) + NB] = NEDGE;
}

// --- p1c: partition scatter into bucketed (src,dst) pairs. grid (NBP1, 3) x 256 ---
__global__ __launch_bounds__(256) void part_scatter(const int* __restrict__ e0,
                                                    const int* __restrict__ e1,
                                                    const int* __restrict__ e2,
                                                    const int* __restrict__ bh,
                                                    int2* __restrict__ bucketed) {
    int r = blockIdx.y, t = threadIdx.x;
    const int* ei  = (r == 0) ? e0 : (r == 1) ? e1 : e2;
    const int* dst = ei + NEDGE;
    __shared__ int cur[NB];
    if (t < NB) cur[t] = bh[((size_t)r * NB + t) * NBP1 + blockIdx.x];
    __syncthreads();
    int2* bk = bucketed + (size_t)r * NEDGE;
    int base = blockIdx.x * BCH;
    int lim  = base + BCH; if (lim > NEDGE) lim = NEDGE;
    for (int i = base + t; i < lim; i += 256) {
        int d = dst[i], s_ = ei[i];
        int pos = atomicAdd(&cur[d >> 10], 1);      // LDS atomic, global position
        bk[pos] = make_int2(s_, d);
    }
}

// --- p2a: per-bucket per-dst counts (exclusive ownership). grid (NB,3) ---
__global__ __launch_bounds__(256) void bucket_count(const int2* __restrict__ bucketed,
                                                    const int* __restrict__ bkbase,
                                                    int* __restrict__ counts_all) {
    int r = blockIdx.y, k = blockIdx.x, t = threadIdx.x;
    int s0 = bkbase[r * (NB + 1) + k], s1 = bkbase[r * (NB + 1) + k + 1];
    __shared__ int lh[1024];
#pragma unroll
    for (int i = 0; i < 4; ++i) lh[t + i * 256] = 0;
    __syncthreads();
    const int2* bk = bucketed + (size_t)r * NEDGE;
    for (int i = s0 + t; i < s1; i += 256)
        atomicAdd(&lh[bk[i].y & 1023], 1);
    __syncthreads();
    int gbase = k << 10;
    int* cnt = counts_all + (size_t)r * N_NODE;
#pragma unroll
    for (int i = 0; i < 4; ++i) {
        int idx = t + i * 256;
        if (gbase + idx < N_NODE) cnt[gbase + idx] = lh[idx];
    }
}

// --- rowptr scans (over counts_all) ---
__global__ __launch_bounds__(256) void scan1(const int* __restrict__ counts_all,
                                             int* __restrict__ bsum) {
    int r = blockIdx.y, b = blockIdx.x, t = threadIdx.x;
    int base = b * 512;
    int lim = N_NODE - base; if (lim > 512) lim = 512;
    const int* c = counts_all + (size_t)r * N_NODE + base;
    int v0 = (2 * t     < lim) ? c[2 * t]     : 0;
    int v1 = (2 * t + 1 < lim) ? c[2 * t + 1] : 0;
    __shared__ int sm[256];
    sm[t] = v0 + v1;
    __syncthreads();
    for (int off = 128; off; off >>= 1) {
        if (t < off) sm[t] += sm[t + off];
        __syncthreads();
    }
    if (t == 0) bsum[r * NBSC + b] = sm[0];
}

__global__ __launch_bounds__(256) void scan3(const int* __restrict__ counts_all,
                                             int* __restrict__ rowptr_all,
                                             const int* __restrict__ bsum) {
    int r = blockIdx.y, b = blockIdx.x, t = threadIdx.x;
    __shared__ int sm[256];
    sm[t] = (t < b) ? bsum[r * NBSC + t] : 0;
    __syncthreads();
    for (int off = 128; off; off >>= 1) {
        if (t < off) sm[t] += sm[t + off];
        __syncthreads();
    }
    int boff = sm[0];
    __syncthreads();

    int base = b * 512;
    int lim = N_NODE - base; if (lim > 512) lim = 512;
    const int* c = counts_all + (size_t)r * N_NODE;
    int* rp = rowptr_all + (size_t)r * (N_NODE + 1);
    int i0 = base + 2 * t, i1 = i0 + 1;
    int v0 = (2 * t     < lim) ? c[i0] : 0;
    int v1 = (2 * t + 1 < lim) ? c[i1] : 0;
    int ps = v0 + v1;
    sm[t] = ps;
    __syncthreads();
    for (int off = 1; off < 256; off <<= 1) {
        int x = (t >= off) ? sm[t - off] : 0;
        __syncthreads();
        sm[t] += x;
        __syncthreads();
    }
    int excl = sm[t] - ps + boff;
    if (2 * t < lim)     rp[i0] = excl;
    if (2 * t + 1 < lim) rp[i1] = excl + v0;
    if (b == 0 && t == 0) rp[N_NODE] = NEDGE;
}

// --- p2b: per-bucket LDS-cursor scatter into contiguous CSR range (src + dst). grid (NB,3) ---
__global__ __launch_bounds__(256) void bucket_scatter(const int2* __restrict__ bucketed,
                                                      const int* __restrict__ bkbase,
                                                      const int* __restrict__ rowptr_all,
                                                      int* __restrict__ srcs_all,
                                                      int* __restrict__ dsts_all) {
    int r = blockIdx.y, k = blockIdx.x, t = threadIdx.x;
    int s0 = bkbase[r * (NB + 1) + k], s1 = bkbase[r * (NB + 1) + k + 1];
    int gbase = k << 10;
    const int* rp = rowptr_all + (size_t)r * (N_NODE + 1);
    __shared__ int cur[1024];
#pragma unroll
    for (int i = 0; i < 4; ++i) {
        int idx = t + i * 256;
        cur[idx] = (gbase + idx < N_NODE) ? rp[gbase + idx] : 0;
    }
    __syncthreads();
    const int2* bk = bucketed + (size_t)r * NEDGE;
    int* out  = srcs_all + (size_t)r * NEDGE;
    int* outd = dsts_all + (size_t)r * NEDGE;
    for (int i = s0 + t; i < s1; i += 256) {
        int2 e = bk[i];
        int pos = atomicAdd(&cur[e.y & 1023], 1);   // LDS atomic
        out[pos]  = e.x;                             // writes confined to bucket's CSR range
        outd[pos] = e.y;
    }
}

// ---------------- edge weights: ex[i] = exp(leaky(al_src[src] + al_dst[dst])) ----------------
// Edge-parallel; computed ONCE per edge (not 64x redundantly in the agg kernels).
__global__ __launch_bounds__(256) void edge_exp(const int* __restrict__ srcs_all,
                                                const int* __restrict__ dsts_all,
                                                const float* __restrict__ alsrc_all,
                                                const float* __restrict__ aldst_all,
                                                float* __restrict__ ex_all) {
    int r = blockIdx.y;
    const int* ss = srcs_all + (size_t)r * NEDGE;
    const int* dd = dsts_all + (size_t)r * NEDGE;
    const float* als = alsrc_all + (size_t)r * N_NODE;
    const float* ald = aldst_all + (size_t)r * N_NODE;
    float* ex = ex_all + (size_t)r * NEDGE;
    int i4 = (blockIdx.x * 256 + threadIdx.x) * 4;
    if (i4 + 4 <= NEDGE) {                        // NEDGE % 4 == 0 -> no partial vectors
        int4 s = *reinterpret_cast<const int4*>(ss + i4);
        int4 d = *reinterpret_cast<const int4*>(dd + i4);
        float4 o;
        o.x = __expf(leakyf(als[s.x] + ald[d.x]));
        o.y = __expf(leakyf(als[s.y] + ald[d.y]));
        o.z = __expf(leakyf(als[s.z] + ald[d.z]));
        o.w = __expf(leakyf(als[s.w] + ald[d.w]));
        *reinterpret_cast<float4*>(ex + i4) = o;
    }
}

// ---------------- GEMM (fp32 math) + bf16 C-store + fused al_src dot ----------------
template <int BM, int BN, bool RELU>
__global__ __launch_bounds__(128) void gemm3(const float* __restrict__ A0,
                                             const float* __restrict__ A1,
                                             const float* __restrict__ A2,
                                             const float* __restrict__ Bbase,
                                             const float* __restrict__ avec_base,
                                             ushort16* __restrict__ Cbase,
                                             float* __restrict__ al_base, int M) {
    constexpr int K  = 128;
    constexpr int KS = 32;
    constexpr int TX = BN / 8;
    constexpr int TY = BM / 8;
    static_assert(TX * TY == 128, "thread grid");
    constexpr int SA = BM + 4;
    constexpr int SB = BN + 4;
    __shared__ float as[KS * SA];
    __shared__ float bs[KS * SB];
    const int r = blockIdx.y;
    const float* A = (r == 0) ? A0 : (r == 1) ? A1 : A2;
    const float* B = Bbase + (size_t)r * K * BN;
    uint32* Cu = reinterpret_cast<uint32*>(Cbase + (size_t)r * M * BN);
    const int t  = threadIdx.x;
    const int tx = t % TX;
    const int ty = t / TX;
    const int m0 = blockIdx.x * BM;
    const int r0 = ty * 8;
    const int c0 = tx * 8;
    float acc[8][8] = {};
    const float4* A4 = reinterpret_cast<const float4*>(A);
    const float4* B4 = reinterpret_cast<const float4*>(B);

    for (int ks = 0; ks < K; ks += KS) {
        __syncthreads();
#pragma unroll
        for (int i = 0; i < BM * 8 / 128; ++i) {
            int idx = t + i * 128;
            int row = idx >> 3;
            int kq  = idx & 7;
            float4 v = make_float4(0.f, 0.f, 0.f, 0.f);
            if (m0 + row < M) {
                v = A4[(size_t)(m0 + row) * (K / 4) + (ks >> 2) + kq];
                if (RELU) {
                    v.x = fmaxf(v.x, 0.f); v.y = fmaxf(v.y, 0.f);
                    v.z = fmaxf(v.z, 0.f); v.w = fmaxf(v.w, 0.f);
                }
            }
            as[(kq * 4 + 0) * SA + row] = v.x;
            as[(kq * 4 + 1) * SA + row] = v.y;
            as[(kq * 4 + 2) * SA + row] = v.z;
            as[(kq * 4 + 3) * SA + row] = v.w;
        }
#pragma unroll
        for (int i = 0; i < KS * BN / 4 / 128; ++i) {
            int idx = t + i * 128;
            int nq  = idx % (BN / 4);
            int kr  = idx / (BN / 4);
            float4 v = B4[(size_t)(ks + kr) * (BN / 4) + nq];
            *reinterpret_cast<float4*>(&bs[kr * SB + nq * 4]) = v;
        }
        __syncthreads();
#pragma unroll 2
        for (int k = 0; k < KS; ++k) {
            float4 a0 = *reinterpret_cast<const float4*>(&as[k * SA + r0]);
            float4 a1 = *reinterpret_cast<const float4*>(&as[k * SA + r0 + 4]);
            float4 b0 = *reinterpret_cast<const float4*>(&bs[k * SB + c0]);
            float4 b1 = *reinterpret_cast<const float4*>(&bs[k * SB + c0 + 4]);
            float av[8] = {a0.x, a0.y, a0.z, a0.w, a1.x, a1.y, a1.z, a1.w};
            float bv[8] = {b0.x, b0.y, b0.z, b0.w, b1.x, b1.y, b1.z, b1.w};
#pragma unroll
            for (int i = 0; i < 8; ++i)
#pragma unroll
                for (int j = 0; j < 8; ++j)
                    acc[i][j] = fmaf(av[i], bv[j], acc[i][j]);
        }
    }
    // bf16 C-store
#pragma unroll
    for (int i = 0; i < 8; ++i) {
        int rr = m0 + r0 + i;
        if (rr < M) {
            uint4 p;
            p.x = bf16r(acc[i][0]) | (bf16r(acc[i][1]) << 16);
            p.y = bf16r(acc[i][2]) | (bf16r(acc[i][3]) << 16);
            p.z = bf16r(acc[i][4]) | (bf16r(acc[i][5]) << 16);
            p.w = bf16r(acc[i][6]) | (bf16r(acc[i][7]) << 16);
            *reinterpret_cast<uint4*>(&Cu[(size_t)rr * (BN / 2) + (c0 >> 1)]) = p;
        }
    }
    // fused al_src = C-row . avec (from fp32 acc, BEFORE bf16 rounding)
    const float* av = avec_base + r * BN;
    float asv[8];
#pragma unroll
    for (int j = 0; j < 8; ++j) asv[j] = av[c0 + j];
    float* al = al_base + (size_t)r * M;
#pragma unroll
    for (int i = 0; i < 8; ++i) {
        float p = 0.f;
#pragma unroll
        for (int j = 0; j < 8; ++j) p += acc[i][j] * asv[j];
#pragma unroll
        for (int off = TX / 2; off; off >>= 1) p += __shfl_xor(p, off);
        int rr = m0 + r0 + i;
        if (tx == 0 && rr < M) al[rr] = p;
    }
}

// ---------------- row dot (al_dst), 3 relations batched, optional ReLU ----------------
__global__ void row_dot3(const float* __restrict__ X0, const float* __restrict__ X1,
                         const float* __restrict__ X2, const float* __restrict__ vbase,
                         int C, float* __restrict__ out_all, int n, int relu) {
    int r    = blockIdx.y;
    int gw   = (blockIdx.x * 256 + threadIdx.x) >> 6;
    int lane = threadIdx.x & 63;
    if (gw >= n) return;
    const float* X = (r == 0) ? X0 : (r == 1) ? X1 : X2;
    const float* v = vbase + r * C;
    const float* row = X + (size_t)gw * C;
    float s = 0.f;
    for (int c = lane; c < C; c += 64) {
        float x = row[c];
        if (relu) x = fmaxf(x, 0.f);
        s += x * v[c];
    }
#pragma unroll
    for (int off = 32; off; off >>= 1) s += __shfl_xor(s, off);
    if (lane == 0) out_all[(size_t)r * n + gw] = s;
}

// ---------------- segment aggregate helpers: precomputed ex, bf16 gathers, 8-deep ILP ----------------
__device__ __forceinline__ float2 seg128(const int* __restrict__ rp, const int* __restrict__ ss,
                                         const float* __restrict__ ex,
                                         const uint32* __restrict__ hv,   // 2 bf16/uint, row=64 uints
                                         int d, int lane) {
    int s = rp[d], e = rp[d + 1];
    float den = 0.f, ax = 0.f, ay = 0.f;
    int i = s;
    for (; i + 8 <= e; i += 8) {
        int   idx[8]; float w[8]; uint32 u[8];
#pragma unroll
        for (int j = 0; j < 8; ++j) idx[j] = ss[i + j];
#pragma unroll
        for (int j = 0; j < 8; ++j) w[j] = ex[i + j];
#pragma unroll
        for (int j = 0; j < 8; ++j) u[j] = hv[(uint32)idx[j] * 64u + lane];
#pragma unroll
        for (int j = 0; j < 8; ++j) {
            den += w[j];
            ax = fmaf(w[j], bf_lo(u[j]), ax);
            ay = fmaf(w[j], bf_hi(u[j]), ay);
        }
    }
    for (; i < e; ++i) {
        float w = ex[i];
        uint32 u = hv[(uint32)ss[i] * 64u + lane];
        den += w;
        ax = fmaf(w, bf_lo(u), ax); ay = fmaf(w, bf_hi(u), ay);
    }
    float rden = 1.0f / (den + 1e-16f);
    return make_float2(ax * rden, ay * rden);
}

__device__ __forceinline__ float seg64(const int* __restrict__ rp, const int* __restrict__ ss,
                                       const float* __restrict__ ex,
                                       const ushort16* __restrict__ hv,  // 1 bf16/lane, row=64
                                       int d, int lane) {
    int s = rp[d], e = rp[d + 1];
    float den = 0.f, acc = 0.f;
    int i = s;
    for (; i + 8 <= e; i += 8) {
        int idx[8]; float w[8]; uint32 u[8];
#pragma unroll
        for (int j = 0; j < 8; ++j) idx[j] = ss[i + j];
#pragma unroll
        for (int j = 0; j < 8; ++j) w[j] = ex[i + j];
#pragma unroll
        for (int j = 0; j < 8; ++j) u[j] = hv[(uint32)idx[j] * 64u + lane];
#pragma unroll
        for (int j = 0; j < 8; ++j) {
            den += w[j];
            acc = fmaf(w[j], __uint_as_float(u[j] << 16), acc);
        }
    }
    for (; i < e; ++i) {
        float w = ex[i];
        uint32 u = hv[(uint32)ss[i] * 64u + lane];
        den += w;
        acc = fmaf(w, __uint_as_float(u << 16), acc);
    }
    return acc / (den + 1e-16f);
}

// ---------------- layer-1 agg: grid (12500, 2), 256 thr = 4 indep waves, no barriers ----------------
__global__ __launch_bounds__(256) void agg1_sp(const int* __restrict__ rowptr_all,
                                               const int* __restrict__ srcs_all,
                                               const float* __restrict__ ex_all,
                                               const ushort16* __restrict__ hs_all,
                                               const float* __restrict__ b1,
                                               float* __restrict__ h_item,
                                               float* __restrict__ h_user) {
    const int lane = threadIdx.x & 63;
    const int d = blockIdx.x * 4 + (threadIdx.x >> 6);
    if (d >= N_NODE) return;
    const uint32* hv = reinterpret_cast<const uint32*>(hs_all);   // per-rel stride N*64 uints
    if (blockIdx.y == 0) {           // item dst: relation 0
        float2 w = seg128(rowptr_all, srcs_all, ex_all, hv, d, lane);
        float2 b = ((const float2*)b1)[lane];
        ((float2*)h_item)[(size_t)d * 64 + lane] = make_float2(w.x + b.x, w.y + b.y);
    } else {                         // user dst: relations 1 + 2 in one wave
        float2 w1 = seg128(rowptr_all + (N_NODE + 1), srcs_all + NEDGE,
                           ex_all + NEDGE, hv + (size_t)N_NODE * 64, d, lane);
        float2 w2 = seg128(rowptr_all + 2 * (N_NODE + 1), srcs_all + (size_t)2 * NEDGE,
                           ex_all + (size_t)2 * NEDGE, hv + (size_t)2 * N_NODE * 64, d, lane);
        float2 bA = ((const float2*)(b1 + HIDD))[lane];
        float2 bB = ((const float2*)(b1 + 2 * HIDD))[lane];
        ((float2*)h_user)[(size_t)d * 64 + lane] =
            make_float2(w1.x + w2.x + bA.x + bB.x, w1.y + w2.y + bA.y + bB.y);
    }
}

// ---------------- layer-2 agg (C=64) ----------------
__global__ __launch_bounds__(256) void agg2_sp(const int* __restrict__ rowptr_all,
                                               const int* __restrict__ srcs_all,
                                               const float* __restrict__ ex_all,
                                               const ushort16* __restrict__ hs_all,
                                               const float* __restrict__ b2,
                                               float* __restrict__ o_item,
                                               float* __restrict__ o_user) {
    const int lane = threadIdx.x & 63;
    const int d = blockIdx.x * 4 + (threadIdx.x >> 6);
    if (d >= N_NODE) return;
    if (blockIdx.y == 0) {
        float w = seg64(rowptr_all, srcs_all, ex_all, hs_all, d, lane);
        o_item[(size_t)d * OUTD + lane] = w + b2[lane];
    } else {
        float w1 = seg64(rowptr_all + (N_NODE + 1), srcs_all + NEDGE,
                         ex_all + NEDGE, hs_all + (size_t)N_NODE * OUTD, d, lane);
        float w2 = seg64(rowptr_all + 2 * (N_NODE + 1), srcs_all + (size_t)2 * NEDGE,
                         ex_all + (size_t)2 * NEDGE, hs_all + (size_t)2 * N_NODE * OUTD, d, lane);
        o_user[(size_t)d * OUTD + lane] = w1 + w2 + b2[OUTD + lane] + b2[2 * OUTD + lane];
    }
}

// ---------------- bilinear edge scoring ----------------
__global__ void score_k(const int* __restrict__ e0, const int* __restrict__ e1,
                        const int* __restrict__ e2,
                        const float* __restrict__ o_user, const float* __restrict__ o_item,
                        const float* __restrict__ relw, float* __restrict__ out, int L) {
    int g    = blockIdx.x * 4 + (threadIdx.x >> 6);
    int lane = threadIdx.x & 63;
    int r = g / L, l = g - r * L;
    if (r >= 3) return;
    const int* ei = (r == 0) ? e0 : (r == 1) ? e1 : e2;
    int ai = ei[l];
    int bi = ei[L + l];
    const float* A = (r == 1) ? o_item : o_user;
    const float* B = (r == 0) ? o_item : o_user;
    float v = A[(size_t)ai * OUTD + lane] * relw[r * OUTD + lane] * B[(size_t)bi * OUTD + lane];
#pragma unroll
    for (int off = 32; off; off >>= 1) v += __shfl_xor(v, off);
    if (lane == 0) out[r * L + l] = v;
}

extern "C" void kernel_launch(void* const* d_in, const int* in_sizes, int n_in,
                              void* d_out, int out_size, void* d_ws, size_t ws_size,
                              hipStream_t stream) {
    const float* x_user = (const float*)d_in[0];
    const float* x_item = (const float*)d_in[1];
    const float* W1s = (const float*)d_in[2];
    const float* W1d = (const float*)d_in[3];
    const float* a1s = (const float*)d_in[4];
    const float* a1d = (const float*)d_in[5];
    const float* b1  = (const float*)d_in[6];
    const float* W2s = (const float*)d_in[7];
    const float* W2d = (const float*)d_in[8];
    const float* a2s = (const float*)d_in[9];
    const float* a2d = (const float*)d_in[10];
    const float* b2  = (const float*)d_in[11];
    const float* relw= (const float*)d_in[12];
    const int* ei0 = (const int*)d_in[13];
    const int* ei1 = (const int*)d_in[14];
    const int* ei2 = (const int*)d_in[15];
    const int* el0 = (const int*)d_in[16];
    const int* el1 = (const int*)d_in[17];
    const int* el2 = (const int*)d_in[18];
    float* out = (float*)d_out;
    (void)ws_size; (void)n_in; (void)in_sizes; (void)out_size;

    char* ws = (char*)d_ws;
    size_t off = 0;
    auto alloc = [&](size_t bytes) -> void* {
        void* p = ws + off;
        off = (off + bytes + 255) & ~(size_t)255;
        return p;
    };
    int*     rowptr_all = (int*)alloc((size_t)3 * (N_NODE + 1) * 4);
    int*     counts_all = (int*)alloc((size_t)3 * N_NODE * 4);
    int*     srcs_all   = (int*)alloc((size_t)3 * NEDGE * 4);
    int*     dsts_all   = (int*)alloc((size_t)3 * NEDGE * 4);
    float*   ex_all     = (float*)alloc((size_t)3 * NEDGE * 4);
    int*     bsum       = (int*)alloc((size_t)3 * NBSC * 4);
    int*     bh         = (int*)alloc((size_t)3 * NB * NBP1 * 4);
    int*     bkbase     = (int*)alloc((size_t)3 * (NB + 1) * 4);
    int2*    bucketed   = (int2*)alloc((size_t)3 * NEDGE * 8);
    ushort16* hs_bf     = (ushort16*)alloc((size_t)3 * N_NODE * HIDD * 2);  // bf16; L2 reuses first 3*N*64
    float*   h_item1    = (float*)alloc((size_t)2 * N_NODE * HIDD * 4);     // fp32
    float*   h_user1    = h_item1 + (size_t)N_NODE * HIDD;
    float*   o_item     = (float*)alloc((size_t)N_NODE * OUTD * 4);
    float*   o_user     = (float*)alloc((size_t)N_NODE * OUTD * 4);
    float*   alsrc_all  = (float*)alloc((size_t)3 * N_NODE * 4);
    float*   aldst_all  = (float*)alloc((size_t)3 * N_NODE * 4);
    float*   wd1        = (float*)alloc(3 * FDIM * 4);
    float*   wd2        = (float*)alloc(3 * HIDD * 4);

    fold_wd<<<3, 128, 0, stream>>>(W1d, a1d, W2d, a2d, wd1, wd2);

    // ---- CSR build: two-level bucket partition ----
    part_hist<<<dim3(NBP1, 3), 256, 0, stream>>>(ei0, ei1, ei2, bh);
    part_scan<<<3, 256, 0, stream>>>(bh, bkbase);
    part_scatter<<<dim3(NBP1, 3), 256, 0, stream>>>(ei0, ei1, ei2, bh, bucketed);
    bucket_count<<<dim3(NB, 3), 256, 0, stream>>>(bucketed, bkbase, counts_all);
    scan1<<<dim3(NBSC, 3), 256, 0, stream>>>(counts_all, bsum);
    scan3<<<dim3(NBSC, 3), 256, 0, stream>>>(counts_all, rowptr_all, bsum);
    bucket_scatter<<<dim3(NB, 3), 256, 0, stream>>>(bucketed, bkbase, rowptr_all,
                                                    srcs_all, dsts_all);

    const int rd = (N_NODE * 64 + 255) / 256;
    const int ag = (N_NODE + 3) / 4;
    const int eg4 = (NEDGE / 4 + 255) / 256;

    // ---- layer 1 ----
    row_dot3<<<dim3(rd, 3), 256, 0, stream>>>(x_item, x_user, x_user, wd1, FDIM,
                                              aldst_all, N_NODE, 0);
    gemm3<64, 128, false><<<dim3((N_NODE + 63) / 64, 3), 128, 0, stream>>>(
        x_user, x_item, x_user, W1s, a1s, hs_bf, alsrc_all, N_NODE);
    edge_exp<<<dim3(eg4, 3), 256, 0, stream>>>(srcs_all, dsts_all, alsrc_all, aldst_all, ex_all);
    agg1_sp<<<dim3(ag, 2), 256, 0, stream>>>(rowptr_all, srcs_all, ex_all,
                                             hs_bf, b1, h_item1, h_user1);

    // ---- layer 2 (ReLU folded into A-staging / row_dot reads; hs_bf overwrite is safe:
    //      layer-1 hs fully consumed by agg1_sp, stream-ordered) ----
    gemm3<128, 64, true><<<dim3((N_NODE + 127) / 128, 3), 128, 0, stream>>>(
        h_user1, h_item1, h_user1, W2s, a2s, hs_bf, alsrc_all, N_NODE);
    row_dot3<<<dim3(rd, 3), 256, 0, stream>>>(h_item1, h_user1, h_user1, wd2, HIDD,
                                              aldst_all, N_NODE, 1);
    edge_exp<<<dim3(eg4, 3), 256, 0, stream>>>(srcs_all, dsts_all, alsrc_all, aldst_all, ex_all);
    agg2_sp<<<dim3(ag, 2), 256, 0, stream>>>(rowptr_all, srcs_all, ex_all,
                                             hs_bf, b2, o_item, o_user);

    // ---- scoring ----
    score_k<<<(3 * NL + 3) / 4, 256, 0, stream>>>(el0, el1, el2, o_user, o_item, relw, out, NL);
}

// Round 11
// 431.397 us; speedup vs baseline: 1.1262x; 1.1262x over previous
//
#include <hip/hip_runtime.h>
#include <cstdint>
#include <cstddef>

#define N_NODE 50000
#define NEDGE  500000
#define NL     100000
#define FDIM   128
#define HIDD   128
#define OUTD   64
#define NBSC   98        // ceil(N_NODE / 512) for rowptr scan
#define NB     49        // buckets = ceil(50000 / 1024), bucket = dst >> 10
#define BCH    8192      // edges per partition block
#define NBP1   62        // ceil(NEDGE / BCH)

typedef unsigned int uint32;
typedef unsigned short ushort16;

__device__ __forceinline__ float leakyf(float x) { return x > 0.f ? x : 0.2f * x; }

// round-to-nearest-even f32 -> bf16 (values are finite/sane here)
__device__ __forceinline__ uint32 bf16r(float x) {
    uint32 u = __float_as_uint(x);
    return (u + 0x7fffu + ((u >> 16) & 1u)) >> 16;
}
__device__ __forceinline__ float bf_lo(uint32 u) { return __uint_as_float(u << 16); }
__device__ __forceinline__ float bf_hi(uint32 u) { return __uint_as_float(u & 0xffff0000u); }

// ---------------- fold Wd @ a_d -> per-relation length-128 vectors ----------------
__global__ void fold_wd(const float* __restrict__ W1d, const float* __restrict__ a1d,
                        const float* __restrict__ W2d, const float* __restrict__ a2d,
                        float* __restrict__ wd1, float* __restrict__ wd2) {
    int r = blockIdx.x;          // 3 relations
    int f = threadIdx.x;         // 128
    const float* w  = W1d + ((size_t)r * FDIM + f) * HIDD;
    const float* a  = a1d + r * HIDD;
    float s = 0.f;
    for (int h = 0; h < HIDD; ++h) s += w[h] * a[h];
    wd1[r * FDIM + f] = s;
    const float* w2 = W2d + ((size_t)r * HIDD + f) * OUTD;
    const float* a2 = a2d + r * OUTD;
    float s2 = 0.f;
    for (int o = 0; o < OUTD; ++o) s2 += w2[o] * a2[o];
    wd2[r * HIDD + f] = s2;
}

// ================= CSR build: two-level bucket partition (write-locality) =================

// --- p1a: per-block bucket histogram. grid (NBP1, 3) x 256 ---
__global__ __launch_bounds__(256) void part_hist(const int* __restrict__ e0,
                                                 const int* __restrict__ e1,
                                                 const int* __restrict__ e2,
                                                 int* __restrict__ bh) {
    int r = blockIdx.y, t = threadIdx.x;
    const int* ei  = (r == 0) ? e0 : (r == 1) ? e1 : e2;
    const int* dst = ei + NEDGE;
    __shared__ int lh[NB];
    if (t < NB) lh[t] = 0;
    __syncthreads();
    int base = blockIdx.x * BCH;
    int lim  = base + BCH; if (lim > NEDGE) lim = NEDGE;
    for (int i = base + t; i < lim; i += 256)
        atomicAdd(&lh[dst[i] >> 10], 1);
    __syncthreads();
    if (t < NB) bh[((size_t)r * NB + t) * NBP1 + blockIdx.x] = lh[t];
}

// --- p1b: per-relation exclusive scan of bh + bucket bases ---
__global__ __launch_bounds__(256) void part_scan(int* __restrict__ bh,
                                                 int* __restrict__ bkbase) {
    int r = blockIdx.x, t = threadIdx.x;
    int* a = bh + (size_t)r * NB * NBP1;
    const int n = NB * NBP1;                 // 3038
    const int per = (n + 255) / 256;         // 12
    int lo = t * per, hi = lo + per; if (hi > n) hi = n;
    int s = 0;
    for (int i = lo; i < hi; ++i) s += a[i];
    __shared__ int sm[256];
    sm[t] = s;
    __syncthreads();
    for (int off = 1; off < 256; off <<= 1) {
        int x = (t >= off) ? sm[t - off] : 0;
        __syncthreads();
        sm[t] += x;
        __syncthreads();
    }
    int run = sm[t] - s;
    for (int i = lo; i < hi; ++i) { int c = a[i]; a[i] = run; run += c; }
    __syncthreads();
    if (t < NB) bkbase[r * (NB + 1) + t] = a[t * NBP1];
    if (t == NB) bkbase[r * (NB + 1) + NB] = NEDGE;
}

// --- p1c: partition scatter into bucketed (src,dst) pairs. grid (NBP1, 3) x 256 ---
__global__ __launch_bounds__(256) void part_scatter(const int* __restrict__ e0,
                                                    const int* __restrict__ e1,
                                                    const int* __restrict__ e2,
                                                    const int* __restrict__ bh,
                                                    int2* __restrict__ bucketed) {
    int r = blockIdx.y, t = threadIdx.x;
    const int* ei  = (r == 0) ? e0 : (r == 1) ? e1 : e2;
    const int* dst = ei + NEDGE;
    __shared__ int cur[NB];
    if (t < NB) cur[t] = bh[((size_t)r * NB + t) * NBP1 + blockIdx.x];
    __syncthreads();
    int2* bk = bucketed + (size_t)r * NEDGE;
    int base = blockIdx.x * BCH;
    int lim  = base + BCH; if (lim > NEDGE) lim = NEDGE;
    for (int i = base + t; i < lim; i += 256) {
        int d = dst[i], s_ = ei[i];
        int pos = atomicAdd(&cur[d >> 10], 1);      // LDS atomic, global position
        bk[pos] = make_int2(s_, d);
    }
}

// --- p2a: per-bucket per-dst counts (exclusive ownership). grid (NB,3) ---
__global__ __launch_bounds__(256) void bucket_count(const int2* __restrict__ bucketed,
                                                    const int* __restrict__ bkbase,
                                                    int* __restrict__ counts_all) {
    int r = blockIdx.y, k = blockIdx.x, t = threadIdx.x;
    int s0 = bkbase[r * (NB + 1) + k], s1 = bkbase[r * (NB + 1) + k + 1];
    __shared__ int lh[1024];
#pragma unroll
    for (int i = 0; i < 4; ++i) lh[t + i * 256] = 0;
    __syncthreads();
    const int2* bk = bucketed + (size_t)r * NEDGE;
    for (int i = s0 + t; i < s1; i += 256)
        atomicAdd(&lh[bk[i].y & 1023], 1);
    __syncthreads();
    int gbase = k << 10;
    int* cnt = counts_all + (size_t)r * N_NODE;
#pragma unroll
    for (int i = 0; i < 4; ++i) {
        int idx = t + i * 256;
        if (gbase + idx < N_NODE) cnt[gbase + idx] = lh[idx];
    }
}

// --- rowptr scans (over counts_all) ---
__global__ __launch_bounds__(256) void scan1(const int* __restrict__ counts_all,
                                             int* __restrict__ bsum) {
    int r = blockIdx.y, b = blockIdx.x, t = threadIdx.x;
    int base = b * 512;
    int lim = N_NODE - base; if (lim > 512) lim = 512;
    const int* c = counts_all + (size_t)r * N_NODE + base;
    int v0 = (2 * t     < lim) ? c[2 * t]     : 0;
    int v1 = (2 * t + 1 < lim) ? c[2 * t + 1] : 0;
    __shared__ int sm[256];
    sm[t] = v0 + v1;
    __syncthreads();
    for (int off = 128; off; off >>= 1) {
        if (t < off) sm[t] += sm[t + off];
        __syncthreads();
    }
    if (t == 0) bsum[r * NBSC + b] = sm[0];
}

__global__ __launch_bounds__(256) void scan3(const int* __restrict__ counts_all,
                                             int* __restrict__ rowptr_all,
                                             const int* __restrict__ bsum) {
    int r = blockIdx.y, b = blockIdx.x, t = threadIdx.x;
    __shared__ int sm[256];
    sm[t] = (t < b) ? bsum[r * NBSC + t] : 0;
    __syncthreads();
    for (int off = 128; off; off >>= 1) {
        if (t < off) sm[t] += sm[t + off];
        __syncthreads();
    }
    int boff = sm[0];
    __syncthreads();

    int base = b * 512;
    int lim = N_NODE - base; if (lim > 512) lim = 512;
    const int* c = counts_all + (size_t)r * N_NODE;
    int* rp = rowptr_all + (size_t)r * (N_NODE + 1);
    int i0 = base + 2 * t, i1 = i0 + 1;
    int v0 = (2 * t     < lim) ? c[i0] : 0;
    int v1 = (2 * t + 1 < lim) ? c[i1] : 0;
    int ps = v0 + v1;
    sm[t] = ps;
    __syncthreads();
    for (int off = 1; off < 256; off <<= 1) {
        int x = (t >= off) ? sm[t - off] : 0;
        __syncthreads();
        sm[t] += x;
        __syncthreads();
    }
    int excl = sm[t] - ps + boff;
    if (2 * t < lim)     rp[i0] = excl;
    if (2 * t + 1 < lim) rp[i1] = excl + v0;
    if (b == 0 && t == 0) rp[N_NODE] = NEDGE;
}

// --- p2b: per-bucket LDS-cursor scatter into contiguous CSR range. grid (NB,3) ---
__global__ __launch_bounds__(256) void bucket_scatter(const int2* __restrict__ bucketed,
                                                      const int* __restrict__ bkbase,
                                                      const int* __restrict__ rowptr_all,
                                                      int* __restrict__ srcs_all) {
    int r = blockIdx.y, k = blockIdx.x, t = threadIdx.x;
    int s0 = bkbase[r * (NB + 1) + k], s1 = bkbase[r * (NB + 1) + k + 1];
    int gbase = k << 10;
    const int* rp = rowptr_all + (size_t)r * (N_NODE + 1);
    __shared__ int cur[1024];
#pragma unroll
    for (int i = 0; i < 4; ++i) {
        int idx = t + i * 256;
        cur[idx] = (gbase + idx < N_NODE) ? rp[gbase + idx] : 0;
    }
    __syncthreads();
    const int2* bk = bucketed + (size_t)r * NEDGE;
    int* out = srcs_all + (size_t)r * NEDGE;
    for (int i = s0 + t; i < s1; i += 256) {
        int2 e = bk[i];
        int pos = atomicAdd(&cur[e.y & 1023], 1);   // LDS atomic
        out[pos] = e.x;                              // write confined to bucket's CSR range
    }
}

// ---------------- GEMM (fp32 math) + bf16 C-store + fused al_src dot ----------------
template <int BM, int BN, bool RELU>
__global__ __launch_bounds__(128) void gemm3(const float* __restrict__ A0,
                                             const float* __restrict__ A1,
                                             const float* __restrict__ A2,
                                             const float* __restrict__ Bbase,
                                             const float* __restrict__ avec_base,
                                             ushort16* __restrict__ Cbase,
                                             float* __restrict__ al_base, int M) {
    constexpr int K  = 128;
    constexpr int KS = 32;
    constexpr int TX = BN / 8;
    constexpr int TY = BM / 8;
    static_assert(TX * TY == 128, "thread grid");
    constexpr int SA = BM + 4;
    constexpr int SB = BN + 4;
    __shared__ float as[KS * SA];
    __shared__ float bs[KS * SB];
    const int r = blockIdx.y;
    const float* A = (r == 0) ? A0 : (r == 1) ? A1 : A2;
    const float* B = Bbase + (size_t)r * K * BN;
    uint32* Cu = reinterpret_cast<uint32*>(Cbase + (size_t)r * M * BN);
    const int t  = threadIdx.x;
    const int tx = t % TX;
    const int ty = t / TX;
    const int m0 = blockIdx.x * BM;
    const int r0 = ty * 8;
    const int c0 = tx * 8;
    float acc[8][8] = {};
    const float4* A4 = reinterpret_cast<const float4*>(A);
    const float4* B4 = reinterpret_cast<const float4*>(B);

    for (int ks = 0; ks < K; ks += KS) {
        __syncthreads();
#pragma unroll
        for (int i = 0; i < BM * 8 / 128; ++i) {
            int idx = t + i * 128;
            int row = idx >> 3;
            int kq  = idx & 7;
            float4 v = make_float4(0.f, 0.f, 0.f, 0.f);
            if (m0 + row < M) {
                v = A4[(size_t)(m0 + row) * (K / 4) + (ks >> 2) + kq];
                if (RELU) {
                    v.x = fmaxf(v.x, 0.f); v.y = fmaxf(v.y, 0.f);
                    v.z = fmaxf(v.z, 0.f); v.w = fmaxf(v.w, 0.f);
                }
            }
            as[(kq * 4 + 0) * SA + row] = v.x;
            as[(kq * 4 + 1) * SA + row] = v.y;
            as[(kq * 4 + 2) * SA + row] = v.z;
            as[(kq * 4 + 3) * SA + row] = v.w;
        }
#pragma unroll
        for (int i = 0; i < KS * BN / 4 / 128; ++i) {
            int idx = t + i * 128;
            int nq  = idx % (BN / 4);
            int kr  = idx / (BN / 4);
            float4 v = B4[(size_t)(ks + kr) * (BN / 4) + nq];
            *reinterpret_cast<float4*>(&bs[kr * SB + nq * 4]) = v;
        }
        __syncthreads();
#pragma unroll 2
        for (int k = 0; k < KS; ++k) {
            float4 a0 = *reinterpret_cast<const float4*>(&as[k * SA + r0]);
            float4 a1 = *reinterpret_cast<const float4*>(&as[k * SA + r0 + 4]);
            float4 b0 = *reinterpret_cast<const float4*>(&bs[k * SB + c0]);
            float4 b1 = *reinterpret_cast<const float4*>(&bs[k * SB + c0 + 4]);
            float av[8] = {a0.x, a0.y, a0.z, a0.w, a1.x, a1.y, a1.z, a1.w};
            float bv[8] = {b0.x, b0.y, b0.z, b0.w, b1.x, b1.y, b1.z, b1.w};
#pragma unroll
            for (int i = 0; i < 8; ++i)
#pragma unroll
                for (int j = 0; j < 8; ++j)
                    acc[i][j] = fmaf(av[i], bv[j], acc[i][j]);
        }
    }
    // bf16 C-store
#pragma unroll
    for (int i = 0; i < 8; ++i) {
        int rr = m0 + r0 + i;
        if (rr < M) {
            uint4 p;
            p.x = bf16r(acc[i][0]) | (bf16r(acc[i][1]) << 16);
            p.y = bf16r(acc[i][2]) | (bf16r(acc[i][3]) << 16);
            p.z = bf16r(acc[i][4]) | (bf16r(acc[i][5]) << 16);
            p.w = bf16r(acc[i][6]) | (bf16r(acc[i][7]) << 16);
            *reinterpret_cast<uint4*>(&Cu[(size_t)rr * (BN / 2) + (c0 >> 1)]) = p;
        }
    }
    // fused al_src = C-row . avec (from fp32 acc, BEFORE bf16 rounding)
    const float* av = avec_base + r * BN;
    float asv[8];
#pragma unroll
    for (int j = 0; j < 8; ++j) asv[j] = av[c0 + j];
    float* al = al_base + (size_t)r * M;
#pragma unroll
    for (int i = 0; i < 8; ++i) {
        float p = 0.f;
#pragma unroll
        for (int j = 0; j < 8; ++j) p += acc[i][j] * asv[j];
#pragma unroll
        for (int off = TX / 2; off; off >>= 1) p += __shfl_xor(p, off);
        int rr = m0 + r0 + i;
        if (tx == 0 && rr < M) al[rr] = p;
    }
}

// ---------------- row dot (layer-1 al_dst), 3 relations batched ----------------
__global__ void row_dot3(const float* __restrict__ X0, const float* __restrict__ X1,
                         const float* __restrict__ X2, const float* __restrict__ vbase,
                         int C, float* __restrict__ out_all, int n) {
    int r    = blockIdx.y;
    int gw   = (blockIdx.x * 256 + threadIdx.x) >> 6;
    int lane = threadIdx.x & 63;
    if (gw >= n) return;
    const float* X = (r == 0) ? X0 : (r == 1) ? X1 : X2;
    const float* v = vbase + r * C;
    const float* row = X + (size_t)gw * C;
    float s = 0.f;
    for (int c = lane; c < C; c += 64) s += row[c] * v[c];
#pragma unroll
    for (int off = 32; off; off >>= 1) s += __shfl_xor(s, off);
    if (lane == 0) out_all[(size_t)r * n + gw] = s;
}

// ---------------- single-pass softmax-aggregate helpers (inline exp, bf16 gathers) ----------------
// No max-subtraction: logits bounded (~|8|) at this data scale; exp() safe in fp32,
// alpha = ex/(den+eps) algebraically identical to the max-shifted form. Inline exp is
// free here: the kernel is memory-bound (r10 experiment: VALUBusy 61->33% left dur unchanged).
__device__ __forceinline__ float2 seg128(const int* __restrict__ rp, const int* __restrict__ ss,
                                         const float* __restrict__ als,
                                         const uint32* __restrict__ hv,   // 2 bf16/uint, row=64 uints
                                         float ad, int d, int lane) {
    int s = rp[d], e = rp[d + 1];
    float den = 0.f, ax = 0.f, ay = 0.f;
    int i = s;
    for (; i + 4 <= e; i += 4) {
        int s0 = ss[i], s1 = ss[i + 1], s2 = ss[i + 2], s3 = ss[i + 3];
        float l0 = als[s0], l1 = als[s1], l2 = als[s2], l3 = als[s3];
        uint32 u0 = hv[(size_t)s0 * 64 + lane];
        uint32 u1 = hv[(size_t)s1 * 64 + lane];
        uint32 u2 = hv[(size_t)s2 * 64 + lane];
        uint32 u3 = hv[(size_t)s3 * 64 + lane];
        float e0 = __expf(leakyf(l0 + ad)), e1 = __expf(leakyf(l1 + ad));
        float e2 = __expf(leakyf(l2 + ad)), e3 = __expf(leakyf(l3 + ad));
        den += (e0 + e1) + (e2 + e3);
        ax = fmaf(e0, bf_lo(u0), ax); ay = fmaf(e0, bf_hi(u0), ay);
        ax = fmaf(e1, bf_lo(u1), ax); ay = fmaf(e1, bf_hi(u1), ay);
        ax = fmaf(e2, bf_lo(u2), ax); ay = fmaf(e2, bf_hi(u2), ay);
        ax = fmaf(e3, bf_lo(u3), ax); ay = fmaf(e3, bf_hi(u3), ay);
    }
    for (; i < e; ++i) {
        int sv = ss[i];
        float ex = __expf(leakyf(als[sv] + ad));
        uint32 u = hv[(size_t)sv * 64 + lane];
        den += ex;
        ax = fmaf(ex, bf_lo(u), ax); ay = fmaf(ex, bf_hi(u), ay);
    }
    float rden = 1.0f / (den + 1e-16f);
    return make_float2(ax * rden, ay * rden);
}

__device__ __forceinline__ float seg64(const int* __restrict__ rp, const int* __restrict__ ss,
                                       const float* __restrict__ als,
                                       const ushort16* __restrict__ hv,  // 1 bf16/lane, row=64
                                       float ad, int d, int lane) {
    int s = rp[d], e = rp[d + 1];
    float den = 0.f, acc = 0.f;
    int i = s;
    for (; i + 4 <= e; i += 4) {
        int s0 = ss[i], s1 = ss[i + 1], s2 = ss[i + 2], s3 = ss[i + 3];
        float l0 = als[s0], l1 = als[s1], l2 = als[s2], l3 = als[s3];
        uint32 h0 = hv[(size_t)s0 * 64 + lane];
        uint32 h1 = hv[(size_t)s1 * 64 + lane];
        uint32 h2 = hv[(size_t)s2 * 64 + lane];
        uint32 h3 = hv[(size_t)s3 * 64 + lane];
        float e0 = __expf(leakyf(l0 + ad)), e1 = __expf(leakyf(l1 + ad));
        float e2 = __expf(leakyf(l2 + ad)), e3 = __expf(leakyf(l3 + ad));
        den += (e0 + e1) + (e2 + e3);
        acc = fmaf(e0, __uint_as_float(h0 << 16), acc);
        acc = fmaf(e1, __uint_as_float(h1 << 16), acc);
        acc = fmaf(e2, __uint_as_float(h2 << 16), acc);
        acc = fmaf(e3, __uint_as_float(h3 << 16), acc);
    }
    for (; i < e; ++i) {
        int sv = ss[i];
        float ex = __expf(leakyf(als[sv] + ad));
        den += ex;
        acc = fmaf(ex, __uint_as_float(((uint32)hv[(size_t)sv * 64 + lane]) << 16), acc);
    }
    return acc / (den + 1e-16f);
}

// ---------------- layer-1 agg + fused layer-2 al_dst; grid (12500, 2), 4 indep waves ----------------
// Epilogue writes aldst_all IN-PLACE with the layer-2 dst logits relu(h).wd2[r]:
// each element aldst_all[r*N+d] is read (layer-1) then overwritten (layer-2) by the SAME block.
__global__ __launch_bounds__(256) void agg1_sp(const int* __restrict__ rowptr_all,
                                               const int* __restrict__ srcs_all,
                                               const float* __restrict__ alsrc_all,
                                               float* __restrict__ aldst_all,
                                               const ushort16* __restrict__ hs_all,
                                               const float* __restrict__ b1,
                                               const float* __restrict__ wd2,
                                               float* __restrict__ h_item,
                                               float* __restrict__ h_user) {
    const int lane = threadIdx.x & 63;
    const int d = blockIdx.x * 4 + (threadIdx.x >> 6);
    if (d >= N_NODE) return;
    const uint32* hv = reinterpret_cast<const uint32*>(hs_all);   // per-rel stride N*64 uints
    if (blockIdx.y == 0) {           // item dst: relation 0
        float2 w = seg128(rowptr_all, srcs_all, alsrc_all, hv, aldst_all[d], d, lane);
        float2 b = ((const float2*)b1)[lane];
        float2 h = make_float2(w.x + b.x, w.y + b.y);
        ((float2*)h_item)[(size_t)d * 64 + lane] = h;
        // fused layer-2 al_dst for item: relu(h) . wd2[0]
        float2 v0 = ((const float2*)wd2)[lane];
        float p = fmaxf(h.x, 0.f) * v0.x + fmaxf(h.y, 0.f) * v0.y;
#pragma unroll
        for (int off = 32; off; off >>= 1) p += __shfl_xor(p, off);
        if (lane == 0) aldst_all[d] = p;
    } else {                         // user dst: relations 1 + 2 in one wave
        float2 w1 = seg128(rowptr_all + (N_NODE + 1), srcs_all + NEDGE,
                           alsrc_all + N_NODE, hv + (size_t)N_NODE * 64,
                           aldst_all[N_NODE + d], d, lane);
        float2 w2 = seg128(rowptr_all + 2 * (N_NODE + 1), srcs_all + (size_t)2 * NEDGE,
                           alsrc_all + 2 * N_NODE, hv + (size_t)2 * N_NODE * 64,
                           aldst_all[2 * N_NODE + d], d, lane);
        float2 bA = ((const float2*)(b1 + HIDD))[lane];
        float2 bB = ((const float2*)(b1 + 2 * HIDD))[lane];
        float2 h = make_float2(w1.x + w2.x + bA.x + bB.x, w1.y + w2.y + bA.y + bB.y);
        ((float2*)h_user)[(size_t)d * 64 + lane] = h;
        // fused layer-2 al_dst for user: relu(h) . wd2[1], relu(h) . wd2[2]
        float hx = fmaxf(h.x, 0.f), hy = fmaxf(h.y, 0.f);
        float2 v1 = ((const float2*)(wd2 + HIDD))[lane];
        float2 v2 = ((const float2*)(wd2 + 2 * HIDD))[lane];
        float p1 = hx * v1.x + hy * v1.y;
        float p2 = hx * v2.x + hy * v2.y;
#pragma unroll
        for (int off = 32; off; off >>= 1) p1 += __shfl_xor(p1, off);
#pragma unroll
        for (int off = 32; off; off >>= 1) p2 += __shfl_xor(p2, off);
        if (lane == 0) {
            aldst_all[N_NODE + d]     = p1;
            aldst_all[2 * N_NODE + d] = p2;
        }
    }
}

// ---------------- layer-2 agg (C=64) ----------------
__global__ __launch_bounds__(256) void agg2_sp(const int* __restrict__ rowptr_all,
                                               const int* __restrict__ srcs_all,
                                               const float* __restrict__ alsrc_all,
                                               const float* __restrict__ aldst_all,
                                               const ushort16* __restrict__ hs_all,
                                               const float* __restrict__ b2,
                                               float* __restrict__ o_item,
                                               float* __restrict__ o_user) {
    const int lane = threadIdx.x & 63;
    const int d = blockIdx.x * 4 + (threadIdx.x >> 6);
    if (d >= N_NODE) return;
    if (blockIdx.y == 0) {
        float w = seg64(rowptr_all, srcs_all, alsrc_all, hs_all, aldst_all[d], d, lane);
        o_item[(size_t)d * OUTD + lane] = w + b2[lane];
    } else {
        float w1 = seg64(rowptr_all + (N_NODE + 1), srcs_all + NEDGE,
                         alsrc_all + N_NODE, hs_all + (size_t)N_NODE * OUTD,
                         aldst_all[N_NODE + d], d, lane);
        float w2 = seg64(rowptr_all + 2 * (N_NODE + 1), srcs_all + (size_t)2 * NEDGE,
                         alsrc_all + 2 * N_NODE, hs_all + (size_t)2 * N_NODE * OUTD,
                         aldst_all[2 * N_NODE + d], d, lane);
        o_user[(size_t)d * OUTD + lane] = w1 + w2 + b2[OUTD + lane] + b2[2 * OUTD + lane];
    }
}

// ---------------- bilinear edge scoring ----------------
__global__ void score_k(const int* __restrict__ e0, const int* __restrict__ e1,
                        const int* __restrict__ e2,
                        const float* __restrict__ o_user, const float* __restrict__ o_item,
                        const float* __restrict__ relw, float* __restrict__ out, int L) {
    int g    = blockIdx.x * 4 + (threadIdx.x >> 6);
    int lane = threadIdx.x & 63;
    int r = g / L, l = g - r * L;
    if (r >= 3) return;
    const int* ei = (r == 0) ? e0 : (r == 1) ? e1 : e2;
    int ai = ei[l];
    int bi = ei[L + l];
    const float* A = (r == 1) ? o_item : o_user;
    const float* B = (r == 0) ? o_item : o_user;
    float v = A[(size_t)ai * OUTD + lane] * relw[r * OUTD + lane] * B[(size_t)bi * OUTD + lane];
#pragma unroll
    for (int off = 32; off; off >>= 1) v += __shfl_xor(v, off);
    if (lane == 0) out[r * L + l] = v;
}

extern "C" void kernel_launch(void* const* d_in, const int* in_sizes, int n_in,
                              void* d_out, int out_size, void* d_ws, size_t ws_size,
                              hipStream_t stream) {
    const float* x_user = (const float*)d_in[0];
    const float* x_item = (const float*)d_in[1];
    const float* W1s = (const float*)d_in[2];
    const float* W1d = (const float*)d_in[3];
    const float* a1s = (const float*)d_in[4];
    const float* a1d = (const float*)d_in[5];
    const float* b1  = (const float*)d_in[6];
    const float* W2s = (const float*)d_in[7];
    const float* W2d = (const float*)d_in[8];
    const float* a2s = (const float*)d_in[9];
    const float* a2d = (const float*)d_in[10];
    const float* b2  = (const float*)d_in[11];
    const float* relw= (const float*)d_in[12];
    const int* ei0 = (const int*)d_in[13];
    const int* ei1 = (const int*)d_in[14];
    const int* ei2 = (const int*)d_in[15];
    const int* el0 = (const int*)d_in[16];
    const int* el1 = (const int*)d_in[17];
    const int* el2 = (const int*)d_in[18];
    float* out = (float*)d_out;
    (void)ws_size; (void)n_in; (void)in_sizes; (void)out_size;

    char* ws = (char*)d_ws;
    size_t off = 0;
    auto alloc = [&](size_t bytes) -> void* {
        void* p = ws + off;
        off = (off + bytes + 255) & ~(size_t)255;
        return p;
    };
    int*     rowptr_all = (int*)alloc((size_t)3 * (N_NODE + 1) * 4);
    int*     counts_all = (int*)alloc((size_t)3 * N_NODE * 4);
    int*     srcs_all   = (int*)alloc((size_t)3 * NEDGE * 4);
    int*     bsum       = (int*)alloc((size_t)3 * NBSC * 4);
    int*     bh         = (int*)alloc((size_t)3 * NB * NBP1 * 4);
    int*     bkbase     = (int*)alloc((size_t)3 * (NB + 1) * 4);
    int2*    bucketed   = (int2*)alloc((size_t)3 * NEDGE * 8);
    ushort16* hs_bf     = (ushort16*)alloc((size_t)3 * N_NODE * HIDD * 2);  // bf16; L2 reuses first 3*N*64
    float*   h_item1    = (float*)alloc((size_t)2 * N_NODE * HIDD * 4);     // fp32
    float*   h_user1    = h_item1 + (size_t)N_NODE * HIDD;
    float*   o_item     = (float*)alloc((size_t)N_NODE * OUTD * 4);
    float*   o_user     = (float*)alloc((size_t)N_NODE * OUTD * 4);
    float*   alsrc_all  = (float*)alloc((size_t)3 * N_NODE * 4);
    float*   aldst_all  = (float*)alloc((size_t)3 * N_NODE * 4);
    float*   wd1        = (float*)alloc(3 * FDIM * 4);
    float*   wd2        = (float*)alloc(3 * HIDD * 4);

    fold_wd<<<3, 128, 0, stream>>>(W1d, a1d, W2d, a2d, wd1, wd2);

    // ---- CSR build: two-level bucket partition ----
    part_hist<<<dim3(NBP1, 3), 256, 0, stream>>>(ei0, ei1, ei2, bh);
    part_scan<<<3, 256, 0, stream>>>(bh, bkbase);
    part_scatter<<<dim3(NBP1, 3), 256, 0, stream>>>(ei0, ei1, ei2, bh, bucketed);
    bucket_count<<<dim3(NB, 3), 256, 0, stream>>>(bucketed, bkbase, counts_all);
    scan1<<<dim3(NBSC, 3), 256, 0, stream>>>(counts_all, bsum);
    scan3<<<dim3(NBSC, 3), 256, 0, stream>>>(counts_all, rowptr_all, bsum);
    bucket_scatter<<<dim3(NB, 3), 256, 0, stream>>>(bucketed, bkbase, rowptr_all, srcs_all);

    const int rd = (N_NODE * 64 + 255) / 256;
    const int ag = (N_NODE + 3) / 4;

    // ---- layer 1 ----
    row_dot3<<<dim3(rd, 3), 256, 0, stream>>>(x_item, x_user, x_user, wd1, FDIM,
                                              aldst_all, N_NODE);
    gemm3<64, 128, false><<<dim3((N_NODE + 63) / 64, 3), 128, 0, stream>>>(
        x_user, x_item, x_user, W1s, a1s, hs_bf, alsrc_all, N_NODE);
    // agg1 also writes layer-2 al_dst into aldst_all in-place (per-block read-then-write)
    agg1_sp<<<dim3(ag, 2), 256, 0, stream>>>(rowptr_all, srcs_all, alsrc_all, aldst_all,
                                             hs_bf, b1, wd2, h_item1, h_user1);

    // ---- layer 2 (ReLU folded into gemm A-staging; hs_bf overwrite safe: L1 hs consumed) ----
    gemm3<128, 64, true><<<dim3((N_NODE + 127) / 128, 3), 128, 0, stream>>>(
        h_user1, h_item1, h_user1, W2s, a2s, hs_bf, alsrc_all, N_NODE);
    agg2_sp<<<dim3(ag, 2), 256, 0, stream>>>(rowptr_all, srcs_all, alsrc_all, aldst_all,
                                             hs_bf, b2, o_item, o_user);

    // ---- scoring ----
    score_k<<<(3 * NL + 3) / 4, 256, 0, stream>>>(el0, el1, el2, o_user, o_item, relw, out, NL);
}

// Round 12
// 408.996 us; speedup vs baseline: 1.1879x; 1.0548x over previous
//
#include <hip/hip_runtime.h>
#include <cstdint>
#include <cstddef>

#define N_NODE 50000
#define NEDGE  500000
#define NL     100000
#define FDIM   128
#define HIDD   128
#define OUTD   64
#define NBSC   98        // ceil(N_NODE / 512) for rowptr scan
#define NB     49        // buckets = ceil(50000 / 1024), bucket = dst >> 10
#define BCH    8192      // edges per partition block
#define NBP1   62        // ceil(NEDGE / BCH)

typedef unsigned int uint32;
typedef unsigned short ushort16;

__device__ __forceinline__ float leakyf(float x) { return x > 0.f ? x : 0.2f * x; }

// round-to-nearest-even f32 -> bf16 (values are finite/sane here)
__device__ __forceinline__ uint32 bf16r(float x) {
    uint32 u = __float_as_uint(x);
    return (u + 0x7fffu + ((u >> 16) & 1u)) >> 16;
}
__device__ __forceinline__ float bf_lo(uint32 u) { return __uint_as_float(u << 16); }
__device__ __forceinline__ float bf_hi(uint32 u) { return __uint_as_float(u & 0xffff0000u); }

// ---------------- fold Wd @ a_d -> per-relation length-128 vectors ----------------
__global__ void fold_wd(const float* __restrict__ W1d, const float* __restrict__ a1d,
                        const float* __restrict__ W2d, const float* __restrict__ a2d,
                        float* __restrict__ wd1, float* __restrict__ wd2) {
    int r = blockIdx.x;          // 3 relations
    int f = threadIdx.x;         // 128
    const float* w  = W1d + ((size_t)r * FDIM + f) * HIDD;
    const float* a  = a1d + r * HIDD;
    float s = 0.f;
    for (int h = 0; h < HIDD; ++h) s += w[h] * a[h];
    wd1[r * FDIM + f] = s;
    const float* w2 = W2d + ((size_t)r * HIDD + f) * OUTD;
    const float* a2 = a2d + r * OUTD;
    float s2 = 0.f;
    for (int o = 0; o < OUTD; ++o) s2 += w2[o] * a2[o];
    wd2[r * HIDD + f] = s2;
}

// ================= CSR build: two-level bucket partition (write-locality) =================

__global__ __launch_bounds__(256) void part_hist(const int* __restrict__ e0,
                                                 const int* __restrict__ e1,
                                                 const int* __restrict__ e2,
                                                 int* __restrict__ bh) {
    int r = blockIdx.y, t = threadIdx.x;
    const int* ei  = (r == 0) ? e0 : (r == 1) ? e1 : e2;
    const int* dst = ei + NEDGE;
    __shared__ int lh[NB];
    if (t < NB) lh[t] = 0;
    __syncthreads();
    int base = blockIdx.x * BCH;
    int lim  = base + BCH; if (lim > NEDGE) lim = NEDGE;
    for (int i = base + t; i < lim; i += 256)
        atomicAdd(&lh[dst[i] >> 10], 1);
    __syncthreads();
    if (t < NB) bh[((size_t)r * NB + t) * NBP1 + blockIdx.x] = lh[t];
}

__global__ __launch_bounds__(256) void part_scan(int* __restrict__ bh,
                                                 int* __restrict__ bkbase) {
    int r = blockIdx.x, t = threadIdx.x;
    int* a = bh + (size_t)r * NB * NBP1;
    const int n = NB * NBP1;                 // 3038
    const int per = (n + 255) / 256;         // 12
    int lo = t * per, hi = lo + per; if (hi > n) hi = n;
    int s = 0;
    for (int i = lo; i < hi; ++i) s += a[i];
    __shared__ int sm[256];
    sm[t] = s;
    __syncthreads();
    for (int off = 1; off < 256; off <<= 1) {
        int x = (t >= off) ? sm[t - off] : 0;
        __syncthreads();
        sm[t] += x;
        __syncthreads();
    }
    int run = sm[t] - s;
    for (int i = lo; i < hi; ++i) { int c = a[i]; a[i] = run; run += c; }
    __syncthreads();
    if (t < NB) bkbase[r * (NB + 1) + t] = a[t * NBP1];
    if (t == NB) bkbase[r * (NB + 1) + NB] = NEDGE;
}

__global__ __launch_bounds__(256) void part_scatter(const int* __restrict__ e0,
                                                    const int* __restrict__ e1,
                                                    const int* __restrict__ e2,
                                                    const int* __restrict__ bh,
                                                    int2* __restrict__ bucketed) {
    int r = blockIdx.y, t = threadIdx.x;
    const int* ei  = (r == 0) ? e0 : (r == 1) ? e1 : e2;
    const int* dst = ei + NEDGE;
    __shared__ int cur[NB];
    if (t < NB) cur[t] = bh[((size_t)r * NB + t) * NBP1 + blockIdx.x];
    __syncthreads();
    int2* bk = bucketed + (size_t)r * NEDGE;
    int base = blockIdx.x * BCH;
    int lim  = base + BCH; if (lim > NEDGE) lim = NEDGE;
    for (int i = base + t; i < lim; i += 256) {
        int d = dst[i], s_ = ei[i];
        int pos = atomicAdd(&cur[d >> 10], 1);      // LDS atomic, global position
        bk[pos] = make_int2(s_, d);
    }
}

__global__ __launch_bounds__(256) void bucket_count(const int2* __restrict__ bucketed,
                                                    const int* __restrict__ bkbase,
                                                    int* __restrict__ counts_all) {
    int r = blockIdx.y, k = blockIdx.x, t = threadIdx.x;
    int s0 = bkbase[r * (NB + 1) + k], s1 = bkbase[r * (NB + 1) + k + 1];
    __shared__ int lh[1024];
#pragma unroll
    for (int i = 0; i < 4; ++i) lh[t + i * 256] = 0;
    __syncthreads();
    const int2* bk = bucketed + (size_t)r * NEDGE;
    for (int i = s0 + t; i < s1; i += 256)
        atomicAdd(&lh[bk[i].y & 1023], 1);
    __syncthreads();
    int gbase = k << 10;
    int* cnt = counts_all + (size_t)r * N_NODE;
#pragma unroll
    for (int i = 0; i < 4; ++i) {
        int idx = t + i * 256;
        if (gbase + idx < N_NODE) cnt[gbase + idx] = lh[idx];
    }
}

__global__ __launch_bounds__(256) void scan1(const int* __restrict__ counts_all,
                                             int* __restrict__ bsum) {
    int r = blockIdx.y, b = blockIdx.x, t = threadIdx.x;
    int base = b * 512;
    int lim = N_NODE - base; if (lim > 512) lim = 512;
    const int* c = counts_all + (size_t)r * N_NODE + base;
    int v0 = (2 * t     < lim) ? c[2 * t]     : 0;
    int v1 = (2 * t + 1 < lim) ? c[2 * t + 1] : 0;
    __shared__ int sm[256];
    sm[t] = v0 + v1;
    __syncthreads();
    for (int off = 128; off; off >>= 1) {
        if (t < off) sm[t] += sm[t + off];
        __syncthreads();
    }
    if (t == 0) bsum[r * NBSC + b] = sm[0];
}

__global__ __launch_bounds__(256) void scan3(const int* __restrict__ counts_all,
                                             int* __restrict__ rowptr_all,
                                             const int* __restrict__ bsum) {
    int r = blockIdx.y, b = blockIdx.x, t = threadIdx.x;
    __shared__ int sm[256];
    sm[t] = (t < b) ? bsum[r * NBSC + t] : 0;
    __syncthreads();
    for (int off = 128; off; off >>= 1) {
        if (t < off) sm[t] += sm[t + off];
        __syncthreads();
    }
    int boff = sm[0];
    __syncthreads();

    int base = b * 512;
    int lim = N_NODE - base; if (lim > 512) lim = 512;
    const int* c = counts_all + (size_t)r * N_NODE;
    int* rp = rowptr_all + (size_t)r * (N_NODE + 1);
    int i0 = base + 2 * t, i1 = i0 + 1;
    int v0 = (2 * t     < lim) ? c[i0] : 0;
    int v1 = (2 * t + 1 < lim) ? c[i1] : 0;
    int ps = v0 + v1;
    sm[t] = ps;
    __syncthreads();
    for (int off = 1; off < 256; off <<= 1) {
        int x = (t >= off) ? sm[t - off] : 0;
        __syncthreads();
        sm[t] += x;
        __syncthreads();
    }
    int excl = sm[t] - ps + boff;
    if (2 * t < lim)     rp[i0] = excl;
    if (2 * t + 1 < lim) rp[i1] = excl + v0;
    if (b == 0 && t == 0) rp[N_NODE] = NEDGE;
}

__global__ __launch_bounds__(256) void bucket_scatter(const int2* __restrict__ bucketed,
                                                      const int* __restrict__ bkbase,
                                                      const int* __restrict__ rowptr_all,
                                                      int* __restrict__ srcs_all) {
    int r = blockIdx.y, k = blockIdx.x, t = threadIdx.x;
    int s0 = bkbase[r * (NB + 1) + k], s1 = bkbase[r * (NB + 1) + k + 1];
    int gbase = k << 10;
    const int* rp = rowptr_all + (size_t)r * (N_NODE + 1);
    __shared__ int cur[1024];
#pragma unroll
    for (int i = 0; i < 4; ++i) {
        int idx = t + i * 256;
        cur[idx] = (gbase + idx < N_NODE) ? rp[gbase + idx] : 0;
    }
    __syncthreads();
    const int2* bk = bucketed + (size_t)r * NEDGE;
    int* out = srcs_all + (size_t)r * NEDGE;
    for (int i = s0 + t; i < s1; i += 256) {
        int2 e = bk[i];
        int pos = atomicAdd(&cur[e.y & 1023], 1);   // LDS atomic
        out[pos] = e.x;                              // write confined to bucket's CSR range
    }
}

// ------- GEMM (fp32) + bf16 C-store + fused al_src dot (+ optional fused al_dst dot) -------
// DOT (layer-1 only): each relation's A matrix IS the dst-feature matrix of another relation:
//   r0 stages x_user -> al_dst[1] = x_user . wd1[1]; r1 stages x_item -> al_dst[0]; r2 -> al_dst[2].
// Per-thread partial over staged float4s, reduced across the 8 lanes sharing a row.
template <int BM, int BN, bool RELU, bool DOT>
__global__ __launch_bounds__(128) void gemm3(const float* __restrict__ A0,
                                             const float* __restrict__ A1,
                                             const float* __restrict__ A2,
                                             const float* __restrict__ Bbase,
                                             const float* __restrict__ avec_base,
                                             ushort16* __restrict__ Cbase,
                                             float* __restrict__ al_base,
                                             const float* __restrict__ wdvec,
                                             float* __restrict__ adst_base, int M) {
    constexpr int K  = 128;
    constexpr int KS = 32;
    constexpr int TX = BN / 8;
    constexpr int TY = BM / 8;
    static_assert(TX * TY == 128, "thread grid");
    constexpr int SA = BM + 4;
    constexpr int SB = BN + 4;
    constexpr int NI = BM * 8 / 128;    // A-stage iterations per ks chunk
    __shared__ float as[KS * SA];
    __shared__ float bs[KS * SB];
    const int r = blockIdx.y;
    const float* A = (r == 0) ? A0 : (r == 1) ? A1 : A2;
    const float* B = Bbase + (size_t)r * K * BN;
    uint32* Cu = reinterpret_cast<uint32*>(Cbase + (size_t)r * M * BN);
    const int t  = threadIdx.x;
    const int tx = t % TX;
    const int ty = t / TX;
    const int m0 = blockIdx.x * BM;
    const int r0 = ty * 8;
    const int c0 = tx * 8;
    const int mr = (r == 0) ? 1 : (r == 1) ? 0 : 2;   // DOT target relation
    const float* wdot = wdvec + mr * K;
    float acc[8][8] = {};
    float dp[NI] = {};
    const float4* A4 = reinterpret_cast<const float4*>(A);
    const float4* B4 = reinterpret_cast<const float4*>(B);

    for (int ks = 0; ks < K; ks += KS) {
        __syncthreads();
#pragma unroll
        for (int i = 0; i < NI; ++i) {
            int idx = t + i * 128;
            int row = idx >> 3;
            int kq  = idx & 7;
            float4 v = make_float4(0.f, 0.f, 0.f, 0.f);
            if (m0 + row < M) {
                v = A4[(size_t)(m0 + row) * (K / 4) + (ks >> 2) + kq];
                if (RELU) {
                    v.x = fmaxf(v.x, 0.f); v.y = fmaxf(v.y, 0.f);
                    v.z = fmaxf(v.z, 0.f); v.w = fmaxf(v.w, 0.f);
                }
            }
            if (DOT) {
                float4 wv = *reinterpret_cast<const float4*>(&wdot[ks + kq * 4]);
                dp[i] = fmaf(v.x, wv.x, dp[i]); dp[i] = fmaf(v.y, wv.y, dp[i]);
                dp[i] = fmaf(v.z, wv.z, dp[i]); dp[i] = fmaf(v.w, wv.w, dp[i]);
            }
            as[(kq * 4 + 0) * SA + row] = v.x;
            as[(kq * 4 + 1) * SA + row] = v.y;
            as[(kq * 4 + 2) * SA + row] = v.z;
            as[(kq * 4 + 3) * SA + row] = v.w;
        }
#pragma unroll
        for (int i = 0; i < KS * BN / 4 / 128; ++i) {
            int idx = t + i * 128;
            int nq  = idx % (BN / 4);
            int kr  = idx / (BN / 4);
            float4 v = B4[(size_t)(ks + kr) * (BN / 4) + nq];
            *reinterpret_cast<float4*>(&bs[kr * SB + nq * 4]) = v;
        }
        __syncthreads();
#pragma unroll 2
        for (int k = 0; k < KS; ++k) {
            float4 a0 = *reinterpret_cast<const float4*>(&as[k * SA + r0]);
            float4 a1 = *reinterpret_cast<const float4*>(&as[k * SA + r0 + 4]);
            float4 b0 = *reinterpret_cast<const float4*>(&bs[k * SB + c0]);
            float4 b1 = *reinterpret_cast<const float4*>(&bs[k * SB + c0 + 4]);
            float av[8] = {a0.x, a0.y, a0.z, a0.w, a1.x, a1.y, a1.z, a1.w};
            float bv[8] = {b0.x, b0.y, b0.z, b0.w, b1.x, b1.y, b1.z, b1.w};
#pragma unroll
            for (int i = 0; i < 8; ++i)
#pragma unroll
                for (int j = 0; j < 8; ++j)
                    acc[i][j] = fmaf(av[i], bv[j], acc[i][j]);
        }
    }
    // fused al_dst write (layer-1): reduce dp over the 8 lanes sharing a row
    if (DOT) {
        float* adst = adst_base + (size_t)mr * M;
#pragma unroll
        for (int i = 0; i < NI; ++i) {
            float p = dp[i];
            p += __shfl_xor(p, 4); p += __shfl_xor(p, 2); p += __shfl_xor(p, 1);
            int row = (t + i * 128) >> 3;
            int rr = m0 + row;
            if ((t & 7) == 0 && rr < M) adst[rr] = p;
        }
    }
    // bf16 C-store
#pragma unroll
    for (int i = 0; i < 8; ++i) {
        int rr = m0 + r0 + i;
        if (rr < M) {
            uint4 p;
            p.x = bf16r(acc[i][0]) | (bf16r(acc[i][1]) << 16);
            p.y = bf16r(acc[i][2]) | (bf16r(acc[i][3]) << 16);
            p.z = bf16r(acc[i][4]) | (bf16r(acc[i][5]) << 16);
            p.w = bf16r(acc[i][6]) | (bf16r(acc[i][7]) << 16);
            *reinterpret_cast<uint4*>(&Cu[(size_t)rr * (BN / 2) + (c0 >> 1)]) = p;
        }
    }
    // fused al_src = C-row . avec (from fp32 acc, BEFORE bf16 rounding)
    const float* av = avec_base + r * BN;
    float asv[8];
#pragma unroll
    for (int j = 0; j < 8; ++j) asv[j] = av[c0 + j];
    float* al = al_base + (size_t)r * M;
#pragma unroll
    for (int i = 0; i < 8; ++i) {
        float p = 0.f;
#pragma unroll
        for (int j = 0; j < 8; ++j) p += acc[i][j] * asv[j];
#pragma unroll
        for (int off = TX / 2; off; off >>= 1) p += __shfl_xor(p, off);
        int rr = m0 + r0 + i;
        if (tx == 0 && rr < M) al[rr] = p;
    }
}

// ------- paired-edge single-pass softmax-aggregate helpers -------
// 2 edges per VMEM instruction: lanes 0-31 carry edge i, lanes 32-63 edge i+1.
// Halves combined at segment end via shfl_xor(,32). Inline exp is free (memory-bound).
__device__ __forceinline__ float4 seg128p(const int* __restrict__ rp, const int* __restrict__ ss,
                                          const float* __restrict__ als,
                                          const uint2* __restrict__ hv2,  // row = 32 uint2 (128 bf16)
                                          float ad, int d, int half, int col) {
    int s = rp[d], e = rp[d + 1];
    float den = 0.f;
    float4 ac = make_float4(0.f, 0.f, 0.f, 0.f);
    int i = s;
    for (; i + 4 <= e; i += 4) {
        int sA = ss[i + half];
        int sB = ss[i + 2 + half];
        float lA = als[sA], lB = als[sB];
        uint2 uA = hv2[(size_t)sA * 32 + col];
        uint2 uB = hv2[(size_t)sB * 32 + col];
        float eA = __expf(leakyf(lA + ad));
        float eB = __expf(leakyf(lB + ad));
        den += eA + eB;
        ac.x = fmaf(eA, bf_lo(uA.x), ac.x); ac.y = fmaf(eA, bf_hi(uA.x), ac.y);
        ac.z = fmaf(eA, bf_lo(uA.y), ac.z); ac.w = fmaf(eA, bf_hi(uA.y), ac.w);
        ac.x = fmaf(eB, bf_lo(uB.x), ac.x); ac.y = fmaf(eB, bf_hi(uB.x), ac.y);
        ac.z = fmaf(eB, bf_lo(uB.y), ac.z); ac.w = fmaf(eB, bf_hi(uB.y), ac.w);
    }
    if (i + 2 <= e) {
        int sA = ss[i + half];
        float lA = als[sA];
        uint2 uA = hv2[(size_t)sA * 32 + col];
        float eA = __expf(leakyf(lA + ad));
        den += eA;
        ac.x = fmaf(eA, bf_lo(uA.x), ac.x); ac.y = fmaf(eA, bf_hi(uA.x), ac.y);
        ac.z = fmaf(eA, bf_lo(uA.y), ac.z); ac.w = fmaf(eA, bf_hi(uA.y), ac.w);
        i += 2;
    }
    if (i < e && half == 0) {        // odd tail: half 0 only
        int sA = ss[i];
        float lA = als[sA];
        uint2 uA = hv2[(size_t)sA * 32 + col];
        float eA = __expf(leakyf(lA + ad));
        den += eA;
        ac.x = fmaf(eA, bf_lo(uA.x), ac.x); ac.y = fmaf(eA, bf_hi(uA.x), ac.y);
        ac.z = fmaf(eA, bf_lo(uA.y), ac.z); ac.w = fmaf(eA, bf_hi(uA.y), ac.w);
    }
    den  += __shfl_xor(den, 32);
    ac.x += __shfl_xor(ac.x, 32); ac.y += __shfl_xor(ac.y, 32);
    ac.z += __shfl_xor(ac.z, 32); ac.w += __shfl_xor(ac.w, 32);
    float rden = 1.0f / (den + 1e-16f);
    return make_float4(ac.x * rden, ac.y * rden, ac.z * rden, ac.w * rden);
}

__device__ __forceinline__ float2 seg64p(const int* __restrict__ rp, const int* __restrict__ ss,
                                         const float* __restrict__ als,
                                         const uint32* __restrict__ hv,  // row = 32 uints (64 bf16)
                                         float ad, int d, int half, int col) {
    int s = rp[d], e = rp[d + 1];
    float den = 0.f, ax = 0.f, ay = 0.f;
    int i = s;
    for (; i + 4 <= e; i += 4) {
        int sA = ss[i + half];
        int sB = ss[i + 2 + half];
        float lA = als[sA], lB = als[sB];
        uint32 uA = hv[(size_t)sA * 32 + col];
        uint32 uB = hv[(size_t)sB * 32 + col];
        float eA = __expf(leakyf(lA + ad));
        float eB = __expf(leakyf(lB + ad));
        den += eA + eB;
        ax = fmaf(eA, bf_lo(uA), ax); ay = fmaf(eA, bf_hi(uA), ay);
        ax = fmaf(eB, bf_lo(uB), ax); ay = fmaf(eB, bf_hi(uB), ay);
    }
    if (i + 2 <= e) {
        int sA = ss[i + half];
        float lA = als[sA];
        uint32 uA = hv[(size_t)sA * 32 + col];
        float eA = __expf(leakyf(lA + ad));
        den += eA;
        ax = fmaf(eA, bf_lo(uA), ax); ay = fmaf(eA, bf_hi(uA), ay);
        i += 2;
    }
    if (i < e && half == 0) {
        int sA = ss[i];
        float lA = als[sA];
        uint32 uA = hv[(size_t)sA * 32 + col];
        float eA = __expf(leakyf(lA + ad));
        den += eA;
        ax = fmaf(eA, bf_lo(uA), ax); ay = fmaf(eA, bf_hi(uA), ay);
    }
    den += __shfl_xor(den, 32);
    ax  += __shfl_xor(ax, 32);
    ay  += __shfl_xor(ay, 32);
    float rden = 1.0f / (den + 1e-16f);
    return make_float2(ax * rden, ay * rden);
}

// ---------------- layer-1 agg + fused layer-2 al_dst; grid (12500, 2), 4 indep waves ----------------
__global__ __launch_bounds__(256) void agg1_sp(const int* __restrict__ rowptr_all,
                                               const int* __restrict__ srcs_all,
                                               const float* __restrict__ alsrc_all,
                                               float* __restrict__ aldst_all,
                                               const ushort16* __restrict__ hs_all,
                                               const float* __restrict__ b1,
                                               const float* __restrict__ wd2,
                                               float* __restrict__ h_item,
                                               float* __restrict__ h_user) {
    const int lane = threadIdx.x & 63;
    const int d = blockIdx.x * 4 + (threadIdx.x >> 6);
    if (d >= N_NODE) return;
    const int half = lane >> 5, col = lane & 31;
    const uint2* hv2 = reinterpret_cast<const uint2*>(hs_all);   // per-rel stride N*32 uint2
    if (blockIdx.y == 0) {           // item dst: relation 0
        float4 w = seg128p(rowptr_all, srcs_all, alsrc_all, hv2, aldst_all[d], d, half, col);
        float4 b = ((const float4*)b1)[col];
        float4 h = make_float4(w.x + b.x, w.y + b.y, w.z + b.z, w.w + b.w);
        if (half == 0) ((float4*)h_item)[(size_t)d * 32 + col] = h;
        // fused layer-2 al_dst (item): relu(h) . wd2[0]
        float4 v0 = ((const float4*)wd2)[col];
        float p = fmaxf(h.x, 0.f) * v0.x + fmaxf(h.y, 0.f) * v0.y
                + fmaxf(h.z, 0.f) * v0.z + fmaxf(h.w, 0.f) * v0.w;
        p += __shfl_xor(p, 16); p += __shfl_xor(p, 8);
        p += __shfl_xor(p, 4);  p += __shfl_xor(p, 2); p += __shfl_xor(p, 1);
        if (lane == 0) aldst_all[d] = p;
    } else {                         // user dst: relations 1 + 2 in one wave
        float4 w1 = seg128p(rowptr_all + (N_NODE + 1), srcs_all + NEDGE,
                            alsrc_all + N_NODE, hv2 + (size_t)N_NODE * 32,
                            aldst_all[N_NODE + d], d, half, col);
        float4 w2 = seg128p(rowptr_all + 2 * (N_NODE + 1), srcs_all + (size_t)2 * NEDGE,
                            alsrc_all + 2 * N_NODE, hv2 + (size_t)2 * N_NODE * 32,
                            aldst_all[2 * N_NODE + d], d, half, col);
        float4 bA = ((const float4*)(b1 + HIDD))[col];
        float4 bB = ((const float4*)(b1 + 2 * HIDD))[col];
        float4 h = make_float4(w1.x + w2.x + bA.x + bB.x, w1.y + w2.y + bA.y + bB.y,
                               w1.z + w2.z + bA.z + bB.z, w1.w + w2.w + bA.w + bB.w);
        if (half == 0) ((float4*)h_user)[(size_t)d * 32 + col] = h;
        float hx = fmaxf(h.x, 0.f), hy = fmaxf(h.y, 0.f);
        float hz = fmaxf(h.z, 0.f), hw = fmaxf(h.w, 0.f);
        float4 v1 = ((const float4*)(wd2 + HIDD))[col];
        float4 v2 = ((const float4*)(wd2 + 2 * HIDD))[col];
        float p1 = hx * v1.x + hy * v1.y + hz * v1.z + hw * v1.w;
        float p2 = hx * v2.x + hy * v2.y + hz * v2.z + hw * v2.w;
        p1 += __shfl_xor(p1, 16); p1 += __shfl_xor(p1, 8);
        p1 += __shfl_xor(p1, 4);  p1 += __shfl_xor(p1, 2); p1 += __shfl_xor(p1, 1);
        p2 += __shfl_xor(p2, 16); p2 += __shfl_xor(p2, 8);
        p2 += __shfl_xor(p2, 4);  p2 += __shfl_xor(p2, 2); p2 += __shfl_xor(p2, 1);
        if (lane == 0) {
            aldst_all[N_NODE + d]     = p1;
            aldst_all[2 * N_NODE + d] = p2;
        }
    }
}

// ---------------- layer-2 agg (C=64), paired edges ----------------
__global__ __launch_bounds__(256) void agg2_sp(const int* __restrict__ rowptr_all,
                                               const int* __restrict__ srcs_all,
                                               const float* __restrict__ alsrc_all,
                                               const float* __restrict__ aldst_all,
                                               const ushort16* __restrict__ hs_all,
                                               const float* __restrict__ b2,
                                               float* __restrict__ o_item,
                                               float* __restrict__ o_user) {
    const int lane = threadIdx.x & 63;
    const int d = blockIdx.x * 4 + (threadIdx.x >> 6);
    if (d >= N_NODE) return;
    const int half = lane >> 5, col = lane & 31;
    const uint32* hv = reinterpret_cast<const uint32*>(hs_all);  // per-rel stride N*32 uints
    if (blockIdx.y == 0) {
        float2 w = seg64p(rowptr_all, srcs_all, alsrc_all, hv, aldst_all[d], d, half, col);
        float2 b = ((const float2*)b2)[col];
        if (half == 0)
            ((float2*)o_item)[(size_t)d * 32 + col] = make_float2(w.x + b.x, w.y + b.y);
    } else {
        float2 w1 = seg64p(rowptr_all + (N_NODE + 1), srcs_all + NEDGE,
                           alsrc_all + N_NODE, hv + (size_t)N_NODE * 32,
                           aldst_all[N_NODE + d], d, half, col);
        float2 w2 = seg64p(rowptr_all + 2 * (N_NODE + 1), srcs_all + (size_t)2 * NEDGE,
                           alsrc_all + 2 * N_NODE, hv + (size_t)2 * N_NODE * 32,
                           aldst_all[2 * N_NODE + d], d, half, col);
        float2 bA = ((const float2*)(b2 + OUTD))[col];
        float2 bB = ((const float2*)(b2 + 2 * OUTD))[col];
        if (half == 0)
            ((float2*)o_user)[(size_t)d * 32 + col] =
                make_float2(w1.x + w2.x + bA.x + bB.x, w1.y + w2.y + bA.y + bB.y);
    }
}

// ---------------- bilinear edge scoring ----------------
__global__ void score_k(const int* __restrict__ e0, const int* __restrict__ e1,
                        const int* __restrict__ e2,
                        const float* __restrict__ o_user, const float* __restrict__ o_item,
                        const float* __restrict__ relw, float* __restrict__ out, int L) {
    int g    = blockIdx.x * 4 + (threadIdx.x >> 6);
    int lane = threadIdx.x & 63;
    int r = g / L, l = g - r * L;
    if (r >= 3) return;
    const int* ei = (r == 0) ? e0 : (r == 1) ? e1 : e2;
    int ai = ei[l];
    int bi = ei[L + l];
    const float* A = (r == 1) ? o_item : o_user;
    const float* B = (r == 0) ? o_item : o_user;
    float v = A[(size_t)ai * OUTD + lane] * relw[r * OUTD + lane] * B[(size_t)bi * OUTD + lane];
#pragma unroll
    for (int off = 32; off; off >>= 1) v += __shfl_xor(v, off);
    if (lane == 0) out[r * L + l] = v;
}

extern "C" void kernel_launch(void* const* d_in, const int* in_sizes, int n_in,
                              void* d_out, int out_size, void* d_ws, size_t ws_size,
                              hipStream_t stream) {
    const float* x_user = (const float*)d_in[0];
    const float* x_item = (const float*)d_in[1];
    const float* W1s = (const float*)d_in[2];
    const float* W1d = (const float*)d_in[3];
    const float* a1s = (const float*)d_in[4];
    const float* a1d = (const float*)d_in[5];
    const float* b1  = (const float*)d_in[6];
    const float* W2s = (const float*)d_in[7];
    const float* W2d = (const float*)d_in[8];
    const float* a2s = (const float*)d_in[9];
    const float* a2d = (const float*)d_in[10];
    const float* b2  = (const float*)d_in[11];
    const float* relw= (const float*)d_in[12];
    const int* ei0 = (const int*)d_in[13];
    const int* ei1 = (const int*)d_in[14];
    const int* ei2 = (const int*)d_in[15];
    const int* el0 = (const int*)d_in[16];
    const int* el1 = (const int*)d_in[17];
    const int* el2 = (const int*)d_in[18];
    float* out = (float*)d_out;
    (void)ws_size; (void)n_in; (void)in_sizes; (void)out_size;

    char* ws = (char*)d_ws;
    size_t off = 0;
    auto alloc = [&](size_t bytes) -> void* {
        void* p = ws + off;
        off = (off + bytes + 255) & ~(size_t)255;
        return p;
    };
    int*     rowptr_all = (int*)alloc((size_t)3 * (N_NODE + 1) * 4);
    int*     counts_all = (int*)alloc((size_t)3 * N_NODE * 4);
    int*     srcs_all   = (int*)alloc((size_t)3 * NEDGE * 4);
    int*     bsum       = (int*)alloc((size_t)3 * NBSC * 4);
    int*     bh         = (int*)alloc((size_t)3 * NB * NBP1 * 4);
    int*     bkbase     = (int*)alloc((size_t)3 * (NB + 1) * 4);
    int2*    bucketed   = (int2*)alloc((size_t)3 * NEDGE * 8);
    ushort16* hs_bf     = (ushort16*)alloc((size_t)3 * N_NODE * HIDD * 2);  // bf16; L2 reuses first 3*N*64
    float*   h_item1    = (float*)alloc((size_t)2 * N_NODE * HIDD * 4);     // fp32
    float*   h_user1    = h_item1 + (size_t)N_NODE * HIDD;
    float*   o_item     = (float*)alloc((size_t)N_NODE * OUTD * 4);
    float*   o_user     = (float*)alloc((size_t)N_NODE * OUTD * 4);
    float*   alsrc_all  = (float*)alloc((size_t)3 * N_NODE * 4);
    float*   aldst_all  = (float*)alloc((size_t)3 * N_NODE * 4);
    float*   wd1        = (float*)alloc(3 * FDIM * 4);
    float*   wd2        = (float*)alloc(3 * HIDD * 4);

    fold_wd<<<3, 128, 0, stream>>>(W1d, a1d, W2d, a2d, wd1, wd2);

    // ---- CSR build: two-level bucket partition ----
    part_hist<<<dim3(NBP1, 3), 256, 0, stream>>>(ei0, ei1, ei2, bh);
    part_scan<<<3, 256, 0, stream>>>(bh, bkbase);
    part_scatter<<<dim3(NBP1, 3), 256, 0, stream>>>(ei0, ei1, ei2, bh, bucketed);
    bucket_count<<<dim3(NB, 3), 256, 0, stream>>>(bucketed, bkbase, counts_all);
    scan1<<<dim3(NBSC, 3), 256, 0, stream>>>(counts_all, bsum);
    scan3<<<dim3(NBSC, 3), 256, 0, stream>>>(counts_all, rowptr_all, bsum);
    bucket_scatter<<<dim3(NB, 3), 256, 0, stream>>>(bucketed, bkbase, rowptr_all, srcs_all);

    const int ag = (N_NODE + 3) / 4;

    // ---- layer 1 (gemm also writes layer-1 al_dst via fused A-staging dot) ----
    gemm3<64, 128, false, true><<<dim3((N_NODE + 63) / 64, 3), 128, 0, stream>>>(
        x_user, x_item, x_user, W1s, a1s, hs_bf, alsrc_all, wd1, aldst_all, N_NODE);
    // agg1 also writes layer-2 al_dst into aldst_all in-place (per-block read-then-write)
    agg1_sp<<<dim3(ag, 2), 256, 0, stream>>>(rowptr_all, srcs_all, alsrc_all, aldst_all,
                                             hs_bf, b1, wd2, h_item1, h_user1);

    // ---- layer 2 (ReLU folded into gemm A-staging; hs_bf overwrite safe: L1 hs consumed) ----
    gemm3<128, 64, true, false><<<dim3((N_NODE + 127) / 128, 3), 128, 0, stream>>>(
        h_user1, h_item1, h_user1, W2s, a2s, hs_bf, alsrc_all, wd2, aldst_all, N_NODE);
    agg2_sp<<<dim3(ag, 2), 256, 0, stream>>>(rowptr_all, srcs_all, alsrc_all, aldst_all,
                                             hs_bf, b2, o_item, o_user);

    // ---- scoring ----
    score_k<<<(3 * NL + 3) / 4, 256, 0, stream>>>(el0, el1, el2, o_user, o_item, relw, out, NL);
}

// Round 13
// 331.663 us; speedup vs baseline: 1.4649x; 1.2332x over previous
//
#include <hip/hip_runtime.h>
#include <cstdint>
#include <cstddef>

#define N_NODE 50000
#define NEDGE  500000
#define NL     100000
#define FDIM   128
#define HIDD   128
#define OUTD   64
#define NBSC   98        // ceil(N_NODE / 512) for rowptr scan
#define NB     49        // buckets = ceil(50000 / 1024), bucket = dst >> 10
#define BCH    8192      // edges per partition block
#define NBP1   62        // ceil(NEDGE / BCH)

typedef unsigned int uint32;
typedef unsigned short ushort16;
typedef __attribute__((ext_vector_type(8))) short bf16x8;
typedef __attribute__((ext_vector_type(4))) float f32x4;

__device__ __forceinline__ float leakyf(float x) { return x > 0.f ? x : 0.2f * x; }

// round-to-nearest-even f32 -> bf16
__device__ __forceinline__ uint32 bf16r(float x) {
    uint32 u = __float_as_uint(x);
    return (u + 0x7fffu + ((u >> 16) & 1u)) >> 16;
}
__device__ __forceinline__ float bf_lo(uint32 u) { return __uint_as_float(u << 16); }
__device__ __forceinline__ float bf_hi(uint32 u) { return __uint_as_float(u & 0xffff0000u); }

// ---------------- fold Wd @ a_d -> per-relation length-128 vectors ----------------
__global__ void fold_wd(const float* __restrict__ W1d, const float* __restrict__ a1d,
                        const float* __restrict__ W2d, const float* __restrict__ a2d,
                        float* __restrict__ wd1, float* __restrict__ wd2) {
    int r = blockIdx.x;          // 3 relations
    int f = threadIdx.x;         // 128
    const float* w  = W1d + ((size_t)r * FDIM + f) * HIDD;
    const float* a  = a1d + r * HIDD;
    float s = 0.f;
    for (int h = 0; h < HIDD; ++h) s += w[h] * a[h];
    wd1[r * FDIM + f] = s;
    const float* w2 = W2d + ((size_t)r * HIDD + f) * OUTD;
    const float* a2 = a2d + r * OUTD;
    float s2 = 0.f;
    for (int o = 0; o < OUTD; ++o) s2 += w2[o] * a2[o];
    wd2[r * HIDD + f] = s2;
}

// ---------------- W -> WT bf16 transpose: WT[r][n][k] = bf16(W[r][k][n]) ----------------
__global__ void wt_k(const float* __restrict__ W1s, const float* __restrict__ W2s,
                     ushort16* __restrict__ WT1, ushort16* __restrict__ WT2) {
    int idx = blockIdx.x * 256 + threadIdx.x;
    if (blockIdx.y == 0) {
        if (idx < 3 * FDIM * HIDD) {
            int k = idx & 127, n = (idx >> 7) & 127, r = idx >> 14;
            WT1[idx] = (ushort16)bf16r(W1s[((size_t)r * FDIM + k) * HIDD + n]);
        }
    } else {
        if (idx < 3 * HIDD * OUTD) {
            int k = idx & 127, n = (idx >> 7) & 63, r = idx >> 13;
            WT2[idx] = (ushort16)bf16r(W2s[((size_t)r * HIDD + k) * OUTD + n]);
        }
    }
}

// ================= CSR build: two-level bucket partition (write-locality) =================

__global__ __launch_bounds__(256) void part_hist(const int* __restrict__ e0,
                                                 const int* __restrict__ e1,
                                                 const int* __restrict__ e2,
                                                 int* __restrict__ bh) {
    int r = blockIdx.y, t = threadIdx.x;
    const int* ei  = (r == 0) ? e0 : (r == 1) ? e1 : e2;
    const int* dst = ei + NEDGE;
    __shared__ int lh[NB];
    if (t < NB) lh[t] = 0;
    __syncthreads();
    int base = blockIdx.x * BCH;
    int lim  = base + BCH; if (lim > NEDGE) lim = NEDGE;
    for (int i = base + t; i < lim; i += 256)
        atomicAdd(&lh[dst[i] >> 10], 1);
    __syncthreads();
    if (t < NB) bh[((size_t)r * NB + t) * NBP1 + blockIdx.x] = lh[t];
}

__global__ __launch_bounds__(256) void part_scan(int* __restrict__ bh,
                                                 int* __restrict__ bkbase) {
    int r = blockIdx.x, t = threadIdx.x;
    int* a = bh + (size_t)r * NB * NBP1;
    const int n = NB * NBP1;                 // 3038
    const int per = (n + 255) / 256;         // 12
    int lo = t * per, hi = lo + per; if (hi > n) hi = n;
    int s = 0;
    for (int i = lo; i < hi; ++i) s += a[i];
    __shared__ int sm[256];
    sm[t] = s;
    __syncthreads();
    for (int off = 1; off < 256; off <<= 1) {
        int x = (t >= off) ? sm[t - off] : 0;
        __syncthreads();
        sm[t] += x;
        __syncthreads();
    }
    int run = sm[t] - s;
    for (int i = lo; i < hi; ++i) { int c = a[i]; a[i] = run; run += c; }
    __syncthreads();
    if (t < NB) bkbase[r * (NB + 1) + t] = a[t * NBP1];
    if (t == NB) bkbase[r * (NB + 1) + NB] = NEDGE;
}

__global__ __launch_bounds__(256) void part_scatter(const int* __restrict__ e0,
                                                    const int* __restrict__ e1,
                                                    const int* __restrict__ e2,
                                                    const int* __restrict__ bh,
                                                    int2* __restrict__ bucketed) {
    int r = blockIdx.y, t = threadIdx.x;
    const int* ei  = (r == 0) ? e0 : (r == 1) ? e1 : e2;
    const int* dst = ei + NEDGE;
    __shared__ int cur[NB];
    if (t < NB) cur[t] = bh[((size_t)r * NB + t) * NBP1 + blockIdx.x];
    __syncthreads();
    int2* bk = bucketed + (size_t)r * NEDGE;
    int base = blockIdx.x * BCH;
    int lim  = base + BCH; if (lim > NEDGE) lim = NEDGE;
    for (int i = base + t; i < lim; i += 256) {
        int d = dst[i], s_ = ei[i];
        int pos = atomicAdd(&cur[d >> 10], 1);      // LDS atomic, global position
        bk[pos] = make_int2(s_, d);
    }
}

__global__ __launch_bounds__(256) void bucket_count(const int2* __restrict__ bucketed,
                                                    const int* __restrict__ bkbase,
                                                    int* __restrict__ counts_all) {
    int r = blockIdx.y, k = blockIdx.x, t = threadIdx.x;
    int s0 = bkbase[r * (NB + 1) + k], s1 = bkbase[r * (NB + 1) + k + 1];
    __shared__ int lh[1024];
#pragma unroll
    for (int i = 0; i < 4; ++i) lh[t + i * 256] = 0;
    __syncthreads();
    const int2* bk = bucketed + (size_t)r * NEDGE;
    for (int i = s0 + t; i < s1; i += 256)
        atomicAdd(&lh[bk[i].y & 1023], 1);
    __syncthreads();
    int gbase = k << 10;
    int* cnt = counts_all + (size_t)r * N_NODE;
#pragma unroll
    for (int i = 0; i < 4; ++i) {
        int idx = t + i * 256;
        if (gbase + idx < N_NODE) cnt[gbase + idx] = lh[idx];
    }
}

__global__ __launch_bounds__(256) void scan1(const int* __restrict__ counts_all,
                                             int* __restrict__ bsum) {
    int r = blockIdx.y, b = blockIdx.x, t = threadIdx.x;
    int base = b * 512;
    int lim = N_NODE - base; if (lim > 512) lim = 512;
    const int* c = counts_all + (size_t)r * N_NODE + base;
    int v0 = (2 * t     < lim) ? c[2 * t]     : 0;
    int v1 = (2 * t + 1 < lim) ? c[2 * t + 1] : 0;
    __shared__ int sm[256];
    sm[t] = v0 + v1;
    __syncthreads();
    for (int off = 128; off; off >>= 1) {
        if (t < off) sm[t] += sm[t + off];
        __syncthreads();
    }
    if (t == 0) bsum[r * NBSC + b] = sm[0];
}

__global__ __launch_bounds__(256) void scan3(const int* __restrict__ counts_all,
                                             int* __restrict__ rowptr_all,
                                             const int* __restrict__ bsum) {
    int r = blockIdx.y, b = blockIdx.x, t = threadIdx.x;
    __shared__ int sm[256];
    sm[t] = (t < b) ? bsum[r * NBSC + t] : 0;
    __syncthreads();
    for (int off = 128; off; off >>= 1) {
        if (t < off) sm[t] += sm[t + off];
        __syncthreads();
    }
    int boff = sm[0];
    __syncthreads();

    int base = b * 512;
    int lim = N_NODE - base; if (lim > 512) lim = 512;
    const int* c = counts_all + (size_t)r * N_NODE;
    int* rp = rowptr_all + (size_t)r * (N_NODE + 1);
    int i0 = base + 2 * t, i1 = i0 + 1;
    int v0 = (2 * t     < lim) ? c[i0] : 0;
    int v1 = (2 * t + 1 < lim) ? c[i1] : 0;
    int ps = v0 + v1;
    sm[t] = ps;
    __syncthreads();
    for (int off = 1; off < 256; off <<= 1) {
        int x = (t >= off) ? sm[t - off] : 0;
        __syncthreads();
        sm[t] += x;
        __syncthreads();
    }
    int excl = sm[t] - ps + boff;
    if (2 * t < lim)     rp[i0] = excl;
    if (2 * t + 1 < lim) rp[i1] = excl + v0;
    if (b == 0 && t == 0) rp[N_NODE] = NEDGE;
}

__global__ __launch_bounds__(256) void bucket_scatter(const int2* __restrict__ bucketed,
                                                      const int* __restrict__ bkbase,
                                                      const int* __restrict__ rowptr_all,
                                                      int* __restrict__ srcs_all) {
    int r = blockIdx.y, k = blockIdx.x, t = threadIdx.x;
    int s0 = bkbase[r * (NB + 1) + k], s1 = bkbase[r * (NB + 1) + k + 1];
    int gbase = k << 10;
    const int* rp = rowptr_all + (size_t)r * (N_NODE + 1);
    __shared__ int cur[1024];
#pragma unroll
    for (int i = 0; i < 4; ++i) {
        int idx = t + i * 256;
        cur[idx] = (gbase + idx < N_NODE) ? rp[gbase + idx] : 0;
    }
    __syncthreads();
    const int2* bk = bucketed + (size_t)r * NEDGE;
    int* out = srcs_all + (size_t)r * NEDGE;
    for (int i = s0 + t; i < s1; i += 256) {
        int2 e = bk[i];
        int pos = atomicAdd(&cur[e.y & 1023], 1);   // LDS atomic
        out[pos] = e.x;                              // write confined to bucket's CSR range
    }
}

// ========== MFMA GEMM: C[M x BN](bf16) = A[M x 128](fp32->bf16) @ WT^T, fused epilogues ==========
// 256 thr = 4 waves; block = 64 rows x BN cols; wave = 16 rows (mfma_f32_16x16x32_bf16).
// LDS XOR swizzle byte ^= (row&7)<<4 on both A and B^T tiles (conflict-free ds_read_b128).
// Fragment layouts (gfx950, guide-verified): A lane: row=l&15, k=(l>>4)*8+j; B lane: col=l&15,
// same k; D: col=lane&15, row=(lane>>4)*4+reg.
template <int BN, bool RELU, bool DOT>
__global__ __launch_bounds__(256) void gemm_mfma(const float* __restrict__ A0,
                                                 const float* __restrict__ A1,
                                                 const float* __restrict__ A2,
                                                 const ushort16* __restrict__ WTbase, // [r][BN][128] bf16
                                                 const float* __restrict__ avec_base,
                                                 ushort16* __restrict__ Cbase,
                                                 float* __restrict__ al_base,
                                                 const float* __restrict__ wdvec,
                                                 float* __restrict__ adst_base, int M) {
    constexpr int K = 128;
    __shared__ ushort16 aslds[64 * K];     // 16 KB
    __shared__ ushort16 bslds[BN * K];     // 32/16 KB
    const int r = blockIdx.y;
    const float* A = (r == 0) ? A0 : (r == 1) ? A1 : A2;
    const int t    = threadIdx.x;
    const int lane = t & 63;
    const int w    = t >> 6;
    const int m0   = blockIdx.x * 64;

    // ---- stage B^T (bf16 global, coalesced 16B) with XOR swizzle ----
    {
        const uint4* src = reinterpret_cast<const uint4*>(WTbase + (size_t)r * BN * K);
        char* bb = reinterpret_cast<char*>(bslds);
#pragma unroll
        for (int i = t; i < BN * 16; i += 256) {
            int n = i >> 4, c16 = i & 15;
            uint32 off = (uint32)(n * 256 + c16 * 16) ^ (uint32)((n & 7) << 4);
            *reinterpret_cast<uint4*>(bb + off) = src[i];
        }
    }
    // ---- stage A tile: fp32 -> bf16, swizzled; optional fused DOT (layer-1 al_dst) ----
    const float4* A4 = reinterpret_cast<const float4*>(A);
    const int mr = (r == 0) ? 1 : (r == 1) ? 0 : 2;
    const float* wdot = wdvec + mr * K;
    char* ab = reinterpret_cast<char*>(aslds);
    float dp[8];
#pragma unroll
    for (int i = 0; i < 8; ++i) dp[i] = 0.f;
#pragma unroll
    for (int i = 0; i < 8; ++i) {
        int idx = t + i * 256;              // 2048 float4 = 64 rows x 32
        int row = idx >> 5, kq = idx & 31;
        float4 v = make_float4(0.f, 0.f, 0.f, 0.f);
        if (m0 + row < M) {
            v = A4[(size_t)(m0 + row) * 32 + kq];
            if (RELU) {
                v.x = fmaxf(v.x, 0.f); v.y = fmaxf(v.y, 0.f);
                v.z = fmaxf(v.z, 0.f); v.w = fmaxf(v.w, 0.f);
            }
        }
        if (DOT) {
            float4 wv = *reinterpret_cast<const float4*>(&wdot[kq * 4]);
            dp[i] = fmaf(v.x, wv.x, dp[i]); dp[i] = fmaf(v.y, wv.y, dp[i]);
            dp[i] = fmaf(v.z, wv.z, dp[i]); dp[i] = fmaf(v.w, wv.w, dp[i]);
        }
        uint2 p;
        p.x = bf16r(v.x) | (bf16r(v.y) << 16);
        p.y = bf16r(v.z) | (bf16r(v.w) << 16);
        uint32 off = (uint32)(row * 256 + kq * 8) ^ (uint32)((row & 7) << 4);
        *reinterpret_cast<uint2*>(ab + off) = p;
    }
    if (DOT) {   // reduce dp across the 32 threads sharing a row (within 32-lane halves)
        float* adst = adst_base + (size_t)mr * M;
#pragma unroll
        for (int i = 0; i < 8; ++i) {
            float p = dp[i];
            p += __shfl_xor(p, 16); p += __shfl_xor(p, 8); p += __shfl_xor(p, 4);
            p += __shfl_xor(p, 2);  p += __shfl_xor(p, 1);
            int row = (t + i * 256) >> 5;
            if ((t & 31) == 0 && m0 + row < M) adst[m0 + row] = p;
        }
    }
    __syncthreads();

    // ---- MFMA main: wave w -> rows m0+w*16..+15, all BN cols ----
    const int col0 = lane & 15;
    const int kgrp = lane >> 4;          // 0..3
    const int arow = w * 16 + col0;
    bf16x8 afrag[4];
#pragma unroll
    for (int ks = 0; ks < 4; ++ks) {
        uint32 off = (uint32)(arow * 256 + ks * 64 + kgrp * 16) ^ (uint32)((arow & 7) << 4);
        afrag[ks] = *reinterpret_cast<const bf16x8*>(ab + off);
    }
    constexpr int NT = BN / 16;
    f32x4 acc[NT];
#pragma unroll
    for (int n = 0; n < NT; ++n) acc[n] = (f32x4){0.f, 0.f, 0.f, 0.f};
    const char* bb = reinterpret_cast<const char*>(bslds);
#pragma unroll
    for (int n = 0; n < NT; ++n) {
        int bcol = n * 16 + col0;
        uint32 xw = (uint32)((bcol & 7) << 4);
#pragma unroll
        for (int ks = 0; ks < 4; ++ks) {
            uint32 off = (uint32)(bcol * 256 + ks * 64 + kgrp * 16) ^ xw;
            bf16x8 bfrag = *reinterpret_cast<const bf16x8*>(bb + off);
            acc[n] = __builtin_amdgcn_mfma_f32_16x16x32_bf16(afrag[ks], bfrag, acc[n], 0, 0, 0);
        }
    }

    // ---- epilogue: bf16 C-store + fused al_src (fp32 acc) ----
    ushort16* C = Cbase + (size_t)r * M * BN;
    const float* av = avec_base + r * BN;
    const int rbase = m0 + w * 16 + kgrp * 4;
    float p4[4] = {0.f, 0.f, 0.f, 0.f};
#pragma unroll
    for (int n = 0; n < NT; ++n) {
        float asv = av[n * 16 + col0];
#pragma unroll
        for (int reg = 0; reg < 4; ++reg) {
            int rr = rbase + reg;
            if (rr < M) C[(size_t)rr * BN + n * 16 + col0] = (ushort16)bf16r(acc[n][reg]);
            p4[reg] = fmaf(acc[n][reg], asv, p4[reg]);
        }
    }
    float* al = al_base + (size_t)r * M;
#pragma unroll
    for (int reg = 0; reg < 4; ++reg) {
        float q = p4[reg];
        q += __shfl_xor(q, 1); q += __shfl_xor(q, 2);
        q += __shfl_xor(q, 4); q += __shfl_xor(q, 8);
        int rr = rbase + reg;
        if (col0 == 0 && rr < M) al[rr] = q;
    }
}

// ------- paired-edge single-pass softmax-aggregate helpers -------
__device__ __forceinline__ float4 seg128p(const int* __restrict__ rp, const int* __restrict__ ss,
                                          const float* __restrict__ als,
                                          const uint2* __restrict__ hv2,
                                          float ad, int d, int half, int col) {
    int s = rp[d], e = rp[d + 1];
    float den = 0.f;
    float4 ac = make_float4(0.f, 0.f, 0.f, 0.f);
    int i = s;
    for (; i + 4 <= e; i += 4) {
        int sA = ss[i + half];
        int sB = ss[i + 2 + half];
        float lA = als[sA], lB = als[sB];
        uint2 uA = hv2[(size_t)sA * 32 + col];
        uint2 uB = hv2[(size_t)sB * 32 + col];
        float eA = __expf(leakyf(lA + ad));
        float eB = __expf(leakyf(lB + ad));
        den += eA + eB;
        ac.x = fmaf(eA, bf_lo(uA.x), ac.x); ac.y = fmaf(eA, bf_hi(uA.x), ac.y);
        ac.z = fmaf(eA, bf_lo(uA.y), ac.z); ac.w = fmaf(eA, bf_hi(uA.y), ac.w);
        ac.x = fmaf(eB, bf_lo(uB.x), ac.x); ac.y = fmaf(eB, bf_hi(uB.x), ac.y);
        ac.z = fmaf(eB, bf_lo(uB.y), ac.z); ac.w = fmaf(eB, bf_hi(uB.y), ac.w);
    }
    if (i + 2 <= e) {
        int sA = ss[i + half];
        float lA = als[sA];
        uint2 uA = hv2[(size_t)sA * 32 + col];
        float eA = __expf(leakyf(lA + ad));
        den += eA;
        ac.x = fmaf(eA, bf_lo(uA.x), ac.x); ac.y = fmaf(eA, bf_hi(uA.x), ac.y);
        ac.z = fmaf(eA, bf_lo(uA.y), ac.z); ac.w = fmaf(eA, bf_hi(uA.y), ac.w);
        i += 2;
    }
    if (i < e && half == 0) {
        int sA = ss[i];
        float lA = als[sA];
        uint2 uA = hv2[(size_t)sA * 32 + col];
        float eA = __expf(leakyf(lA + ad));
        den += eA;
        ac.x = fmaf(eA, bf_lo(uA.x), ac.x); ac.y = fmaf(eA, bf_hi(uA.x), ac.y);
        ac.z = fmaf(eA, bf_lo(uA.y), ac.z); ac.w = fmaf(eA, bf_hi(uA.y), ac.w);
    }
    den  += __shfl_xor(den, 32);
    ac.x += __shfl_xor(ac.x, 32); ac.y += __shfl_xor(ac.y, 32);
    ac.z += __shfl_xor(ac.z, 32); ac.w += __shfl_xor(ac.w, 32);
    float rden = 1.0f / (den + 1e-16f);
    return make_float4(ac.x * rden, ac.y * rden, ac.z * rden, ac.w * rden);
}

__device__ __forceinline__ float2 seg64p(const int* __restrict__ rp, const int* __restrict__ ss,
                                         const float* __restrict__ als,
                                         const uint32* __restrict__ hv,
                                         float ad, int d, int half, int col) {
    int s = rp[d], e = rp[d + 1];
    float den = 0.f, ax = 0.f, ay = 0.f;
    int i = s;
    for (; i + 4 <= e; i += 4) {
        int sA = ss[i + half];
        int sB = ss[i + 2 + half];
        float lA = als[sA], lB = als[sB];
        uint32 uA = hv[(size_t)sA * 32 + col];
        uint32 uB = hv[(size_t)sB * 32 + col];
        float eA = __expf(leakyf(lA + ad));
        float eB = __expf(leakyf(lB + ad));
        den += eA + eB;
        ax = fmaf(eA, bf_lo(uA), ax); ay = fmaf(eA, bf_hi(uA), ay);
        ax = fmaf(eB, bf_lo(uB), ax); ay = fmaf(eB, bf_hi(uB), ay);
    }
    if (i + 2 <= e) {
        int sA = ss[i + half];
        float lA = als[sA];
        uint32 uA = hv[(size_t)sA * 32 + col];
        float eA = __expf(leakyf(lA + ad));
        den += eA;
        ax = fmaf(eA, bf_lo(uA), ax); ay = fmaf(eA, bf_hi(uA), ay);
        i += 2;
    }
    if (i < e && half == 0) {
        int sA = ss[i];
        float lA = als[sA];
        uint32 uA = hv[(size_t)sA * 32 + col];
        float eA = __expf(leakyf(lA + ad));
        den += eA;
        ax = fmaf(eA, bf_lo(uA), ax); ay = fmaf(eA, bf_hi(uA), ay);
    }
    den += __shfl_xor(den, 32);
    ax  += __shfl_xor(ax, 32);
    ay  += __shfl_xor(ay, 32);
    float rden = 1.0f / (den + 1e-16f);
    return make_float2(ax * rden, ay * rden);
}

// ---------------- layer-1 agg + fused layer-2 al_dst; grid (12500, 2), 4 indep waves ----------------
__global__ __launch_bounds__(256) void agg1_sp(const int* __restrict__ rowptr_all,
                                               const int* __restrict__ srcs_all,
                                               const float* __restrict__ alsrc_all,
                                               float* __restrict__ aldst_all,
                                               const ushort16* __restrict__ hs_all,
                                               const float* __restrict__ b1,
                                               const float* __restrict__ wd2,
                                               float* __restrict__ h_item,
                                               float* __restrict__ h_user) {
    const int lane = threadIdx.x & 63;
    const int d = blockIdx.x * 4 + (threadIdx.x >> 6);
    if (d >= N_NODE) return;
    const int half = lane >> 5, col = lane & 31;
    const uint2* hv2 = reinterpret_cast<const uint2*>(hs_all);
    if (blockIdx.y == 0) {           // item dst: relation 0
        float4 w = seg128p(rowptr_all, srcs_all, alsrc_all, hv2, aldst_all[d], d, half, col);
        float4 b = ((const float4*)b1)[col];
        float4 h = make_float4(w.x + b.x, w.y + b.y, w.z + b.z, w.w + b.w);
        if (half == 0) ((float4*)h_item)[(size_t)d * 32 + col] = h;
        float4 v0 = ((const float4*)wd2)[col];
        float p = fmaxf(h.x, 0.f) * v0.x + fmaxf(h.y, 0.f) * v0.y
                + fmaxf(h.z, 0.f) * v0.z + fmaxf(h.w, 0.f) * v0.w;
        p += __shfl_xor(p, 16); p += __shfl_xor(p, 8);
        p += __shfl_xor(p, 4);  p += __shfl_xor(p, 2); p += __shfl_xor(p, 1);
        if (lane == 0) aldst_all[d] = p;
    } else {                         // user dst: relations 1 + 2 in one wave
        float4 w1 = seg128p(rowptr_all + (N_NODE + 1), srcs_all + NEDGE,
                            alsrc_all + N_NODE, hv2 + (size_t)N_NODE * 32,
                            aldst_all[N_NODE + d], d, half, col);
        float4 w2 = seg128p(rowptr_all + 2 * (N_NODE + 1), srcs_all + (size_t)2 * NEDGE,
                            alsrc_all + 2 * N_NODE, hv2 + (size_t)2 * N_NODE * 32,
                            aldst_all[2 * N_NODE + d], d, half, col);
        float4 bA = ((const float4*)(b1 + HIDD))[col];
        float4 bB = ((const float4*)(b1 + 2 * HIDD))[col];
        float4 h = make_float4(w1.x + w2.x + bA.x + bB.x, w1.y + w2.y + bA.y + bB.y,
                               w1.z + w2.z + bA.z + bB.z, w1.w + w2.w + bA.w + bB.w);
        if (half == 0) ((float4*)h_user)[(size_t)d * 32 + col] = h;
        float hx = fmaxf(h.x, 0.f), hy = fmaxf(h.y, 0.f);
        float hz = fmaxf(h.z, 0.f), hw = fmaxf(h.w, 0.f);
        float4 v1 = ((const float4*)(wd2 + HIDD))[col];
        float4 v2 = ((const float4*)(wd2 + 2 * HIDD))[col];
        float p1 = hx * v1.x + hy * v1.y + hz * v1.z + hw * v1.w;
        float p2 = hx * v2.x + hy * v2.y + hz * v2.z + hw * v2.w;
        p1 += __shfl_xor(p1, 16); p1 += __shfl_xor(p1, 8);
        p1 += __shfl_xor(p1, 4);  p1 += __shfl_xor(p1, 2); p1 += __shfl_xor(p1, 1);
        p2 += __shfl_xor(p2, 16); p2 += __shfl_xor(p2, 8);
        p2 += __shfl_xor(p2, 4);  p2 += __shfl_xor(p2, 2); p2 += __shfl_xor(p2, 1);
        if (lane == 0) {
            aldst_all[N_NODE + d]     = p1;
            aldst_all[2 * N_NODE + d] = p2;
        }
    }
}

// ---------------- layer-2 agg (C=64), paired edges ----------------
__global__ __launch_bounds__(256) void agg2_sp(const int* __restrict__ rowptr_all,
                                               const int* __restrict__ srcs_all,
                                               const float* __restrict__ alsrc_all,
                                               const float* __restrict__ aldst_all,
                                               const ushort16* __restrict__ hs_all,
                                               const float* __restrict__ b2,
                                               float* __restrict__ o_item,
                                               float* __restrict__ o_user) {
    const int lane = threadIdx.x & 63;
    const int d = blockIdx.x * 4 + (threadIdx.x >> 6);
    if (d >= N_NODE) return;
    const int half = lane >> 5, col = lane & 31;
    const uint32* hv = reinterpret_cast<const uint32*>(hs_all);
    if (blockIdx.y == 0) {
        float2 w = seg64p(rowptr_all, srcs_all, alsrc_all, hv, aldst_all[d], d, half, col);
        float2 b = ((const float2*)b2)[col];
        if (half == 0)
            ((float2*)o_item)[(size_t)d * 32 + col] = make_float2(w.x + b.x, w.y + b.y);
    } else {
        float2 w1 = seg64p(rowptr_all + (N_NODE + 1), srcs_all + NEDGE,
                           alsrc_all + N_NODE, hv + (size_t)N_NODE * 32,
                           aldst_all[N_NODE + d], d, half, col);
        float2 w2 = seg64p(rowptr_all + 2 * (N_NODE + 1), srcs_all + (size_t)2 * NEDGE,
                           alsrc_all + 2 * N_NODE, hv + (size_t)2 * N_NODE * 32,
                           aldst_all[2 * N_NODE + d], d, half, col);
        float2 bA = ((const float2*)(b2 + OUTD))[col];
        float2 bB = ((const float2*)(b2 + 2 * OUTD))[col];
        if (half == 0)
            ((float2*)o_user)[(size_t)d * 32 + col] =
                make_float2(w1.x + w2.x + bA.x + bB.x, w1.y + w2.y + bA.y + bB.y);
    }
}

// ---------------- bilinear edge scoring ----------------
__global__ void score_k(const int* __restrict__ e0, const int* __restrict__ e1,
                        const int* __restrict__ e2,
                        const float* __restrict__ o_user, const float* __restrict__ o_item,
                        const float* __restrict__ relw, float* __restrict__ out, int L) {
    int g    = blockIdx.x * 4 + (threadIdx.x >> 6);
    int lane = threadIdx.x & 63;
    int r = g / L, l = g - r * L;
    if (r >= 3) return;
    const int* ei = (r == 0) ? e0 : (r == 1) ? e1 : e2;
    int ai = ei[l];
    int bi = ei[L + l];
    const float* A = (r == 1) ? o_item : o_user;
    const float* B = (r == 0) ? o_item : o_user;
    float v = A[(size_t)ai * OUTD + lane] * relw[r * OUTD + lane] * B[(size_t)bi * OUTD + lane];
#pragma unroll
    for (int off = 32; off; off >>= 1) v += __shfl_xor(v, off);
    if (lane == 0) out[r * L + l] = v;
}

extern "C" void kernel_launch(void* const* d_in, const int* in_sizes, int n_in,
                              void* d_out, int out_size, void* d_ws, size_t ws_size,
                              hipStream_t stream) {
    const float* x_user = (const float*)d_in[0];
    const float* x_item = (const float*)d_in[1];
    const float* W1s = (const float*)d_in[2];
    const float* W1d = (const float*)d_in[3];
    const float* a1s = (const float*)d_in[4];
    const float* a1d = (const float*)d_in[5];
    const float* b1  = (const float*)d_in[6];
    const float* W2s = (const float*)d_in[7];
    const float* W2d = (const float*)d_in[8];
    const float* a2s = (const float*)d_in[9];
    const float* a2d = (const float*)d_in[10];
    const float* b2  = (const float*)d_in[11];
    const float* relw= (const float*)d_in[12];
    const int* ei0 = (const int*)d_in[13];
    const int* ei1 = (const int*)d_in[14];
    const int* ei2 = (const int*)d_in[15];
    const int* el0 = (const int*)d_in[16];
    const int* el1 = (const int*)d_in[17];
    const int* el2 = (const int*)d_in[18];
    float* out = (float*)d_out;
    (void)ws_size; (void)n_in; (void)in_sizes; (void)out_size;

    char* ws = (char*)d_ws;
    size_t off = 0;
    auto alloc = [&](size_t bytes) -> void* {
        void* p = ws + off;
        off = (off + bytes + 255) & ~(size_t)255;
        return p;
    };
    int*     rowptr_all = (int*)alloc((size_t)3 * (N_NODE + 1) * 4);
    int*     counts_all = (int*)alloc((size_t)3 * N_NODE * 4);
    int*     srcs_all   = (int*)alloc((size_t)3 * NEDGE * 4);
    int*     bsum       = (int*)alloc((size_t)3 * NBSC * 4);
    int*     bh         = (int*)alloc((size_t)3 * NB * NBP1 * 4);
    int*     bkbase     = (int*)alloc((size_t)3 * (NB + 1) * 4);
    int2*    bucketed   = (int2*)alloc((size_t)3 * NEDGE * 8);
    ushort16* hs_bf     = (ushort16*)alloc((size_t)3 * N_NODE * HIDD * 2);  // bf16
    ushort16* WT1       = (ushort16*)alloc((size_t)3 * HIDD * FDIM * 2);    // [r][n][k] bf16
    ushort16* WT2       = (ushort16*)alloc((size_t)3 * OUTD * HIDD * 2);
    float*   h_item1    = (float*)alloc((size_t)2 * N_NODE * HIDD * 4);     // fp32
    float*   h_user1    = h_item1 + (size_t)N_NODE * HIDD;
    float*   o_item     = (float*)alloc((size_t)N_NODE * OUTD * 4);
    float*   o_user     = (float*)alloc((size_t)N_NODE * OUTD * 4);
    float*   alsrc_all  = (float*)alloc((size_t)3 * N_NODE * 4);
    float*   aldst_all  = (float*)alloc((size_t)3 * N_NODE * 4);
    float*   wd1        = (float*)alloc(3 * FDIM * 4);
    float*   wd2        = (float*)alloc(3 * HIDD * 4);

    fold_wd<<<3, 128, 0, stream>>>(W1d, a1d, W2d, a2d, wd1, wd2);
    wt_k<<<dim3(192, 2), 256, 0, stream>>>(W1s, W2s, WT1, WT2);

    // ---- CSR build: two-level bucket partition ----
    part_hist<<<dim3(NBP1, 3), 256, 0, stream>>>(ei0, ei1, ei2, bh);
    part_scan<<<3, 256, 0, stream>>>(bh, bkbase);
    part_scatter<<<dim3(NBP1, 3), 256, 0, stream>>>(ei0, ei1, ei2, bh, bucketed);
    bucket_count<<<dim3(NB, 3), 256, 0, stream>>>(bucketed, bkbase, counts_all);
    scan1<<<dim3(NBSC, 3), 256, 0, stream>>>(counts_all, bsum);
    scan3<<<dim3(NBSC, 3), 256, 0, stream>>>(counts_all, rowptr_all, bsum);
    bucket_scatter<<<dim3(NB, 3), 256, 0, stream>>>(bucketed, bkbase, rowptr_all, srcs_all);

    const int ag = (N_NODE + 3) / 4;
    const int gg = (N_NODE + 63) / 64;

    // ---- layer 1 (MFMA gemm; fused al_src + layer-1 al_dst DOT) ----
    gemm_mfma<128, false, true><<<dim3(gg, 3), 256, 0, stream>>>(
        x_user, x_item, x_user, WT1, a1s, hs_bf, alsrc_all, wd1, aldst_all, N_NODE);
    // agg1 also writes layer-2 al_dst into aldst_all in-place (per-block read-then-write)
    agg1_sp<<<dim3(ag, 2), 256, 0, stream>>>(rowptr_all, srcs_all, alsrc_all, aldst_all,
                                             hs_bf, b1, wd2, h_item1, h_user1);

    // ---- layer 2 (MFMA gemm, ReLU in A-staging; hs_bf overwrite safe: L1 hs consumed) ----
    gemm_mfma<64, true, false><<<dim3(gg, 3), 256, 0, stream>>>(
        h_user1, h_item1, h_user1, WT2, a2s, hs_bf, alsrc_all, wd2, aldst_all, N_NODE);
    agg2_sp<<<dim3(ag, 2), 256, 0, stream>>>(rowptr_all, srcs_all, alsrc_all, aldst_all,
                                             hs_bf, b2, o_item, o_user);

    // ---- scoring ----
    score_k<<<(3 * NL + 3) / 4, 256, 0, stream>>>(el0, el1, el2, o_user, o_item, relw, out, NL);
}

// Round 14
// 329.267 us; speedup vs baseline: 1.4756x; 1.0073x over previous
//
#include <hip/hip_runtime.h>
#include <cstdint>
#include <cstddef>

#define N_NODE 50000
#define NEDGE  500000
#define NL     100000
#define FDIM   128
#define HIDD   128
#define OUTD   64
#define NBSC   98        // ceil(N_NODE / 512) for rowptr scan
#define NB     49        // buckets = ceil(50000 / 1024), bucket = dst >> 10
#define BCH    8192      // edges per partition block
#define NBP1   62        // ceil(NEDGE / BCH)

typedef unsigned int uint32;
typedef unsigned short ushort16;
typedef __attribute__((ext_vector_type(8))) short bf16x8;
typedef __attribute__((ext_vector_type(4))) float f32x4;

static_assert(N_NODE < 65536, "src packs into 16 bits");

__device__ __forceinline__ float leakyf(float x) { return x > 0.f ? x : 0.2f * x; }

// round-to-nearest-even f32 -> bf16
__device__ __forceinline__ uint32 bf16r(float x) {
    uint32 u = __float_as_uint(x);
    return (u + 0x7fffu + ((u >> 16) & 1u)) >> 16;
}
__device__ __forceinline__ float bf_lo(uint32 u) { return __uint_as_float(u << 16); }
__device__ __forceinline__ float bf_hi(uint32 u) { return __uint_as_float(u & 0xffff0000u); }
// ReLU on 2 packed bf16 (sign-bit test; exact: relu(bf16(x)) == bf16(relu(x)))
__device__ __forceinline__ uint32 relu_bf2(uint32 u) {
    uint32 lo = u & 0xFFFFu, hi = u >> 16;
    lo = (lo & 0x8000u) ? 0u : lo;
    hi = (hi & 0x8000u) ? 0u : hi;
    return lo | (hi << 16);
}

// ---------------- fold Wd @ a_d -> per-relation length-128 vectors ----------------
__global__ void fold_wd(const float* __restrict__ W1d, const float* __restrict__ a1d,
                        const float* __restrict__ W2d, const float* __restrict__ a2d,
                        float* __restrict__ wd1, float* __restrict__ wd2) {
    int r = blockIdx.x;          // 3 relations
    int f = threadIdx.x;         // 128
    const float* w  = W1d + ((size_t)r * FDIM + f) * HIDD;
    const float* a  = a1d + r * HIDD;
    float s = 0.f;
    for (int h = 0; h < HIDD; ++h) s += w[h] * a[h];
    wd1[r * FDIM + f] = s;
    const float* w2 = W2d + ((size_t)r * HIDD + f) * OUTD;
    const float* a2 = a2d + r * OUTD;
    float s2 = 0.f;
    for (int o = 0; o < OUTD; ++o) s2 += w2[o] * a2[o];
    wd2[r * HIDD + f] = s2;
}

// ---------------- W -> WT bf16 transpose: WT[r][n][k] = bf16(W[r][k][n]) ----------------
__global__ void wt_k(const float* __restrict__ W1s, const float* __restrict__ W2s,
                     ushort16* __restrict__ WT1, ushort16* __restrict__ WT2) {
    int idx = blockIdx.x * 256 + threadIdx.x;
    if (blockIdx.y == 0) {
        if (idx < 3 * FDIM * HIDD) {
            int k = idx & 127, n = (idx >> 7) & 127, r = idx >> 14;
            WT1[idx] = (ushort16)bf16r(W1s[((size_t)r * FDIM + k) * HIDD + n]);
        }
    } else {
        if (idx < 3 * HIDD * OUTD) {
            int k = idx & 127, n = (idx >> 7) & 63, r = idx >> 13;
            WT2[idx] = (ushort16)bf16r(W2s[((size_t)r * HIDD + k) * OUTD + n]);
        }
    }
}

// ================= CSR build: two-level bucket partition (write-locality) =================
// bucketed entry packs src (low 16) | dst-local (high bits, 10 used).

__global__ __launch_bounds__(256) void part_hist(const int* __restrict__ e0,
                                                 const int* __restrict__ e1,
                                                 const int* __restrict__ e2,
                                                 int* __restrict__ bh) {
    int r = blockIdx.y, t = threadIdx.x;
    const int* ei  = (r == 0) ? e0 : (r == 1) ? e1 : e2;
    const int* dst = ei + NEDGE;
    __shared__ int lh[NB];
    if (t < NB) lh[t] = 0;
    __syncthreads();
    int base = blockIdx.x * BCH;
    int lim  = base + BCH; if (lim > NEDGE) lim = NEDGE;
    for (int i = base + t; i < lim; i += 256)
        atomicAdd(&lh[dst[i] >> 10], 1);
    __syncthreads();
    if (t < NB) bh[((size_t)r * NB + t) * NBP1 + blockIdx.x] = lh[t];
}

__global__ __launch_bounds__(256) void part_scan(int* __restrict__ bh,
                                                 int* __restrict__ bkbase) {
    int r = blockIdx.x, t = threadIdx.x;
    int* a = bh + (size_t)r * NB * NBP1;
    const int n = NB * NBP1;                 // 3038
    const int per = (n + 255) / 256;         // 12
    int lo = t * per, hi = lo + per; if (hi > n) hi = n;
    int s = 0;
    for (int i = lo; i < hi; ++i) s += a[i];
    __shared__ int sm[256];
    sm[t] = s;
    __syncthreads();
    for (int off = 1; off < 256; off <<= 1) {
        int x = (t >= off) ? sm[t - off] : 0;
        __syncthreads();
        sm[t] += x;
        __syncthreads();
    }
    int run = sm[t] - s;
    for (int i = lo; i < hi; ++i) { int c = a[i]; a[i] = run; run += c; }
    __syncthreads();
    if (t < NB) bkbase[r * (NB + 1) + t] = a[t * NBP1];
    if (t == NB) bkbase[r * (NB + 1) + NB] = NEDGE;
}

__global__ __launch_bounds__(256) void part_scatter(const int* __restrict__ e0,
                                                    const int* __restrict__ e1,
                                                    const int* __restrict__ e2,
                                                    const int* __restrict__ bh,
                                                    uint32* __restrict__ bucketed) {
    int r = blockIdx.y, t = threadIdx.x;
    const int* ei  = (r == 0) ? e0 : (r == 1) ? e1 : e2;
    const int* dst = ei + NEDGE;
    __shared__ int cur[NB];
    if (t < NB) cur[t] = bh[((size_t)r * NB + t) * NBP1 + blockIdx.x];
    __syncthreads();
    uint32* bk = bucketed + (size_t)r * NEDGE;
    int base = blockIdx.x * BCH;
    int lim  = base + BCH; if (lim > NEDGE) lim = NEDGE;
    for (int i = base + t; i < lim; i += 256) {
        int d = dst[i], s_ = ei[i];
        int pos = atomicAdd(&cur[d >> 10], 1);      // LDS atomic, global position
        bk[pos] = (uint32)s_ | ((uint32)(d & 1023) << 16);
    }
}

__global__ __launch_bounds__(256) void bucket_count(const uint32* __restrict__ bucketed,
                                                    const int* __restrict__ bkbase,
                                                    int* __restrict__ counts_all) {
    int r = blockIdx.y, k = blockIdx.x, t = threadIdx.x;
    int s0 = bkbase[r * (NB + 1) + k], s1 = bkbase[r * (NB + 1) + k + 1];
    __shared__ int lh[1024];
#pragma unroll
    for (int i = 0; i < 4; ++i) lh[t + i * 256] = 0;
    __syncthreads();
    const uint32* bk = bucketed + (size_t)r * NEDGE;
    for (int i = s0 + t; i < s1; i += 256)
        atomicAdd(&lh[bk[i] >> 16], 1);
    __syncthreads();
    int gbase = k << 10;
    int* cnt = counts_all + (size_t)r * N_NODE;
#pragma unroll
    for (int i = 0; i < 4; ++i) {
        int idx = t + i * 256;
        if (gbase + idx < N_NODE) cnt[gbase + idx] = lh[idx];
    }
}

__global__ __launch_bounds__(256) void scan1(const int* __restrict__ counts_all,
                                             int* __restrict__ bsum) {
    int r = blockIdx.y, b = blockIdx.x, t = threadIdx.x;
    int base = b * 512;
    int lim = N_NODE - base; if (lim > 512) lim = 512;
    const int* c = counts_all + (size_t)r * N_NODE + base;
    int v0 = (2 * t     < lim) ? c[2 * t]     : 0;
    int v1 = (2 * t + 1 < lim) ? c[2 * t + 1] : 0;
    __shared__ int sm[256];
    sm[t] = v0 + v1;
    __syncthreads();
    for (int off = 128; off; off >>= 1) {
        if (t < off) sm[t] += sm[t + off];
        __syncthreads();
    }
    if (t == 0) bsum[r * NBSC + b] = sm[0];
}

__global__ __launch_bounds__(256) void scan3(const int* __restrict__ counts_all,
                                             int* __restrict__ rowptr_all,
                                             const int* __restrict__ bsum) {
    int r = blockIdx.y, b = blockIdx.x, t = threadIdx.x;
    __shared__ int sm[256];
    sm[t] = (t < b) ? bsum[r * NBSC + t] : 0;
    __syncthreads();
    for (int off = 128; off; off >>= 1) {
        if (t < off) sm[t] += sm[t + off];
        __syncthreads();
    }
    int boff = sm[0];
    __syncthreads();

    int base = b * 512;
    int lim = N_NODE - base; if (lim > 512) lim = 512;
    const int* c = counts_all + (size_t)r * N_NODE;
    int* rp = rowptr_all + (size_t)r * (N_NODE + 1);
    int i0 = base + 2 * t, i1 = i0 + 1;
    int v0 = (2 * t     < lim) ? c[i0] : 0;
    int v1 = (2 * t + 1 < lim) ? c[i1] : 0;
    int ps = v0 + v1;
    sm[t] = ps;
    __syncthreads();
    for (int off = 1; off < 256; off <<= 1) {
        int x = (t >= off) ? sm[t - off] : 0;
        __syncthreads();
        sm[t] += x;
        __syncthreads();
    }
    int excl = sm[t] - ps + boff;
    if (2 * t < lim)     rp[i0] = excl;
    if (2 * t + 1 < lim) rp[i1] = excl + v0;
    if (b == 0 && t == 0) rp[N_NODE] = NEDGE;
}

__global__ __launch_bounds__(256) void bucket_scatter(const uint32* __restrict__ bucketed,
                                                      const int* __restrict__ bkbase,
                                                      const int* __restrict__ rowptr_all,
                                                      int* __restrict__ srcs_all) {
    int r = blockIdx.y, k = blockIdx.x, t = threadIdx.x;
    int s0 = bkbase[r * (NB + 1) + k], s1 = bkbase[r * (NB + 1) + k + 1];
    int gbase = k << 10;
    const int* rp = rowptr_all + (size_t)r * (N_NODE + 1);
    __shared__ int cur[1024];
#pragma unroll
    for (int i = 0; i < 4; ++i) {
        int idx = t + i * 256;
        cur[idx] = (gbase + idx < N_NODE) ? rp[gbase + idx] : 0;
    }
    __syncthreads();
    const uint32* bk = bucketed + (size_t)r * NEDGE;
    int* out = srcs_all + (size_t)r * NEDGE;
    for (int i = s0 + t; i < s1; i += 256) {
        uint32 e = bk[i];
        int pos = atomicAdd(&cur[e >> 16], 1);       // LDS atomic
        out[pos] = (int)(e & 0xFFFFu);               // write confined to bucket's CSR range
    }
}

// ========== MFMA GEMM: C[M x BN](bf16) = A[M x 128] @ WT^T, fused epilogues ==========
// A is fp32 (ABF16=false) or bf16 (ABF16=true). 256 thr = 4 waves; block = 64 rows x BN.
// LDS XOR swizzle byte ^= (row&7)<<4 (conflict-free ds_read_b128).
template <int BN, bool RELU, bool DOT, bool ABF16>
__global__ __launch_bounds__(256) void gemm_mfma(const void* __restrict__ A0,
                                                 const void* __restrict__ A1,
                                                 const void* __restrict__ A2,
                                                 const ushort16* __restrict__ WTbase, // [r][BN][128] bf16
                                                 const float* __restrict__ avec_base,
                                                 ushort16* __restrict__ Cbase,
                                                 float* __restrict__ al_base,
                                                 const float* __restrict__ wdvec,
                                                 float* __restrict__ adst_base, int M) {
    constexpr int K = 128;
    __shared__ ushort16 aslds[64 * K];     // 16 KB
    __shared__ ushort16 bslds[BN * K];     // 32/16 KB
    const int r = blockIdx.y;
    const void* Av = (r == 0) ? A0 : (r == 1) ? A1 : A2;
    const int t    = threadIdx.x;
    const int lane = t & 63;
    const int w    = t >> 6;
    const int m0   = blockIdx.x * 64;

    // ---- stage B^T (bf16 global, coalesced 16B) with XOR swizzle ----
    {
        const uint4* src = reinterpret_cast<const uint4*>(WTbase + (size_t)r * BN * K);
        char* bb = reinterpret_cast<char*>(bslds);
#pragma unroll
        for (int i = t; i < BN * 16; i += 256) {
            int n = i >> 4, c16 = i & 15;
            uint32 off = (uint32)(n * 256 + c16 * 16) ^ (uint32)((n & 7) << 4);
            *reinterpret_cast<uint4*>(bb + off) = src[i];
        }
    }
    // ---- stage A tile (swizzled); fp32 path: ->bf16 + optional DOT; bf16 path: optional ReLU ----
    char* ab = reinterpret_cast<char*>(aslds);
    if (ABF16) {
        const uint2* A2v = reinterpret_cast<const uint2*>(Av);
#pragma unroll
        for (int i = 0; i < 8; ++i) {
            int idx = t + i * 256;              // 2048 uint2 = 64 rows x 32 groups of 4 bf16
            int row = idx >> 5, kq = idx & 31;
            uint2 p = make_uint2(0u, 0u);
            if (m0 + row < M) {
                p = A2v[(size_t)(m0 + row) * 32 + kq];
                if (RELU) { p.x = relu_bf2(p.x); p.y = relu_bf2(p.y); }
            }
            uint32 off = (uint32)(row * 256 + kq * 8) ^ (uint32)((row & 7) << 4);
            *reinterpret_cast<uint2*>(ab + off) = p;
        }
    } else {
        const float4* A4 = reinterpret_cast<const float4*>(Av);
        const int mr = (r == 0) ? 1 : (r == 1) ? 0 : 2;
        const float* wdot = wdvec + mr * K;
        float dp[8];
#pragma unroll
        for (int i = 0; i < 8; ++i) dp[i] = 0.f;
#pragma unroll
        for (int i = 0; i < 8; ++i) {
            int idx = t + i * 256;              // 2048 float4 = 64 rows x 32
            int row = idx >> 5, kq = idx & 31;
            float4 v = make_float4(0.f, 0.f, 0.f, 0.f);
            if (m0 + row < M) {
                v = A4[(size_t)(m0 + row) * 32 + kq];
                if (RELU) {
                    v.x = fmaxf(v.x, 0.f); v.y = fmaxf(v.y, 0.f);
                    v.z = fmaxf(v.z, 0.f); v.w = fmaxf(v.w, 0.f);
                }
            }
            if (DOT) {
                float4 wv = *reinterpret_cast<const float4*>(&wdot[kq * 4]);
                dp[i] = fmaf(v.x, wv.x, dp[i]); dp[i] = fmaf(v.y, wv.y, dp[i]);
                dp[i] = fmaf(v.z, wv.z, dp[i]); dp[i] = fmaf(v.w, wv.w, dp[i]);
            }
            uint2 p;
            p.x = bf16r(v.x) | (bf16r(v.y) << 16);
            p.y = bf16r(v.z) | (bf16r(v.w) << 16);
            uint32 off = (uint32)(row * 256 + kq * 8) ^ (uint32)((row & 7) << 4);
            *reinterpret_cast<uint2*>(ab + off) = p;
        }
        if (DOT) {   // reduce dp across the 32 threads sharing a row
            float* adst = adst_base + (size_t)mr * M;
#pragma unroll
            for (int i = 0; i < 8; ++i) {
                float p = dp[i];
                p += __shfl_xor(p, 16); p += __shfl_xor(p, 8); p += __shfl_xor(p, 4);
                p += __shfl_xor(p, 2);  p += __shfl_xor(p, 1);
                int row = (t + i * 256) >> 5;
                if ((t & 31) == 0 && m0 + row < M) adst[m0 + row] = p;
            }
        }
    }
    __syncthreads();

    // ---- MFMA main: wave w -> rows m0+w*16..+15, all BN cols ----
    const int col0 = lane & 15;
    const int kgrp = lane >> 4;          // 0..3
    const int arow = w * 16 + col0;
    bf16x8 afrag[4];
#pragma unroll
    for (int ks = 0; ks < 4; ++ks) {
        uint32 off = (uint32)(arow * 256 + ks * 64 + kgrp * 16) ^ (uint32)((arow & 7) << 4);
        afrag[ks] = *reinterpret_cast<const bf16x8*>(ab + off);
    }
    constexpr int NT = BN / 16;
    f32x4 acc[NT];
#pragma unroll
    for (int n = 0; n < NT; ++n) acc[n] = (f32x4){0.f, 0.f, 0.f, 0.f};
    const char* bb = reinterpret_cast<const char*>(bslds);
#pragma unroll
    for (int n = 0; n < NT; ++n) {
        int bcol = n * 16 + col0;
        uint32 xw = (uint32)((bcol & 7) << 4);
#pragma unroll
        for (int ks = 0; ks < 4; ++ks) {
            uint32 off = (uint32)(bcol * 256 + ks * 64 + kgrp * 16) ^ xw;
            bf16x8 bfrag = *reinterpret_cast<const bf16x8*>(bb + off);
            acc[n] = __builtin_amdgcn_mfma_f32_16x16x32_bf16(afrag[ks], bfrag, acc[n], 0, 0, 0);
        }
    }

    // ---- epilogue: bf16 C-store + fused al_src (fp32 acc) ----
    ushort16* C = Cbase + (size_t)r * M * BN;
    const float* av = avec_base + r * BN;
    const int rbase = m0 + w * 16 + kgrp * 4;
    float p4[4] = {0.f, 0.f, 0.f, 0.f};
#pragma unroll
    for (int n = 0; n < NT; ++n) {
        float asv = av[n * 16 + col0];
#pragma unroll
        for (int reg = 0; reg < 4; ++reg) {
            int rr = rbase + reg;
            if (rr < M) C[(size_t)rr * BN + n * 16 + col0] = (ushort16)bf16r(acc[n][reg]);
            p4[reg] = fmaf(acc[n][reg], asv, p4[reg]);
        }
    }
    float* al = al_base + (size_t)r * M;
#pragma unroll
    for (int reg = 0; reg < 4; ++reg) {
        float q = p4[reg];
        q += __shfl_xor(q, 1); q += __shfl_xor(q, 2);
        q += __shfl_xor(q, 4); q += __shfl_xor(q, 8);
        int rr = rbase + reg;
        if (col0 == 0 && rr < M) al[rr] = q;
    }
}

// ------- paired-edge single-pass softmax-aggregate helpers -------
__device__ __forceinline__ float4 seg128p(const int* __restrict__ rp, const int* __restrict__ ss,
                                          const float* __restrict__ als,
                                          const uint2* __restrict__ hv2,
                                          float ad, int d, int half, int col) {
    int s = rp[d], e = rp[d + 1];
    float den = 0.f;
    float4 ac = make_float4(0.f, 0.f, 0.f, 0.f);
    int i = s;
    for (; i + 4 <= e; i += 4) {
        int sA = ss[i + half];
        int sB = ss[i + 2 + half];
        float lA = als[sA], lB = als[sB];
        uint2 uA = hv2[(size_t)sA * 32 + col];
        uint2 uB = hv2[(size_t)sB * 32 + col];
        float eA = __expf(leakyf(lA + ad));
        float eB = __expf(leakyf(lB + ad));
        den += eA + eB;
        ac.x = fmaf(eA, bf_lo(uA.x), ac.x); ac.y = fmaf(eA, bf_hi(uA.x), ac.y);
        ac.z = fmaf(eA, bf_lo(uA.y), ac.z); ac.w = fmaf(eA, bf_hi(uA.y), ac.w);
        ac.x = fmaf(eB, bf_lo(uB.x), ac.x); ac.y = fmaf(eB, bf_hi(uB.x), ac.y);
        ac.z = fmaf(eB, bf_lo(uB.y), ac.z); ac.w = fmaf(eB, bf_hi(uB.y), ac.w);
    }
    if (i + 2 <= e) {
        int sA = ss[i + half];
        float lA = als[sA];
        uint2 uA = hv2[(size_t)sA * 32 + col];
        float eA = __expf(leakyf(lA + ad));
        den += eA;
        ac.x = fmaf(eA, bf_lo(uA.x), ac.x); ac.y = fmaf(eA, bf_hi(uA.x), ac.y);
        ac.z = fmaf(eA, bf_lo(uA.y), ac.z); ac.w = fmaf(eA, bf_hi(uA.y), ac.w);
        i += 2;
    }
    if (i < e && half == 0) {
        int sA = ss[i];
        float lA = als[sA];
        uint2 uA = hv2[(size_t)sA * 32 + col];
        float eA = __expf(leakyf(lA + ad));
        den += eA;
        ac.x = fmaf(eA, bf_lo(uA.x), ac.x); ac.y = fmaf(eA, bf_hi(uA.x), ac.y);
        ac.z = fmaf(eA, bf_lo(uA.y), ac.z); ac.w = fmaf(eA, bf_hi(uA.y), ac.w);
    }
    den  += __shfl_xor(den, 32);
    ac.x += __shfl_xor(ac.x, 32); ac.y += __shfl_xor(ac.y, 32);
    ac.z += __shfl_xor(ac.z, 32); ac.w += __shfl_xor(ac.w, 32);
    float rden = 1.0f / (den + 1e-16f);
    return make_float4(ac.x * rden, ac.y * rden, ac.z * rden, ac.w * rden);
}

__device__ __forceinline__ float2 seg64p(const int* __restrict__ rp, const int* __restrict__ ss,
                                         const float* __restrict__ als,
                                         const uint32* __restrict__ hv,
                                         float ad, int d, int half, int col) {
    int s = rp[d], e = rp[d + 1];
    float den = 0.f, ax = 0.f, ay = 0.f;
    int i = s;
    for (; i + 4 <= e; i += 4) {
        int sA = ss[i + half];
        int sB = ss[i + 2 + half];
        float lA = als[sA], lB = als[sB];
        uint32 uA = hv[(size_t)sA * 32 + col];
        uint32 uB = hv[(size_t)sB * 32 + col];
        float eA = __expf(leakyf(lA + ad));
        float eB = __expf(leakyf(lB + ad));
        den += eA + eB;
        ax = fmaf(eA, bf_lo(uA), ax); ay = fmaf(eA, bf_hi(uA), ay);
        ax = fmaf(eB, bf_lo(uB), ax); ay = fmaf(eB, bf_hi(uB), ay);
    }
    if (i + 2 <= e) {
        int sA = ss[i + half];
        float lA = als[sA];
        uint32 uA = hv[(size_t)sA * 32 + col];
        float eA = __expf(leakyf(lA + ad));
        den += eA;
        ax = fmaf(eA, bf_lo(uA), ax); ay = fmaf(eA, bf_hi(uA), ay);
        i += 2;
    }
    if (i < e && half == 0) {
        int sA = ss[i];
        float lA = als[sA];
        uint32 uA = hv[(size_t)sA * 32 + col];
        float eA = __expf(leakyf(lA + ad));
        den += eA;
        ax = fmaf(eA, bf_lo(uA), ax); ay = fmaf(eA, bf_hi(uA), ay);
    }
    den += __shfl_xor(den, 32);
    ax  += __shfl_xor(ax, 32);
    ay  += __shfl_xor(ay, 32);
    float rden = 1.0f / (den + 1e-16f);
    return make_float2(ax * rden, ay * rden);
}

// ---------------- layer-1 agg + fused layer-2 al_dst; grid (12500, 2), 4 indep waves ----------------
// h written in bf16 (numerically identical downstream: gemm2 would round anyway; fp32 h kept
// in registers for the fused layer-2 al_dst dot).
__global__ __launch_bounds__(256) void agg1_sp(const int* __restrict__ rowptr_all,
                                               const int* __restrict__ srcs_all,
                                               const float* __restrict__ alsrc_all,
                                               float* __restrict__ aldst_all,
                                               const ushort16* __restrict__ hs_all,
                                               const float* __restrict__ b1,
                                               const float* __restrict__ wd2,
                                               ushort16* __restrict__ h_item,
                                               ushort16* __restrict__ h_user) {
    const int lane = threadIdx.x & 63;
    const int d = blockIdx.x * 4 + (threadIdx.x >> 6);
    if (d >= N_NODE) return;
    const int half = lane >> 5, col = lane & 31;
    const uint2* hv2 = reinterpret_cast<const uint2*>(hs_all);
    if (blockIdx.y == 0) {           // item dst: relation 0
        float4 w = seg128p(rowptr_all, srcs_all, alsrc_all, hv2, aldst_all[d], d, half, col);
        float4 b = ((const float4*)b1)[col];
        float4 h = make_float4(w.x + b.x, w.y + b.y, w.z + b.z, w.w + b.w);
        if (half == 0) {
            uint2 p;
            p.x = bf16r(h.x) | (bf16r(h.y) << 16);
            p.y = bf16r(h.z) | (bf16r(h.w) << 16);
            ((uint2*)h_item)[(size_t)d * 32 + col] = p;
        }
        float4 v0 = ((const float4*)wd2)[col];
        float p = fmaxf(h.x, 0.f) * v0.x + fmaxf(h.y, 0.f) * v0.y
                + fmaxf(h.z, 0.f) * v0.z + fmaxf(h.w, 0.f) * v0.w;
        p += __shfl_xor(p, 16); p += __shfl_xor(p, 8);
        p += __shfl_xor(p, 4);  p += __shfl_xor(p, 2); p += __shfl_xor(p, 1);
        if (lane == 0) aldst_all[d] = p;
    } else {                         // user dst: relations 1 + 2 in one wave
        float4 w1 = seg128p(rowptr_all + (N_NODE + 1), srcs_all + NEDGE,
                            alsrc_all + N_NODE, hv2 + (size_t)N_NODE * 32,
                            aldst_all[N_NODE + d], d, half, col);
        float4 w2 = seg128p(rowptr_all + 2 * (N_NODE + 1), srcs_all + (size_t)2 * NEDGE,
                            alsrc_all + 2 * N_NODE, hv2 + (size_t)2 * N_NODE * 32,
                            aldst_all[2 * N_NODE + d], d, half, col);
        float4 bA = ((const float4*)(b1 + HIDD))[col];
        float4 bB = ((const float4*)(b1 + 2 * HIDD))[col];
        float4 h = make_float4(w1.x + w2.x + bA.x + bB.x, w1.y + w2.y + bA.y + bB.y,
                               w1.z + w2.z + bA.z + bB.z, w1.w + w2.w + bA.w + bB.w);
        if (half == 0) {
            uint2 p;
            p.x = bf16r(h.x) | (bf16r(h.y) << 16);
            p.y = bf16r(h.z) | (bf16r(h.w) << 16);
            ((uint2*)h_user)[(size_t)d * 32 + col] = p;
        }
        float hx = fmaxf(h.x, 0.f), hy = fmaxf(h.y, 0.f);
        float hz = fmaxf(h.z, 0.f), hw = fmaxf(h.w, 0.f);
        float4 v1 = ((const float4*)(wd2 + HIDD))[col];
        float4 v2 = ((const float4*)(wd2 + 2 * HIDD))[col];
        float p1 = hx * v1.x + hy * v1.y + hz * v1.z + hw * v1.w;
        float p2 = hx * v2.x + hy * v2.y + hz * v2.z + hw * v2.w;
        p1 += __shfl_xor(p1, 16); p1 += __shfl_xor(p1, 8);
        p1 += __shfl_xor(p1, 4);  p1 += __shfl_xor(p1, 2); p1 += __shfl_xor(p1, 1);
        p2 += __shfl_xor(p2, 16); p2 += __shfl_xor(p2, 8);
        p2 += __shfl_xor(p2, 4);  p2 += __shfl_xor(p2, 2); p2 += __shfl_xor(p2, 1);
        if (lane == 0) {
            aldst_all[N_NODE + d]     = p1;
            aldst_all[2 * N_NODE + d] = p2;
        }
    }
}

// ---------------- layer-2 agg (C=64), paired edges; o in bf16 ----------------
__global__ __launch_bounds__(256) void agg2_sp(const int* __restrict__ rowptr_all,
                                               const int* __restrict__ srcs_all,
                                               const float* __restrict__ alsrc_all,
                                               const float* __restrict__ aldst_all,
                                               const ushort16* __restrict__ hs_all,
                                               const float* __restrict__ b2,
                                               ushort16* __restrict__ o_item,
                                               ushort16* __restrict__ o_user) {
    const int lane = threadIdx.x & 63;
    const int d = blockIdx.x * 4 + (threadIdx.x >> 6);
    if (d >= N_NODE) return;
    const int half = lane >> 5, col = lane & 31;
    const uint32* hv = reinterpret_cast<const uint32*>(hs_all);
    if (blockIdx.y == 0) {
        float2 w = seg64p(rowptr_all, srcs_all, alsrc_all, hv, aldst_all[d], d, half, col);
        float2 b = ((const float2*)b2)[col];
        if (half == 0)
            ((uint32*)o_item)[(size_t)d * 32 + col] =
                bf16r(w.x + b.x) | (bf16r(w.y + b.y) << 16);
    } else {
        float2 w1 = seg64p(rowptr_all + (N_NODE + 1), srcs_all + NEDGE,
                           alsrc_all + N_NODE, hv + (size_t)N_NODE * 32,
                           aldst_all[N_NODE + d], d, half, col);
        float2 w2 = seg64p(rowptr_all + 2 * (N_NODE + 1), srcs_all + (size_t)2 * NEDGE,
                           alsrc_all + 2 * N_NODE, hv + (size_t)2 * N_NODE * 32,
                           aldst_all[2 * N_NODE + d], d, half, col);
        float2 bA = ((const float2*)(b2 + OUTD))[col];
        float2 bB = ((const float2*)(b2 + 2 * OUTD))[col];
        if (half == 0)
            ((uint32*)o_user)[(size_t)d * 32 + col] =
                bf16r(w1.x + w2.x + bA.x + bB.x) | (bf16r(w1.y + w2.y + bA.y + bB.y) << 16);
    }
}

// ---------------- bilinear edge scoring (o tables bf16) ----------------
__global__ void score_k(const int* __restrict__ e0, const int* __restrict__ e1,
                        const int* __restrict__ e2,
                        const ushort16* __restrict__ o_user, const ushort16* __restrict__ o_item,
                        const float* __restrict__ relw, float* __restrict__ out, int L) {
    int g    = blockIdx.x * 4 + (threadIdx.x >> 6);
    int lane = threadIdx.x & 63;
    int r = g / L, l = g - r * L;
    if (r >= 3) return;
    const int* ei = (r == 0) ? e0 : (r == 1) ? e1 : e2;
    int ai = ei[l];
    int bi = ei[L + l];
    const ushort16* A = (r == 1) ? o_item : o_user;
    const ushort16* B = (r == 0) ? o_item : o_user;
    float av = __uint_as_float(((uint32)A[(size_t)ai * OUTD + lane]) << 16);
    float bv = __uint_as_float(((uint32)B[(size_t)bi * OUTD + lane]) << 16);
    float v = av * relw[r * OUTD + lane] * bv;
#pragma unroll
    for (int off = 32; off; off >>= 1) v += __shfl_xor(v, off);
    if (lane == 0) out[r * L + l] = v;
}

extern "C" void kernel_launch(void* const* d_in, const int* in_sizes, int n_in,
                              void* d_out, int out_size, void* d_ws, size_t ws_size,
                              hipStream_t stream) {
    const float* x_user = (const float*)d_in[0];
    const float* x_item = (const float*)d_in[1];
    const float* W1s = (const float*)d_in[2];
    const float* W1d = (const float*)d_in[3];
    const float* a1s = (const float*)d_in[4];
    const float* a1d = (const float*)d_in[5];
    const float* b1  = (const float*)d_in[6];
    const float* W2s = (const float*)d_in[7];
    const float* W2d = (const float*)d_in[8];
    const float* a2s = (const float*)d_in[9];
    const float* a2d = (const float*)d_in[10];
    const float* b2  = (const float*)d_in[11];
    const float* relw= (const float*)d_in[12];
    const int* ei0 = (const int*)d_in[13];
    const int* ei1 = (const int*)d_in[14];
    const int* ei2 = (const int*)d_in[15];
    const int* el0 = (const int*)d_in[16];
    const int* el1 = (const int*)d_in[17];
    const int* el2 = (const int*)d_in[18];
    float* out = (float*)d_out;
    (void)ws_size; (void)n_in; (void)in_sizes; (void)out_size;

    char* ws = (char*)d_ws;
    size_t off = 0;
    auto alloc = [&](size_t bytes) -> void* {
        void* p = ws + off;
        off = (off + bytes + 255) & ~(size_t)255;
        return p;
    };
    int*     rowptr_all = (int*)alloc((size_t)3 * (N_NODE + 1) * 4);
    int*     counts_all = (int*)alloc((size_t)3 * N_NODE * 4);
    int*     srcs_all   = (int*)alloc((size_t)3 * NEDGE * 4);
    int*     bsum       = (int*)alloc((size_t)3 * NBSC * 4);
    int*     bh         = (int*)alloc((size_t)3 * NB * NBP1 * 4);
    int*     bkbase     = (int*)alloc((size_t)3 * (NB + 1) * 4);
    uint32*  bucketed   = (uint32*)alloc((size_t)3 * NEDGE * 4);            // packed src|dlocal
    ushort16* hs_bf     = (ushort16*)alloc((size_t)3 * N_NODE * HIDD * 2);  // bf16
    ushort16* WT1       = (ushort16*)alloc((size_t)3 * HIDD * FDIM * 2);    // [r][n][k] bf16
    ushort16* WT2       = (ushort16*)alloc((size_t)3 * OUTD * HIDD * 2);
    ushort16* h_item1   = (ushort16*)alloc((size_t)2 * N_NODE * HIDD * 2);  // bf16
    ushort16* h_user1   = h_item1 + (size_t)N_NODE * HIDD;
    ushort16* o_item    = (ushort16*)alloc((size_t)N_NODE * OUTD * 2);      // bf16
    ushort16* o_user    = (ushort16*)alloc((size_t)N_NODE * OUTD * 2);
    float*   alsrc_all  = (float*)alloc((size_t)3 * N_NODE * 4);
    float*   aldst_all  = (float*)alloc((size_t)3 * N_NODE * 4);
    float*   wd1        = (float*)alloc(3 * FDIM * 4);
    float*   wd2        = (float*)alloc(3 * HIDD * 4);

    fold_wd<<<3, 128, 0, stream>>>(W1d, a1d, W2d, a2d, wd1, wd2);
    wt_k<<<dim3(192, 2), 256, 0, stream>>>(W1s, W2s, WT1, WT2);

    // ---- CSR build: two-level bucket partition ----
    part_hist<<<dim3(NBP1, 3), 256, 0, stream>>>(ei0, ei1, ei2, bh);
    part_scan<<<3, 256, 0, stream>>>(bh, bkbase);
    part_scatter<<<dim3(NBP1, 3), 256, 0, stream>>>(ei0, ei1, ei2, bh, bucketed);
    bucket_count<<<dim3(NB, 3), 256, 0, stream>>>(bucketed, bkbase, counts_all);
    scan1<<<dim3(NBSC, 3), 256, 0, stream>>>(counts_all, bsum);
    scan3<<<dim3(NBSC, 3), 256, 0, stream>>>(counts_all, rowptr_all, bsum);
    bucket_scatter<<<dim3(NB, 3), 256, 0, stream>>>(bucketed, bkbase, rowptr_all, srcs_all);

    const int ag = (N_NODE + 3) / 4;
    const int gg = (N_NODE + 63) / 64;

    // ---- layer 1 (MFMA gemm; fused al_src + layer-1 al_dst DOT; A = fp32 inputs) ----
    gemm_mfma<128, false, true, false><<<dim3(gg, 3), 256, 0, stream>>>(
        x_user, x_item, x_user, WT1, a1s, hs_bf, alsrc_all, wd1, aldst_all, N_NODE);
    // agg1 also writes layer-2 al_dst into aldst_all in-place (per-block read-then-write)
    agg1_sp<<<dim3(ag, 2), 256, 0, stream>>>(rowptr_all, srcs_all, alsrc_all, aldst_all,
                                             hs_bf, b1, wd2, h_item1, h_user1);

    // ---- layer 2 (MFMA gemm; A = bf16 h, ReLU in staging; hs_bf overwrite safe) ----
    gemm_mfma<64, true, false, true><<<dim3(gg, 3), 256, 0, stream>>>(
        h_user1, h_item1, h_user1, WT2, a2s, hs_bf, alsrc_all, wd2, aldst_all, N_NODE);
    agg2_sp<<<dim3(ag, 2), 256, 0, stream>>>(rowptr_all, srcs_all, alsrc_all, aldst_all,
                                             hs_bf, b2, o_item, o_user);

    // ---- scoring ----
    score_k<<<(3 * NL + 3) / 4, 256, 0, stream>>>(el0, el1, el2, o_user, o_item, relw, out, NL);
}

// Round 15
// 320.934 us; speedup vs baseline: 1.5139x; 1.0260x over previous
//
#include <hip/hip_runtime.h>
#include <cstdint>
#include <cstddef>

#define N_NODE 50000
#define NEDGE  500000
#define NL     100000
#define FDIM   128
#define HIDD   128
#define OUTD   64
#define NBSC   98        // ceil(N_NODE / 512) for rowptr scan
#define NB     49        // buckets = ceil(50000 / 1024), bucket = dst >> 10
#define BCH    8192      // edges per partition block
#define NBP1   62        // ceil(NEDGE / BCH)

typedef unsigned int uint32;
typedef unsigned short ushort16;
typedef __attribute__((ext_vector_type(8))) short bf16x8;
typedef __attribute__((ext_vector_type(4))) float f32x4;

static_assert(N_NODE < 65536, "src packs into 16 bits");

__device__ __forceinline__ float leakyf(float x) { return x > 0.f ? x : 0.2f * x; }

// round-to-nearest-even f32 -> bf16
__device__ __forceinline__ uint32 bf16r(float x) {
    uint32 u = __float_as_uint(x);
    return (u + 0x7fffu + ((u >> 16) & 1u)) >> 16;
}
__device__ __forceinline__ float bf_lo(uint32 u) { return __uint_as_float(u << 16); }
__device__ __forceinline__ float bf_hi(uint32 u) { return __uint_as_float(u & 0xffff0000u); }
// ReLU on 2 packed bf16 (exact: relu(bf16(x)) == bf16(relu(x)))
__device__ __forceinline__ uint32 relu_bf2(uint32 u) {
    uint32 lo = u & 0xFFFFu, hi = u >> 16;
    lo = (lo & 0x8000u) ? 0u : lo;
    hi = (hi & 0x8000u) ? 0u : hi;
    return lo | (hi << 16);
}

// ---------------- fold Wd @ a_d -> per-relation length-128 vectors ----------------
__global__ void fold_wd(const float* __restrict__ W1d, const float* __restrict__ a1d,
                        const float* __restrict__ W2d, const float* __restrict__ a2d,
                        float* __restrict__ wd1, float* __restrict__ wd2) {
    int r = blockIdx.x;          // 3 relations
    int f = threadIdx.x;         // 128
    const float* w  = W1d + ((size_t)r * FDIM + f) * HIDD;
    const float* a  = a1d + r * HIDD;
    float s = 0.f;
    for (int h = 0; h < HIDD; ++h) s += w[h] * a[h];
    wd1[r * FDIM + f] = s;
    const float* w2 = W2d + ((size_t)r * HIDD + f) * OUTD;
    const float* a2 = a2d + r * OUTD;
    float s2 = 0.f;
    for (int o = 0; o < OUTD; ++o) s2 += w2[o] * a2[o];
    wd2[r * HIDD + f] = s2;
}

// ---------------- W -> WT bf16 transpose: WT[r][n][k] = bf16(W[r][k][n]) ----------------
__global__ void wt_k(const float* __restrict__ W1s, const float* __restrict__ W2s,
                     ushort16* __restrict__ WT1, ushort16* __restrict__ WT2) {
    int idx = blockIdx.x * 256 + threadIdx.x;
    if (blockIdx.y == 0) {
        if (idx < 3 * FDIM * HIDD) {
            int k = idx & 127, n = (idx >> 7) & 127, r = idx >> 14;
            WT1[idx] = (ushort16)bf16r(W1s[((size_t)r * FDIM + k) * HIDD + n]);
        }
    } else {
        if (idx < 3 * HIDD * OUTD) {
            int k = idx & 127, n = (idx >> 7) & 63, r = idx >> 13;
            WT2[idx] = (ushort16)bf16r(W2s[((size_t)r * HIDD + k) * OUTD + n]);
        }
    }
}

// ================= CSR build: two-level bucket partition (write-locality) =================

__global__ __launch_bounds__(256) void part_hist(const int* __restrict__ e0,
                                                 const int* __restrict__ e1,
                                                 const int* __restrict__ e2,
                                                 int* __restrict__ bh) {
    int r = blockIdx.y, t = threadIdx.x;
    const int* ei  = (r == 0) ? e0 : (r == 1) ? e1 : e2;
    const int* dst = ei + NEDGE;
    __shared__ int lh[NB];
    if (t < NB) lh[t] = 0;
    __syncthreads();
    int base = blockIdx.x * BCH;
    int lim  = base + BCH; if (lim > NEDGE) lim = NEDGE;
    for (int i = base + t; i < lim; i += 256)
        atomicAdd(&lh[dst[i] >> 10], 1);
    __syncthreads();
    if (t < NB) bh[((size_t)r * NB + t) * NBP1 + blockIdx.x] = lh[t];
}

__global__ __launch_bounds__(256) void part_scan(int* __restrict__ bh,
                                                 int* __restrict__ bkbase) {
    int r = blockIdx.x, t = threadIdx.x;
    int* a = bh + (size_t)r * NB * NBP1;
    const int n = NB * NBP1;                 // 3038
    const int per = (n + 255) / 256;         // 12
    int lo = t * per, hi = lo + per; if (hi > n) hi = n;
    int s = 0;
    for (int i = lo; i < hi; ++i) s += a[i];
    __shared__ int sm[256];
    sm[t] = s;
    __syncthreads();
    for (int off = 1; off < 256; off <<= 1) {
        int x = (t >= off) ? sm[t - off] : 0;
        __syncthreads();
        sm[t] += x;
        __syncthreads();
    }
    int run = sm[t] - s;
    for (int i = lo; i < hi; ++i) { int c = a[i]; a[i] = run; run += c; }
    __syncthreads();
    if (t < NB) bkbase[r * (NB + 1) + t] = a[t * NBP1];
    if (t == NB) bkbase[r * (NB + 1) + NB] = NEDGE;
}

__global__ __launch_bounds__(256) void part_scatter(const int* __restrict__ e0,
                                                    const int* __restrict__ e1,
                                                    const int* __restrict__ e2,
                                                    const int* __restrict__ bh,
                                                    uint32* __restrict__ bucketed) {
    int r = blockIdx.y, t = threadIdx.x;
    const int* ei  = (r == 0) ? e0 : (r == 1) ? e1 : e2;
    const int* dst = ei + NEDGE;
    __shared__ int cur[NB];
    if (t < NB) cur[t] = bh[((size_t)r * NB + t) * NBP1 + blockIdx.x];
    __syncthreads();
    uint32* bk = bucketed + (size_t)r * NEDGE;
    int base = blockIdx.x * BCH;
    int lim  = base + BCH; if (lim > NEDGE) lim = NEDGE;
    for (int i = base + t; i < lim; i += 256) {
        int d = dst[i], s_ = ei[i];
        int pos = atomicAdd(&cur[d >> 10], 1);      // LDS atomic, global position
        bk[pos] = (uint32)s_ | ((uint32)(d & 1023) << 16);
    }
}

__global__ __launch_bounds__(256) void bucket_count(const uint32* __restrict__ bucketed,
                                                    const int* __restrict__ bkbase,
                                                    int* __restrict__ counts_all) {
    int r = blockIdx.y, k = blockIdx.x, t = threadIdx.x;
    int s0 = bkbase[r * (NB + 1) + k], s1 = bkbase[r * (NB + 1) + k + 1];
    __shared__ int lh[1024];
#pragma unroll
    for (int i = 0; i < 4; ++i) lh[t + i * 256] = 0;
    __syncthreads();
    const uint32* bk = bucketed + (size_t)r * NEDGE;
    for (int i = s0 + t; i < s1; i += 256)
        atomicAdd(&lh[bk[i] >> 16], 1);
    __syncthreads();
    int gbase = k << 10;
    int* cnt = counts_all + (size_t)r * N_NODE;
#pragma unroll
    for (int i = 0; i < 4; ++i) {
        int idx = t + i * 256;
        if (gbase + idx < N_NODE) cnt[gbase + idx] = lh[idx];
    }
}

__global__ __launch_bounds__(256) void scan1(const int* __restrict__ counts_all,
                                             int* __restrict__ bsum) {
    int r = blockIdx.y, b = blockIdx.x, t = threadIdx.x;
    int base = b * 512;
    int lim = N_NODE - base; if (lim > 512) lim = 512;
    const int* c = counts_all + (size_t)r * N_NODE + base;
    int v0 = (2 * t     < lim) ? c[2 * t]     : 0;
    int v1 = (2 * t + 1 < lim) ? c[2 * t + 1] : 0;
    __shared__ int sm[256];
    sm[t] = v0 + v1;
    __syncthreads();
    for (int off = 128; off; off >>= 1) {
        if (t < off) sm[t] += sm[t + off];
        __syncthreads();
    }
    if (t == 0) bsum[r * NBSC + b] = sm[0];
}

__global__ __launch_bounds__(256) void scan3(const int* __restrict__ counts_all,
                                             int* __restrict__ rowptr_all,
                                             const int* __restrict__ bsum) {
    int r = blockIdx.y, b = blockIdx.x, t = threadIdx.x;
    __shared__ int sm[256];
    sm[t] = (t < b) ? bsum[r * NBSC + t] : 0;
    __syncthreads();
    for (int off = 128; off; off >>= 1) {
        if (t < off) sm[t] += sm[t + off];
        __syncthreads();
    }
    int boff = sm[0];
    __syncthreads();

    int base = b * 512;
    int lim = N_NODE - base; if (lim > 512) lim = 512;
    const int* c = counts_all + (size_t)r * N_NODE;
    int* rp = rowptr_all + (size_t)r * (N_NODE + 1);
    int i0 = base + 2 * t, i1 = i0 + 1;
    int v0 = (2 * t     < lim) ? c[i0] : 0;
    int v1 = (2 * t + 1 < lim) ? c[i1] : 0;
    int ps = v0 + v1;
    sm[t] = ps;
    __syncthreads();
    for (int off = 1; off < 256; off <<= 1) {
        int x = (t >= off) ? sm[t - off] : 0;
        __syncthreads();
        sm[t] += x;
        __syncthreads();
    }
    int excl = sm[t] - ps + boff;
    if (2 * t < lim)     rp[i0] = excl;
    if (2 * t + 1 < lim) rp[i1] = excl + v0;
    if (b == 0 && t == 0) rp[N_NODE] = NEDGE;
}

__global__ __launch_bounds__(256) void bucket_scatter(const uint32* __restrict__ bucketed,
                                                      const int* __restrict__ bkbase,
                                                      const int* __restrict__ rowptr_all,
                                                      int* __restrict__ srcs_all) {
    int r = blockIdx.y, k = blockIdx.x, t = threadIdx.x;
    int s0 = bkbase[r * (NB + 1) + k], s1 = bkbase[r * (NB + 1) + k + 1];
    int gbase = k << 10;
    const int* rp = rowptr_all + (size_t)r * (N_NODE + 1);
    __shared__ int cur[1024];
#pragma unroll
    for (int i = 0; i < 4; ++i) {
        int idx = t + i * 256;
        cur[idx] = (gbase + idx < N_NODE) ? rp[gbase + idx] : 0;
    }
    __syncthreads();
    const uint32* bk = bucketed + (size_t)r * NEDGE;
    int* out = srcs_all + (size_t)r * NEDGE;
    for (int i = s0 + t; i < s1; i += 256) {
        uint32 e = bk[i];
        int pos = atomicAdd(&cur[e >> 16], 1);       // LDS atomic
        out[pos] = (int)(e & 0xFFFFu);               // write confined to bucket's CSR range
    }
}

// ========== MFMA GEMM: C[M x BN](bf16) = A[M x 128] @ WT^T, fused epilogues ==========
template <int BN, bool RELU, bool DOT, bool ABF16>
__global__ __launch_bounds__(256) void gemm_mfma(const void* __restrict__ A0,
                                                 const void* __restrict__ A1,
                                                 const void* __restrict__ A2,
                                                 const ushort16* __restrict__ WTbase, // [r][BN][128] bf16
                                                 const float* __restrict__ avec_base,
                                                 ushort16* __restrict__ Cbase,
                                                 float* __restrict__ al_base,
                                                 const float* __restrict__ wdvec,
                                                 float* __restrict__ adst_base, int M) {
    constexpr int K = 128;
    __shared__ ushort16 aslds[64 * K];     // 16 KB
    __shared__ ushort16 bslds[BN * K];     // 32/16 KB
    const int r = blockIdx.y;
    const void* Av = (r == 0) ? A0 : (r == 1) ? A1 : A2;
    const int t    = threadIdx.x;
    const int lane = t & 63;
    const int w    = t >> 6;
    const int m0   = blockIdx.x * 64;

    // ---- stage B^T (bf16 global, coalesced 16B) with XOR swizzle ----
    {
        const uint4* src = reinterpret_cast<const uint4*>(WTbase + (size_t)r * BN * K);
        char* bb = reinterpret_cast<char*>(bslds);
#pragma unroll
        for (int i = t; i < BN * 16; i += 256) {
            int n = i >> 4, c16 = i & 15;
            uint32 off = (uint32)(n * 256 + c16 * 16) ^ (uint32)((n & 7) << 4);
            *reinterpret_cast<uint4*>(bb + off) = src[i];
        }
    }
    // ---- stage A tile (swizzled) ----
    char* ab = reinterpret_cast<char*>(aslds);
    if (ABF16) {
        const uint2* A2v = reinterpret_cast<const uint2*>(Av);
#pragma unroll
        for (int i = 0; i < 8; ++i) {
            int idx = t + i * 256;
            int row = idx >> 5, kq = idx & 31;
            uint2 p = make_uint2(0u, 0u);
            if (m0 + row < M) {
                p = A2v[(size_t)(m0 + row) * 32 + kq];
                if (RELU) { p.x = relu_bf2(p.x); p.y = relu_bf2(p.y); }
            }
            uint32 off = (uint32)(row * 256 + kq * 8) ^ (uint32)((row & 7) << 4);
            *reinterpret_cast<uint2*>(ab + off) = p;
        }
    } else {
        const float4* A4 = reinterpret_cast<const float4*>(Av);
        const int mr = (r == 0) ? 1 : (r == 1) ? 0 : 2;
        const float* wdot = wdvec + mr * K;
        float dp[8];
#pragma unroll
        for (int i = 0; i < 8; ++i) dp[i] = 0.f;
#pragma unroll
        for (int i = 0; i < 8; ++i) {
            int idx = t + i * 256;
            int row = idx >> 5, kq = idx & 31;
            float4 v = make_float4(0.f, 0.f, 0.f, 0.f);
            if (m0 + row < M) {
                v = A4[(size_t)(m0 + row) * 32 + kq];
                if (RELU) {
                    v.x = fmaxf(v.x, 0.f); v.y = fmaxf(v.y, 0.f);
                    v.z = fmaxf(v.z, 0.f); v.w = fmaxf(v.w, 0.f);
                }
            }
            if (DOT) {
                float4 wv = *reinterpret_cast<const float4*>(&wdot[kq * 4]);
                dp[i] = fmaf(v.x, wv.x, dp[i]); dp[i] = fmaf(v.y, wv.y, dp[i]);
                dp[i] = fmaf(v.z, wv.z, dp[i]); dp[i] = fmaf(v.w, wv.w, dp[i]);
            }
            uint2 p;
            p.x = bf16r(v.x) | (bf16r(v.y) << 16);
            p.y = bf16r(v.z) | (bf16r(v.w) << 16);
            uint32 off = (uint32)(row * 256 + kq * 8) ^ (uint32)((row & 7) << 4);
            *reinterpret_cast<uint2*>(ab + off) = p;
        }
        if (DOT) {
            float* adst = adst_base + (size_t)mr * M;
#pragma unroll
            for (int i = 0; i < 8; ++i) {
                float p = dp[i];
                p += __shfl_xor(p, 16); p += __shfl_xor(p, 8); p += __shfl_xor(p, 4);
                p += __shfl_xor(p, 2);  p += __shfl_xor(p, 1);
                int row = (t + i * 256) >> 5;
                if ((t & 31) == 0 && m0 + row < M) adst[m0 + row] = p;
            }
        }
    }
    __syncthreads();

    // ---- MFMA main ----
    const int col0 = lane & 15;
    const int kgrp = lane >> 4;
    const int arow = w * 16 + col0;
    bf16x8 afrag[4];
#pragma unroll
    for (int ks = 0; ks < 4; ++ks) {
        uint32 off = (uint32)(arow * 256 + ks * 64 + kgrp * 16) ^ (uint32)((arow & 7) << 4);
        afrag[ks] = *reinterpret_cast<const bf16x8*>(ab + off);
    }
    constexpr int NT = BN / 16;
    f32x4 acc[NT];
#pragma unroll
    for (int n = 0; n < NT; ++n) acc[n] = (f32x4){0.f, 0.f, 0.f, 0.f};
    const char* bb = reinterpret_cast<const char*>(bslds);
#pragma unroll
    for (int n = 0; n < NT; ++n) {
        int bcol = n * 16 + col0;
        uint32 xw = (uint32)((bcol & 7) << 4);
#pragma unroll
        for (int ks = 0; ks < 4; ++ks) {
            uint32 off = (uint32)(bcol * 256 + ks * 64 + kgrp * 16) ^ xw;
            bf16x8 bfrag = *reinterpret_cast<const bf16x8*>(bb + off);
            acc[n] = __builtin_amdgcn_mfma_f32_16x16x32_bf16(afrag[ks], bfrag, acc[n], 0, 0, 0);
        }
    }

    // ---- epilogue: bf16 C-store + fused al_src ----
    ushort16* C = Cbase + (size_t)r * M * BN;
    const float* av = avec_base + r * BN;
    const int rbase = m0 + w * 16 + kgrp * 4;
    float p4[4] = {0.f, 0.f, 0.f, 0.f};
#pragma unroll
    for (int n = 0; n < NT; ++n) {
        float asv = av[n * 16 + col0];
#pragma unroll
        for (int reg = 0; reg < 4; ++reg) {
            int rr = rbase + reg;
            if (rr < M) C[(size_t)rr * BN + n * 16 + col0] = (ushort16)bf16r(acc[n][reg]);
            p4[reg] = fmaf(acc[n][reg], asv, p4[reg]);
        }
    }
    float* al = al_base + (size_t)r * M;
#pragma unroll
    for (int reg = 0; reg < 4; ++reg) {
        float q = p4[reg];
        q += __shfl_xor(q, 1); q += __shfl_xor(q, 2);
        q += __shfl_xor(q, 4); q += __shfl_xor(q, 8);
        int rr = rbase + reg;
        if (col0 == 0 && rr < M) al[rr] = q;
    }
}

// ------- paired-edge single-pass softmax-aggregate, 8 edges / 4 gathers in flight -------
__device__ __forceinline__ float4 seg128p(const int* __restrict__ rp, const int* __restrict__ ss,
                                          const float* __restrict__ als,
                                          const uint2* __restrict__ hv2,
                                          float ad, int d, int half, int col) {
    int s = rp[d], e = rp[d + 1];
    float den = 0.f;
    float4 ac = make_float4(0.f, 0.f, 0.f, 0.f);
    int i = s;
    for (; i + 8 <= e; i += 8) {         // 8 edges, 4 independent gathers in flight
        int sA = ss[i + half];
        int sB = ss[i + 2 + half];
        int sC = ss[i + 4 + half];
        int sD = ss[i + 6 + half];
        float lA = als[sA], lB = als[sB], lC = als[sC], lD = als[sD];
        uint2 uA = hv2[(uint32)sA * 32u + col];
        uint2 uB = hv2[(uint32)sB * 32u + col];
        uint2 uC = hv2[(uint32)sC * 32u + col];
        uint2 uD = hv2[(uint32)sD * 32u + col];
        float eA = __expf(leakyf(lA + ad));
        float eB = __expf(leakyf(lB + ad));
        float eC = __expf(leakyf(lC + ad));
        float eD = __expf(leakyf(lD + ad));
        den += (eA + eB) + (eC + eD);
        ac.x = fmaf(eA, bf_lo(uA.x), ac.x); ac.y = fmaf(eA, bf_hi(uA.x), ac.y);
        ac.z = fmaf(eA, bf_lo(uA.y), ac.z); ac.w = fmaf(eA, bf_hi(uA.y), ac.w);
        ac.x = fmaf(eB, bf_lo(uB.x), ac.x); ac.y = fmaf(eB, bf_hi(uB.x), ac.y);
        ac.z = fmaf(eB, bf_lo(uB.y), ac.z); ac.w = fmaf(eB, bf_hi(uB.y), ac.w);
        ac.x = fmaf(eC, bf_lo(uC.x), ac.x); ac.y = fmaf(eC, bf_hi(uC.x), ac.y);
        ac.z = fmaf(eC, bf_lo(uC.y), ac.z); ac.w = fmaf(eC, bf_hi(uC.y), ac.w);
        ac.x = fmaf(eD, bf_lo(uD.x), ac.x); ac.y = fmaf(eD, bf_hi(uD.x), ac.y);
        ac.z = fmaf(eD, bf_lo(uD.y), ac.z); ac.w = fmaf(eD, bf_hi(uD.y), ac.w);
    }
    for (; i + 2 <= e; i += 2) {
        int sA = ss[i + half];
        float lA = als[sA];
        uint2 uA = hv2[(uint32)sA * 32u + col];
        float eA = __expf(leakyf(lA + ad));
        den += eA;
        ac.x = fmaf(eA, bf_lo(uA.x), ac.x); ac.y = fmaf(eA, bf_hi(uA.x), ac.y);
        ac.z = fmaf(eA, bf_lo(uA.y), ac.z); ac.w = fmaf(eA, bf_hi(uA.y), ac.w);
    }
    if (i < e && half == 0) {            // odd tail: half 0 only
        int sA = ss[i];
        float lA = als[sA];
        uint2 uA = hv2[(uint32)sA * 32u + col];
        float eA = __expf(leakyf(lA + ad));
        den += eA;
        ac.x = fmaf(eA, bf_lo(uA.x), ac.x); ac.y = fmaf(eA, bf_hi(uA.x), ac.y);
        ac.z = fmaf(eA, bf_lo(uA.y), ac.z); ac.w = fmaf(eA, bf_hi(uA.y), ac.w);
    }
    den  += __shfl_xor(den, 32);
    ac.x += __shfl_xor(ac.x, 32); ac.y += __shfl_xor(ac.y, 32);
    ac.z += __shfl_xor(ac.z, 32); ac.w += __shfl_xor(ac.w, 32);
    float rden = 1.0f / (den + 1e-16f);
    return make_float4(ac.x * rden, ac.y * rden, ac.z * rden, ac.w * rden);
}

__device__ __forceinline__ float2 seg64p(const int* __restrict__ rp, const int* __restrict__ ss,
                                         const float* __restrict__ als,
                                         const uint32* __restrict__ hv,
                                         float ad, int d, int half, int col) {
    int s = rp[d], e = rp[d + 1];
    float den = 0.f, ax = 0.f, ay = 0.f;
    int i = s;
    for (; i + 8 <= e; i += 8) {         // 8 edges, 4 independent gathers in flight
        int sA = ss[i + half];
        int sB = ss[i + 2 + half];
        int sC = ss[i + 4 + half];
        int sD = ss[i + 6 + half];
        float lA = als[sA], lB = als[sB], lC = als[sC], lD = als[sD];
        uint32 uA = hv[(uint32)sA * 32u + col];
        uint32 uB = hv[(uint32)sB * 32u + col];
        uint32 uC = hv[(uint32)sC * 32u + col];
        uint32 uD = hv[(uint32)sD * 32u + col];
        float eA = __expf(leakyf(lA + ad));
        float eB = __expf(leakyf(lB + ad));
        float eC = __expf(leakyf(lC + ad));
        float eD = __expf(leakyf(lD + ad));
        den += (eA + eB) + (eC + eD);
        ax = fmaf(eA, bf_lo(uA), ax); ay = fmaf(eA, bf_hi(uA), ay);
        ax = fmaf(eB, bf_lo(uB), ax); ay = fmaf(eB, bf_hi(uB), ay);
        ax = fmaf(eC, bf_lo(uC), ax); ay = fmaf(eC, bf_hi(uC), ay);
        ax = fmaf(eD, bf_lo(uD), ax); ay = fmaf(eD, bf_hi(uD), ay);
    }
    for (; i + 2 <= e; i += 2) {
        int sA = ss[i + half];
        float lA = als[sA];
        uint32 uA = hv[(uint32)sA * 32u + col];
        float eA = __expf(leakyf(lA + ad));
        den += eA;
        ax = fmaf(eA, bf_lo(uA), ax); ay = fmaf(eA, bf_hi(uA), ay);
    }
    if (i < e && half == 0) {
        int sA = ss[i];
        float lA = als[sA];
        uint32 uA = hv[(uint32)sA * 32u + col];
        float eA = __expf(leakyf(lA + ad));
        den += eA;
        ax = fmaf(eA, bf_lo(uA), ax); ay = fmaf(eA, bf_hi(uA), ay);
    }
    den += __shfl_xor(den, 32);
    ax  += __shfl_xor(ax, 32);
    ay  += __shfl_xor(ay, 32);
    float rden = 1.0f / (den + 1e-16f);
    return make_float2(ax * rden, ay * rden);
}

// ---------------- layer-1 agg + fused layer-2 al_dst; grid (12500, 2), 4 indep waves ----------------
__global__ __launch_bounds__(256) void agg1_sp(const int* __restrict__ rowptr_all,
                                               const int* __restrict__ srcs_all,
                                               const float* __restrict__ alsrc_all,
                                               float* __restrict__ aldst_all,
                                               const ushort16* __restrict__ hs_all,
                                               const float* __restrict__ b1,
                                               const float* __restrict__ wd2,
                                               ushort16* __restrict__ h_item,
                                               ushort16* __restrict__ h_user) {
    const int lane = threadIdx.x & 63;
    const int d = blockIdx.x * 4 + (threadIdx.x >> 6);
    if (d >= N_NODE) return;
    const int half = lane >> 5, col = lane & 31;
    const uint2* hv2 = reinterpret_cast<const uint2*>(hs_all);
    if (blockIdx.y == 0) {           // item dst: relation 0
        float4 w = seg128p(rowptr_all, srcs_all, alsrc_all, hv2, aldst_all[d], d, half, col);
        float4 b = ((const float4*)b1)[col];
        float4 h = make_float4(w.x + b.x, w.y + b.y, w.z + b.z, w.w + b.w);
        if (half == 0) {
            uint2 p;
            p.x = bf16r(h.x) | (bf16r(h.y) << 16);
            p.y = bf16r(h.z) | (bf16r(h.w) << 16);
            ((uint2*)h_item)[(size_t)d * 32 + col] = p;
        }
        float4 v0 = ((const float4*)wd2)[col];
        float p = fmaxf(h.x, 0.f) * v0.x + fmaxf(h.y, 0.f) * v0.y
                + fmaxf(h.z, 0.f) * v0.z + fmaxf(h.w, 0.f) * v0.w;
        p += __shfl_xor(p, 16); p += __shfl_xor(p, 8);
        p += __shfl_xor(p, 4);  p += __shfl_xor(p, 2); p += __shfl_xor(p, 1);
        if (lane == 0) aldst_all[d] = p;
    } else {                         // user dst: relations 1 + 2 in one wave
        float4 w1 = seg128p(rowptr_all + (N_NODE + 1), srcs_all + NEDGE,
                            alsrc_all + N_NODE, hv2 + (size_t)N_NODE * 32,
                            aldst_all[N_NODE + d], d, half, col);
        float4 w2 = seg128p(rowptr_all + 2 * (N_NODE + 1), srcs_all + (size_t)2 * NEDGE,
                            alsrc_all + 2 * N_NODE, hv2 + (size_t)2 * N_NODE * 32,
                            aldst_all[2 * N_NODE + d], d, half, col);
        float4 bA = ((const float4*)(b1 + HIDD))[col];
        float4 bB = ((const float4*)(b1 + 2 * HIDD))[col];
        float4 h = make_float4(w1.x + w2.x + bA.x + bB.x, w1.y + w2.y + bA.y + bB.y,
                               w1.z + w2.z + bA.z + bB.z, w1.w + w2.w + bA.w + bB.w);
        if (half == 0) {
            uint2 p;
            p.x = bf16r(h.x) | (bf16r(h.y) << 16);
            p.y = bf16r(h.z) | (bf16r(h.w) << 16);
            ((uint2*)h_user)[(size_t)d * 32 + col] = p;
        }
        float hx = fmaxf(h.x, 0.f), hy = fmaxf(h.y, 0.f);
        float hz = fmaxf(h.z, 0.f), hw = fmaxf(h.w, 0.f);
        float4 v1 = ((const float4*)(wd2 + HIDD))[col];
        float4 v2 = ((const float4*)(wd2 + 2 * HIDD))[col];
        float p1 = hx * v1.x + hy * v1.y + hz * v1.z + hw * v1.w;
        float p2 = hx * v2.x + hy * v2.y + hz * v2.z + hw * v2.w;
        p1 += __shfl_xor(p1, 16); p1 += __shfl_xor(p1, 8);
        p1 += __shfl_xor(p1, 4);  p1 += __shfl_xor(p1, 2); p1 += __shfl_xor(p1, 1);
        p2 += __shfl_xor(p2, 16); p2 += __shfl_xor(p2, 8);
        p2 += __shfl_xor(p2, 4);  p2 += __shfl_xor(p2, 2); p2 += __shfl_xor(p2, 1);
        if (lane == 0) {
            aldst_all[N_NODE + d]     = p1;
            aldst_all[2 * N_NODE + d] = p2;
        }
    }
}

// ---------------- layer-2 agg (C=64), paired edges; o in bf16 ----------------
__global__ __launch_bounds__(256) void agg2_sp(const int* __restrict__ rowptr_all,
                                               const int* __restrict__ srcs_all,
                                               const float* __restrict__ alsrc_all,
                                               const float* __restrict__ aldst_all,
                                               const ushort16* __restrict__ hs_all,
                                               const float* __restrict__ b2,
                                               ushort16* __restrict__ o_item,
                                               ushort16* __restrict__ o_user) {
    const int lane = threadIdx.x & 63;
    const int d = blockIdx.x * 4 + (threadIdx.x >> 6);
    if (d >= N_NODE) return;
    const int half = lane >> 5, col = lane & 31;
    const uint32* hv = reinterpret_cast<const uint32*>(hs_all);
    if (blockIdx.y == 0) {
        float2 w = seg64p(rowptr_all, srcs_all, alsrc_all, hv, aldst_all[d], d, half, col);
        float2 b = ((const float2*)b2)[col];
        if (half == 0)
            ((uint32*)o_item)[(size_t)d * 32 + col] =
                bf16r(w.x + b.x) | (bf16r(w.y + b.y) << 16);
    } else {
        float2 w1 = seg64p(rowptr_all + (N_NODE + 1), srcs_all + NEDGE,
                           alsrc_all + N_NODE, hv + (size_t)N_NODE * 32,
                           aldst_all[N_NODE + d], d, half, col);
        float2 w2 = seg64p(rowptr_all + 2 * (N_NODE + 1), srcs_all + (size_t)2 * NEDGE,
                           alsrc_all + 2 * N_NODE, hv + (size_t)2 * N_NODE * 32,
                           aldst_all[2 * N_NODE + d], d, half, col);
        float2 bA = ((const float2*)(b2 + OUTD))[col];
        float2 bB = ((const float2*)(b2 + 2 * OUTD))[col];
        if (half == 0)
            ((uint32*)o_user)[(size_t)d * 32 + col] =
                bf16r(w1.x + w2.x + bA.x + bB.x) | (bf16r(w1.y + w2.y + bA.y + bB.y) << 16);
    }
}

// ---------------- bilinear edge scoring (o tables bf16) ----------------
__global__ void score_k(const int* __restrict__ e0, const int* __restrict__ e1,
                        const int* __restrict__ e2,
                        const ushort16* __restrict__ o_user, const ushort16* __restrict__ o_item,
                        const float* __restrict__ relw, float* __restrict__ out, int L) {
    int g    = blockIdx.x * 4 + (threadIdx.x >> 6);
    int lane = threadIdx.x & 63;
    int r = g / L, l = g - r * L;
    if (r >= 3) return;
    const int* ei = (r == 0) ? e0 : (r == 1) ? e1 : e2;
    int ai = ei[l];
    int bi = ei[L + l];
    const ushort16* A = (r == 1) ? o_item : o_user;
    const ushort16* B = (r == 0) ? o_item : o_user;
    float av = __uint_as_float(((uint32)A[(size_t)ai * OUTD + lane]) << 16);
    float bv = __uint_as_float(((uint32)B[(size_t)bi * OUTD + lane]) << 16);
    float v = av * relw[r * OUTD + lane] * bv;
#pragma unroll
    for (int off = 32; off; off >>= 1) v += __shfl_xor(v, off);
    if (lane == 0) out[r * L + l] = v;
}

extern "C" void kernel_launch(void* const* d_in, const int* in_sizes, int n_in,
                              void* d_out, int out_size, void* d_ws, size_t ws_size,
                              hipStream_t stream) {
    const float* x_user = (const float*)d_in[0];
    const float* x_item = (const float*)d_in[1];
    const float* W1s = (const float*)d_in[2];
    const float* W1d = (const float*)d_in[3];
    const float* a1s = (const float*)d_in[4];
    const float* a1d = (const float*)d_in[5];
    const float* b1  = (const float*)d_in[6];
    const float* W2s = (const float*)d_in[7];
    const float* W2d = (const float*)d_in[8];
    const float* a2s = (const float*)d_in[9];
    const float* a2d = (const float*)d_in[10];
    const float* b2  = (const float*)d_in[11];
    const float* relw= (const float*)d_in[12];
    const int* ei0 = (const int*)d_in[13];
    const int* ei1 = (const int*)d_in[14];
    const int* ei2 = (const int*)d_in[15];
    const int* el0 = (const int*)d_in[16];
    const int* el1 = (const int*)d_in[17];
    const int* el2 = (const int*)d_in[18];
    float* out = (float*)d_out;
    (void)ws_size; (void)n_in; (void)in_sizes; (void)out_size;

    char* ws = (char*)d_ws;
    size_t off = 0;
    auto alloc = [&](size_t bytes) -> void* {
        void* p = ws + off;
        off = (off + bytes + 255) & ~(size_t)255;
        return p;
    };
    int*     rowptr_all = (int*)alloc((size_t)3 * (N_NODE + 1) * 4);
    int*     counts_all = (int*)alloc((size_t)3 * N_NODE * 4);
    int*     srcs_all   = (int*)alloc((size_t)3 * NEDGE * 4);
    int*     bsum       = (int*)alloc((size_t)3 * NBSC * 4);
    int*     bh         = (int*)alloc((size_t)3 * NB * NBP1 * 4);
    int*     bkbase     = (int*)alloc((size_t)3 * (NB + 1) * 4);
    uint32*  bucketed   = (uint32*)alloc((size_t)3 * NEDGE * 4);            // packed src|dlocal
    ushort16* hs_bf     = (ushort16*)alloc((size_t)3 * N_NODE * HIDD * 2);  // bf16
    ushort16* WT1       = (ushort16*)alloc((size_t)3 * HIDD * FDIM * 2);    // [r][n][k] bf16
    ushort16* WT2       = (ushort16*)alloc((size_t)3 * OUTD * HIDD * 2);
    ushort16* h_item1   = (ushort16*)alloc((size_t)2 * N_NODE * HIDD * 2);  // bf16
    ushort16* h_user1   = h_item1 + (size_t)N_NODE * HIDD;
    ushort16* o_item    = (ushort16*)alloc((size_t)N_NODE * OUTD * 2);      // bf16
    ushort16* o_user    = (ushort16*)alloc((size_t)N_NODE * OUTD * 2);
    float*   alsrc_all  = (float*)alloc((size_t)3 * N_NODE * 4);
    float*   aldst_all  = (float*)alloc((size_t)3 * N_NODE * 4);
    float*   wd1        = (float*)alloc(3 * FDIM * 4);
    float*   wd2        = (float*)alloc(3 * HIDD * 4);

    fold_wd<<<3, 128, 0, stream>>>(W1d, a1d, W2d, a2d, wd1, wd2);
    wt_k<<<dim3(192, 2), 256, 0, stream>>>(W1s, W2s, WT1, WT2);

    // ---- CSR build: two-level bucket partition ----
    part_hist<<<dim3(NBP1, 3), 256, 0, stream>>>(ei0, ei1, ei2, bh);
    part_scan<<<3, 256, 0, stream>>>(bh, bkbase);
    part_scatter<<<dim3(NBP1, 3), 256, 0, stream>>>(ei0, ei1, ei2, bh, bucketed);
    bucket_count<<<dim3(NB, 3), 256, 0, stream>>>(bucketed, bkbase, counts_all);
    scan1<<<dim3(NBSC, 3), 256, 0, stream>>>(counts_all, bsum);
    scan3<<<dim3(NBSC, 3), 256, 0, stream>>>(counts_all, rowptr_all, bsum);
    bucket_scatter<<<dim3(NB, 3), 256, 0, stream>>>(bucketed, bkbase, rowptr_all, srcs_all);

    const int ag = (N_NODE + 3) / 4;
    const int gg = (N_NODE + 63) / 64;

    // ---- layer 1 (MFMA gemm; fused al_src + layer-1 al_dst DOT; A = fp32 inputs) ----
    gemm_mfma<128, false, true, false><<<dim3(gg, 3), 256, 0, stream>>>(
        x_user, x_item, x_user, WT1, a1s, hs_bf, alsrc_all, wd1, aldst_all, N_NODE);
    // agg1 also writes layer-2 al_dst into aldst_all in-place (per-block read-then-write)
    agg1_sp<<<dim3(ag, 2), 256, 0, stream>>>(rowptr_all, srcs_all, alsrc_all, aldst_all,
                                             hs_bf, b1, wd2, h_item1, h_user1);

    // ---- layer 2 (MFMA gemm; A = bf16 h, ReLU in staging; hs_bf overwrite safe) ----
    gemm_mfma<64, true, false, true><<<dim3(gg, 3), 256, 0, stream>>>(
        h_user1, h_item1, h_user1, WT2, a2s, hs_bf, alsrc_all, wd2, aldst_all, N_NODE);
    agg2_sp<<<dim3(ag, 2), 256, 0, stream>>>(rowptr_all, srcs_all, alsrc_all, aldst_all,
                                             hs_bf, b2, o_item, o_user);

    // ---- scoring ----
    score_k<<<(3 * NL + 3) / 4, 256, 0, stream>>>(el0, el1, el2, o_user, o_item, relw, out, NL);
}

// Round 16
// 318.313 us; speedup vs baseline: 1.5263x; 1.0082x over previous
//
#include <hip/hip_runtime.h>
#include <cstdint>
#include <cstddef>

#define N_NODE 50000
#define NEDGE  500000
#define NL     100000
#define FDIM   128
#define HIDD   128
#define OUTD   64
#define NB     49        // buckets = ceil(50000 / 1024), bucket = dst >> 10
#define BCH    8192      // edges per partition block
#define NBP1   62        // ceil(NEDGE / BCH)

typedef unsigned int uint32;
typedef unsigned short ushort16;
typedef __attribute__((ext_vector_type(8))) short bf16x8;
typedef __attribute__((ext_vector_type(4))) float f32x4;

static_assert(N_NODE < 65536, "src packs into 16 bits");

__device__ __forceinline__ float leakyf(float x) { return x > 0.f ? x : 0.2f * x; }

// round-to-nearest-even f32 -> bf16
__device__ __forceinline__ uint32 bf16r(float x) {
    uint32 u = __float_as_uint(x);
    return (u + 0x7fffu + ((u >> 16) & 1u)) >> 16;
}
__device__ __forceinline__ float bf_lo(uint32 u) { return __uint_as_float(u << 16); }
__device__ __forceinline__ float bf_hi(uint32 u) { return __uint_as_float(u & 0xffff0000u); }
// ReLU on 2 packed bf16 (exact: relu(bf16(x)) == bf16(relu(x)))
__device__ __forceinline__ uint32 relu_bf2(uint32 u) {
    uint32 lo = u & 0xFFFFu, hi = u >> 16;
    lo = (lo & 0x8000u) ? 0u : lo;
    hi = (hi & 0x8000u) ? 0u : hi;
    return lo | (hi << 16);
}

// ---- prep: WT bf16 transposes (y=0,1) + fold Wd@a_d vectors (y=2) ----
__global__ void prep_k(const float* __restrict__ W1s, const float* __restrict__ W2s,
                       const float* __restrict__ W1d, const float* __restrict__ a1d,
                       const float* __restrict__ W2d, const float* __restrict__ a2d,
                       ushort16* __restrict__ WT1, ushort16* __restrict__ WT2,
                       float* __restrict__ wd1, float* __restrict__ wd2) {
    int idx = blockIdx.x * 256 + threadIdx.x;
    if (blockIdx.y == 0) {
        if (idx < 3 * FDIM * HIDD) {
            int k = idx & 127, n = (idx >> 7) & 127, r = idx >> 14;
            WT1[idx] = (ushort16)bf16r(W1s[((size_t)r * FDIM + k) * HIDD + n]);
        }
    } else if (blockIdx.y == 1) {
        if (idx < 3 * HIDD * OUTD) {
            int k = idx & 127, n = (idx >> 7) & 63, r = idx >> 13;
            WT2[idx] = (ushort16)bf16r(W2s[((size_t)r * HIDD + k) * OUTD + n]);
        }
    } else {
        if (idx < 3 * FDIM) {
            int r = idx >> 7, f = idx & 127;
            const float* w  = W1d + ((size_t)r * FDIM + f) * HIDD;
            const float* a  = a1d + r * HIDD;
            float s = 0.f;
            for (int h = 0; h < HIDD; ++h) s += w[h] * a[h];
            wd1[r * FDIM + f] = s;
            const float* w2 = W2d + ((size_t)r * HIDD + f) * OUTD;
            const float* a2 = a2d + r * OUTD;
            float s2 = 0.f;
            for (int o = 0; o < OUTD; ++o) s2 += w2[o] * a2[o];
            wd2[r * HIDD + f] = s2;
        }
    }
}

// ================= CSR build: two-level bucket partition (write-locality) =================

__global__ __launch_bounds__(256) void part_hist(const int* __restrict__ e0,
                                                 const int* __restrict__ e1,
                                                 const int* __restrict__ e2,
                                                 int* __restrict__ bh) {
    int r = blockIdx.y, t = threadIdx.x;
    const int* ei  = (r == 0) ? e0 : (r == 1) ? e1 : e2;
    const int* dst = ei + NEDGE;
    __shared__ int lh[NB];
    if (t < NB) lh[t] = 0;
    __syncthreads();
    int base = blockIdx.x * BCH;
    int lim  = base + BCH; if (lim > NEDGE) lim = NEDGE;
    for (int i = base + t; i < lim; i += 256)
        atomicAdd(&lh[dst[i] >> 10], 1);
    __syncthreads();
    if (t < NB) bh[((size_t)r * NB + t) * NBP1 + blockIdx.x] = lh[t];
}

__global__ __launch_bounds__(256) void part_scan(int* __restrict__ bh,
                                                 int* __restrict__ bkbase) {
    int r = blockIdx.x, t = threadIdx.x;
    int* a = bh + (size_t)r * NB * NBP1;
    const int n = NB * NBP1;                 // 3038
    const int per = (n + 255) / 256;         // 12
    int lo = t * per, hi = lo + per; if (hi > n) hi = n;
    int s = 0;
    for (int i = lo; i < hi; ++i) s += a[i];
    __shared__ int sm[256];
    sm[t] = s;
    __syncthreads();
    for (int off = 1; off < 256; off <<= 1) {
        int x = (t >= off) ? sm[t - off] : 0;
        __syncthreads();
        sm[t] += x;
        __syncthreads();
    }
    int run = sm[t] - s;
    for (int i = lo; i < hi; ++i) { int c = a[i]; a[i] = run; run += c; }
    __syncthreads();
    if (t < NB) bkbase[r * (NB + 1) + t] = a[t * NBP1];
    if (t == NB) bkbase[r * (NB + 1) + NB] = NEDGE;
}

__global__ __launch_bounds__(256) void part_scatter(const int* __restrict__ e0,
                                                    const int* __restrict__ e1,
                                                    const int* __restrict__ e2,
                                                    const int* __restrict__ bh,
                                                    uint32* __restrict__ bucketed) {
    int r = blockIdx.y, t = threadIdx.x;
    const int* ei  = (r == 0) ? e0 : (r == 1) ? e1 : e2;
    const int* dst = ei + NEDGE;
    __shared__ int cur[NB];
    if (t < NB) cur[t] = bh[((size_t)r * NB + t) * NBP1 + blockIdx.x];
    __syncthreads();
    uint32* bk = bucketed + (size_t)r * NEDGE;
    int base = blockIdx.x * BCH;
    int lim  = base + BCH; if (lim > NEDGE) lim = NEDGE;
    for (int i = base + t; i < lim; i += 256) {
        int d = dst[i], s_ = ei[i];
        int pos = atomicAdd(&cur[d >> 10], 1);      // LDS atomic, global position
        bk[pos] = (uint32)s_ | ((uint32)(d & 1023) << 16);
    }
}

// per-bucket histogram + LOCAL scan -> rowptr directly (CSR order == (bucket, dst, arrival),
// so rowptr[d] = bkbase[bucket] + prefix-within-bucket). Replaces count+2 global scans.
__global__ __launch_bounds__(256) void bucket_rowptr(const uint32* __restrict__ bucketed,
                                                     const int* __restrict__ bkbase,
                                                     int* __restrict__ rowptr_all) {
    int r = blockIdx.y, k = blockIdx.x, t = threadIdx.x;
    int s0 = bkbase[r * (NB + 1) + k], s1 = bkbase[r * (NB + 1) + k + 1];
    __shared__ int lh[1024];
#pragma unroll
    for (int i = 0; i < 4; ++i) lh[t + i * 256] = 0;
    __syncthreads();
    const uint32* bk = bucketed + (size_t)r * NEDGE;
    for (int i = s0 + t; i < s1; i += 256)
        atomicAdd(&lh[bk[i] >> 16], 1);
    __syncthreads();
    // exclusive scan over the 1024 counts (4 consecutive per thread)
    int b4 = t * 4;
    int c0 = lh[b4], c1 = lh[b4 + 1], c2 = lh[b4 + 2], c3 = lh[b4 + 3];
    int s = c0 + c1 + c2 + c3;
    __shared__ int sm[256];
    sm[t] = s;
    __syncthreads();
    for (int off = 1; off < 256; off <<= 1) {
        int x = (t >= off) ? sm[t - off] : 0;
        __syncthreads();
        sm[t] += x;
        __syncthreads();
    }
    int run = s0 + sm[t] - s;
    int gbase = k << 10;
    int* rp = rowptr_all + (size_t)r * (N_NODE + 1);
    if (gbase + b4 < N_NODE)     rp[gbase + b4]     = run;
    if (gbase + b4 + 1 < N_NODE) rp[gbase + b4 + 1] = run + c0;
    if (gbase + b4 + 2 < N_NODE) rp[gbase + b4 + 2] = run + c0 + c1;
    if (gbase + b4 + 3 < N_NODE) rp[gbase + b4 + 3] = run + c0 + c1 + c2;
    if (k == NB - 1 && t == 255) rp[N_NODE] = NEDGE;
}

__global__ __launch_bounds__(256) void bucket_scatter(const uint32* __restrict__ bucketed,
                                                      const int* __restrict__ bkbase,
                                                      const int* __restrict__ rowptr_all,
                                                      int* __restrict__ srcs_all) {
    int r = blockIdx.y, k = blockIdx.x, t = threadIdx.x;
    int s0 = bkbase[r * (NB + 1) + k], s1 = bkbase[r * (NB + 1) + k + 1];
    int gbase = k << 10;
    const int* rp = rowptr_all + (size_t)r * (N_NODE + 1);
    __shared__ int cur[1024];
#pragma unroll
    for (int i = 0; i < 4; ++i) {
        int idx = t + i * 256;
        cur[idx] = (gbase + idx < N_NODE) ? rp[gbase + idx] : 0;
    }
    __syncthreads();
    const uint32* bk = bucketed + (size_t)r * NEDGE;
    int* out = srcs_all + (size_t)r * NEDGE;
    for (int i = s0 + t; i < s1; i += 256) {
        uint32 e = bk[i];
        int pos = atomicAdd(&cur[e >> 16], 1);       // LDS atomic
        out[pos] = (int)(e & 0xFFFFu);               // write confined to bucket's CSR range
    }
}

// ========== MFMA GEMM: C[M x BN](bf16) = A[M x 128] @ WT^T, fused epilogues ==========
template <int BN, bool RELU, bool DOT, bool ABF16>
__global__ __launch_bounds__(256) void gemm_mfma(const void* __restrict__ A0,
                                                 const void* __restrict__ A1,
                                                 const void* __restrict__ A2,
                                                 const ushort16* __restrict__ WTbase, // [r][BN][128] bf16
                                                 const float* __restrict__ avec_base,
                                                 ushort16* __restrict__ Cbase,
                                                 float* __restrict__ al_base,
                                                 const float* __restrict__ wdvec,
                                                 float* __restrict__ adst_base, int M) {
    constexpr int K = 128;
    __shared__ ushort16 aslds[64 * K];     // 16 KB
    __shared__ ushort16 bslds[BN * K];     // 32/16 KB
    const int r = blockIdx.y;
    const void* Av = (r == 0) ? A0 : (r == 1) ? A1 : A2;
    const int t    = threadIdx.x;
    const int lane = t & 63;
    const int w    = t >> 6;
    const int m0   = blockIdx.x * 64;

    // ---- stage B^T (bf16 global, coalesced 16B) with XOR swizzle ----
    {
        const uint4* src = reinterpret_cast<const uint4*>(WTbase + (size_t)r * BN * K);
        char* bb = reinterpret_cast<char*>(bslds);
#pragma unroll
        for (int i = t; i < BN * 16; i += 256) {
            int n = i >> 4, c16 = i & 15;
            uint32 off = (uint32)(n * 256 + c16 * 16) ^ (uint32)((n & 7) << 4);
            *reinterpret_cast<uint4*>(bb + off) = src[i];
        }
    }
    // ---- stage A tile (swizzled) ----
    char* ab = reinterpret_cast<char*>(aslds);
    if (ABF16) {
        const uint2* A2v = reinterpret_cast<const uint2*>(Av);
#pragma unroll
        for (int i = 0; i < 8; ++i) {
            int idx = t + i * 256;
            int row = idx >> 5, kq = idx & 31;
            uint2 p = make_uint2(0u, 0u);
            if (m0 + row < M) {
                p = A2v[(size_t)(m0 + row) * 32 + kq];
                if (RELU) { p.x = relu_bf2(p.x); p.y = relu_bf2(p.y); }
            }
            uint32 off = (uint32)(row * 256 + kq * 8) ^ (uint32)((row & 7) << 4);
            *reinterpret_cast<uint2*>(ab + off) = p;
        }
    } else {
        const float4* A4 = reinterpret_cast<const float4*>(Av);
        const int mr = (r == 0) ? 1 : (r == 1) ? 0 : 2;
        const float* wdot = wdvec + mr * K;
        float dp[8];
#pragma unroll
        for (int i = 0; i < 8; ++i) dp[i] = 0.f;
#pragma unroll
        for (int i = 0; i < 8; ++i) {
            int idx = t + i * 256;
            int row = idx >> 5, kq = idx & 31;
            float4 v = make_float4(0.f, 0.f, 0.f, 0.f);
            if (m0 + row < M) {
                v = A4[(size_t)(m0 + row) * 32 + kq];
                if (RELU) {
                    v.x = fmaxf(v.x, 0.f); v.y = fmaxf(v.y, 0.f);
                    v.z = fmaxf(v.z, 0.f); v.w = fmaxf(v.w, 0.f);
                }
            }
            if (DOT) {
                float4 wv = *reinterpret_cast<const float4*>(&wdot[kq * 4]);
                dp[i] = fmaf(v.x, wv.x, dp[i]); dp[i] = fmaf(v.y, wv.y, dp[i]);
                dp[i] = fmaf(v.z, wv.z, dp[i]); dp[i] = fmaf(v.w, wv.w, dp[i]);
            }
            uint2 p;
            p.x = bf16r(v.x) | (bf16r(v.y) << 16);
            p.y = bf16r(v.z) | (bf16r(v.w) << 16);
            uint32 off = (uint32)(row * 256 + kq * 8) ^ (uint32)((row & 7) << 4);
            *reinterpret_cast<uint2*>(ab + off) = p;
        }
        if (DOT) {
            float* adst = adst_base + (size_t)mr * M;
#pragma unroll
            for (int i = 0; i < 8; ++i) {
                float p = dp[i];
                p += __shfl_xor(p, 16); p += __shfl_xor(p, 8); p += __shfl_xor(p, 4);
                p += __shfl_xor(p, 2);  p += __shfl_xor(p, 1);
                int row = (t + i * 256) >> 5;
                if ((t & 31) == 0 && m0 + row < M) adst[m0 + row] = p;
            }
        }
    }
    __syncthreads();

    // ---- MFMA main ----
    const int col0 = lane & 15;
    const int kgrp = lane >> 4;
    const int arow = w * 16 + col0;
    bf16x8 afrag[4];
#pragma unroll
    for (int ks = 0; ks < 4; ++ks) {
        uint32 off = (uint32)(arow * 256 + ks * 64 + kgrp * 16) ^ (uint32)((arow & 7) << 4);
        afrag[ks] = *reinterpret_cast<const bf16x8*>(ab + off);
    }
    constexpr int NT = BN / 16;
    f32x4 acc[NT];
#pragma unroll
    for (int n = 0; n < NT; ++n) acc[n] = (f32x4){0.f, 0.f, 0.f, 0.f};
    const char* bb = reinterpret_cast<const char*>(bslds);
#pragma unroll
    for (int n = 0; n < NT; ++n) {
        int bcol = n * 16 + col0;
        uint32 xw = (uint32)((bcol & 7) << 4);
#pragma unroll
        for (int ks = 0; ks < 4; ++ks) {
            uint32 off = (uint32)(bcol * 256 + ks * 64 + kgrp * 16) ^ xw;
            bf16x8 bfrag = *reinterpret_cast<const bf16x8*>(bb + off);
            acc[n] = __builtin_amdgcn_mfma_f32_16x16x32_bf16(afrag[ks], bfrag, acc[n], 0, 0, 0);
        }
    }

    // ---- epilogue: bf16 C-store + fused al_src ----
    ushort16* C = Cbase + (size_t)r * M * BN;
    const float* av = avec_base + r * BN;
    const int rbase = m0 + w * 16 + kgrp * 4;
    float p4[4] = {0.f, 0.f, 0.f, 0.f};
#pragma unroll
    for (int n = 0; n < NT; ++n) {
        float asv = av[n * 16 + col0];
#pragma unroll
        for (int reg = 0; reg < 4; ++reg) {
            int rr = rbase + reg;
            if (rr < M) C[(size_t)rr * BN + n * 16 + col0] = (ushort16)bf16r(acc[n][reg]);
            p4[reg] = fmaf(acc[n][reg], asv, p4[reg]);
        }
    }
    float* al = al_base + (size_t)r * M;
#pragma unroll
    for (int reg = 0; reg < 4; ++reg) {
        float q = p4[reg];
        q += __shfl_xor(q, 1); q += __shfl_xor(q, 2);
        q += __shfl_xor(q, 4); q += __shfl_xor(q, 8);
        int rr = rbase + reg;
        if (col0 == 0 && rr < M) al[rr] = q;
    }
}

// ------- paired-edge single-pass softmax-aggregate, 8 edges / 4 gathers in flight -------
__device__ __forceinline__ float4 seg128p(const int* __restrict__ rp, const int* __restrict__ ss,
                                          const float* __restrict__ als,
                                          const uint2* __restrict__ hv2,
                                          float ad, int d, int half, int col) {
    int s = rp[d], e = rp[d + 1];
    float den = 0.f;
    float4 ac = make_float4(0.f, 0.f, 0.f, 0.f);
    int i = s;
    for (; i + 8 <= e; i += 8) {
        int sA = ss[i + half];
        int sB = ss[i + 2 + half];
        int sC = ss[i + 4 + half];
        int sD = ss[i + 6 + half];
        float lA = als[sA], lB = als[sB], lC = als[sC], lD = als[sD];
        uint2 uA = hv2[(uint32)sA * 32u + col];
        uint2 uB = hv2[(uint32)sB * 32u + col];
        uint2 uC = hv2[(uint32)sC * 32u + col];
        uint2 uD = hv2[(uint32)sD * 32u + col];
        float eA = __expf(leakyf(lA + ad));
        float eB = __expf(leakyf(lB + ad));
        float eC = __expf(leakyf(lC + ad));
        float eD = __expf(leakyf(lD + ad));
        den += (eA + eB) + (eC + eD);
        ac.x = fmaf(eA, bf_lo(uA.x), ac.x); ac.y = fmaf(eA, bf_hi(uA.x), ac.y);
        ac.z = fmaf(eA, bf_lo(uA.y), ac.z); ac.w = fmaf(eA, bf_hi(uA.y), ac.w);
        ac.x = fmaf(eB, bf_lo(uB.x), ac.x); ac.y = fmaf(eB, bf_hi(uB.x), ac.y);
        ac.z = fmaf(eB, bf_lo(uB.y), ac.z); ac.w = fmaf(eB, bf_hi(uB.y), ac.w);
        ac.x = fmaf(eC, bf_lo(uC.x), ac.x); ac.y = fmaf(eC, bf_hi(uC.x), ac.y);
        ac.z = fmaf(eC, bf_lo(uC.y), ac.z); ac.w = fmaf(eC, bf_hi(uC.y), ac.w);
        ac.x = fmaf(eD, bf_lo(uD.x), ac.x); ac.y = fmaf(eD, bf_hi(uD.x), ac.y);
        ac.z = fmaf(eD, bf_lo(uD.y), ac.z); ac.w = fmaf(eD, bf_hi(uD.y), ac.w);
    }
    for (; i + 2 <= e; i += 2) {
        int sA = ss[i + half];
        float lA = als[sA];
        uint2 uA = hv2[(uint32)sA * 32u + col];
        float eA = __expf(leakyf(lA + ad));
        den += eA;
        ac.x = fmaf(eA, bf_lo(uA.x), ac.x); ac.y = fmaf(eA, bf_hi(uA.x), ac.y);
        ac.z = fmaf(eA, bf_lo(uA.y), ac.z); ac.w = fmaf(eA, bf_hi(uA.y), ac.w);
    }
    if (i < e && half == 0) {
        int sA = ss[i];
        float lA = als[sA];
        uint2 uA = hv2[(uint32)sA * 32u + col];
        float eA = __expf(leakyf(lA + ad));
        den += eA;
        ac.x = fmaf(eA, bf_lo(uA.x), ac.x); ac.y = fmaf(eA, bf_hi(uA.x), ac.y);
        ac.z = fmaf(eA, bf_lo(uA.y), ac.z); ac.w = fmaf(eA, bf_hi(uA.y), ac.w);
    }
    den  += __shfl_xor(den, 32);
    ac.x += __shfl_xor(ac.x, 32); ac.y += __shfl_xor(ac.y, 32);
    ac.z += __shfl_xor(ac.z, 32); ac.w += __shfl_xor(ac.w, 32);
    float rden = 1.0f / (den + 1e-16f);
    return make_float4(ac.x * rden, ac.y * rden, ac.z * rden, ac.w * rden);
}

__device__ __forceinline__ float2 seg64p(const int* __restrict__ rp, const int* __restrict__ ss,
                                         const float* __restrict__ als,
                                         const uint32* __restrict__ hv,
                                         float ad, int d, int half, int col) {
    int s = rp[d], e = rp[d + 1];
    float den = 0.f, ax = 0.f, ay = 0.f;
    int i = s;
    for (; i + 8 <= e; i += 8) {
        int sA = ss[i + half];
        int sB = ss[i + 2 + half];
        int sC = ss[i + 4 + half];
        int sD = ss[i + 6 + half];
        float lA = als[sA], lB = als[sB], lC = als[sC], lD = als[sD];
        uint32 uA = hv[(uint32)sA * 32u + col];
        uint32 uB = hv[(uint32)sB * 32u + col];
        uint32 uC = hv[(uint32)sC * 32u + col];
        uint32 uD = hv[(uint32)sD * 32u + col];
        float eA = __expf(leakyf(lA + ad));
        float eB = __expf(leakyf(lB + ad));
        float eC = __expf(leakyf(lC + ad));
        float eD = __expf(leakyf(lD + ad));
        den += (eA + eB) + (eC + eD);
        ax = fmaf(eA, bf_lo(uA), ax); ay = fmaf(eA, bf_hi(uA), ay);
        ax = fmaf(eB, bf_lo(uB), ax); ay = fmaf(eB, bf_hi(uB), ay);
        ax = fmaf(eC, bf_lo(uC), ax); ay = fmaf(eC, bf_hi(uC), ay);
        ax = fmaf(eD, bf_lo(uD), ax); ay = fmaf(eD, bf_hi(uD), ay);
    }
    for (; i + 2 <= e; i += 2) {
        int sA = ss[i + half];
        float lA = als[sA];
        uint32 uA = hv[(uint32)sA * 32u + col];
        float eA = __expf(leakyf(lA + ad));
        den += eA;
        ax = fmaf(eA, bf_lo(uA), ax); ay = fmaf(eA, bf_hi(uA), ay);
    }
    if (i < e && half == 0) {
        int sA = ss[i];
        float lA = als[sA];
        uint32 uA = hv[(uint32)sA * 32u + col];
        float eA = __expf(leakyf(lA + ad));
        den += eA;
        ax = fmaf(eA, bf_lo(uA), ax); ay = fmaf(eA, bf_hi(uA), ay);
    }
    den += __shfl_xor(den, 32);
    ax  += __shfl_xor(ax, 32);
    ay  += __shfl_xor(ay, 32);
    float rden = 1.0f / (den + 1e-16f);
    return make_float2(ax * rden, ay * rden);
}

// ---------------- layer-1 agg + fused layer-2 al_dst; grid (12500, 2), 4 indep waves ----------------
__global__ __launch_bounds__(256) void agg1_sp(const int* __restrict__ rowptr_all,
                                               const int* __restrict__ srcs_all,
                                               const float* __restrict__ alsrc_all,
                                               float* __restrict__ aldst_all,
                                               const ushort16* __restrict__ hs_all,
                                               const float* __restrict__ b1,
                                               const float* __restrict__ wd2,
                                               ushort16* __restrict__ h_item,
                                               ushort16* __restrict__ h_user) {
    const int lane = threadIdx.x & 63;
    const int d = blockIdx.x * 4 + (threadIdx.x >> 6);
    if (d >= N_NODE) return;
    const int half = lane >> 5, col = lane & 31;
    const uint2* hv2 = reinterpret_cast<const uint2*>(hs_all);
    if (blockIdx.y == 0) {           // item dst: relation 0
        float4 w = seg128p(rowptr_all, srcs_all, alsrc_all, hv2, aldst_all[d], d, half, col);
        float4 b = ((const float4*)b1)[col];
        float4 h = make_float4(w.x + b.x, w.y + b.y, w.z + b.z, w.w + b.w);
        if (half == 0) {
            uint2 p;
            p.x = bf16r(h.x) | (bf16r(h.y) << 16);
            p.y = bf16r(h.z) | (bf16r(h.w) << 16);
            ((uint2*)h_item)[(size_t)d * 32 + col] = p;
        }
        float4 v0 = ((const float4*)wd2)[col];
        float p = fmaxf(h.x, 0.f) * v0.x + fmaxf(h.y, 0.f) * v0.y
                + fmaxf(h.z, 0.f) * v0.z + fmaxf(h.w, 0.f) * v0.w;
        p += __shfl_xor(p, 16); p += __shfl_xor(p, 8);
        p += __shfl_xor(p, 4);  p += __shfl_xor(p, 2); p += __shfl_xor(p, 1);
        if (lane == 0) aldst_all[d] = p;
    } else {                         // user dst: relations 1 + 2 in one wave
        float4 w1 = seg128p(rowptr_all + (N_NODE + 1), srcs_all + NEDGE,
                            alsrc_all + N_NODE, hv2 + (size_t)N_NODE * 32,
                            aldst_all[N_NODE + d], d, half, col);
        float4 w2 = seg128p(rowptr_all + 2 * (N_NODE + 1), srcs_all + (size_t)2 * NEDGE,
                            alsrc_all + 2 * N_NODE, hv2 + (size_t)2 * N_NODE * 32,
                            aldst_all[2 * N_NODE + d], d, half, col);
        float4 bA = ((const float4*)(b1 + HIDD))[col];
        float4 bB = ((const float4*)(b1 + 2 * HIDD))[col];
        float4 h = make_float4(w1.x + w2.x + bA.x + bB.x, w1.y + w2.y + bA.y + bB.y,
                               w1.z + w2.z + bA.z + bB.z, w1.w + w2.w + bA.w + bB.w);
        if (half == 0) {
            uint2 p;
            p.x = bf16r(h.x) | (bf16r(h.y) << 16);
            p.y = bf16r(h.z) | (bf16r(h.w) << 16);
            ((uint2*)h_user)[(size_t)d * 32 + col] = p;
        }
        float hx = fmaxf(h.x, 0.f), hy = fmaxf(h.y, 0.f);
        float hz = fmaxf(h.z, 0.f), hw = fmaxf(h.w, 0.f);
        float4 v1 = ((const float4*)(wd2 + HIDD))[col];
        float4 v2 = ((const float4*)(wd2 + 2 * HIDD))[col];
        float p1 = hx * v1.x + hy * v1.y + hz * v1.z + hw * v1.w;
        float p2 = hx * v2.x + hy * v2.y + hz * v2.z + hw * v2.w;
        p1 += __shfl_xor(p1, 16); p1 += __shfl_xor(p1, 8);
        p1 += __shfl_xor(p1, 4);  p1 += __shfl_xor(p1, 2); p1 += __shfl_xor(p1, 1);
        p2 += __shfl_xor(p2, 16); p2 += __shfl_xor(p2, 8);
        p2 += __shfl_xor(p2, 4);  p2 += __shfl_xor(p2, 2); p2 += __shfl_xor(p2, 1);
        if (lane == 0) {
            aldst_all[N_NODE + d]     = p1;
            aldst_all[2 * N_NODE + d] = p2;
        }
    }
}

// ---------------- layer-2 agg (C=64), paired edges; o in bf16 ----------------
__global__ __launch_bounds__(256) void agg2_sp(const int* __restrict__ rowptr_all,
                                               const int* __restrict__ srcs_all,
                                               const float* __restrict__ alsrc_all,
                                               const float* __restrict__ aldst_all,
                                               const ushort16* __restrict__ hs_all,
                                               const float* __restrict__ b2,
                                               ushort16* __restrict__ o_item,
                                               ushort16* __restrict__ o_user) {
    const int lane = threadIdx.x & 63;
    const int d = blockIdx.x * 4 + (threadIdx.x >> 6);
    if (d >= N_NODE) return;
    const int half = lane >> 5, col = lane & 31;
    const uint32* hv = reinterpret_cast<const uint32*>(hs_all);
    if (blockIdx.y == 0) {
        float2 w = seg64p(rowptr_all, srcs_all, alsrc_all, hv, aldst_all[d], d, half, col);
        float2 b = ((const float2*)b2)[col];
        if (half == 0)
            ((uint32*)o_item)[(size_t)d * 32 + col] =
                bf16r(w.x + b.x) | (bf16r(w.y + b.y) << 16);
    } else {
        float2 w1 = seg64p(rowptr_all + (N_NODE + 1), srcs_all + NEDGE,
                           alsrc_all + N_NODE, hv + (size_t)N_NODE * 32,
                           aldst_all[N_NODE + d], d, half, col);
        float2 w2 = seg64p(rowptr_all + 2 * (N_NODE + 1), srcs_all + (size_t)2 * NEDGE,
                           alsrc_all + 2 * N_NODE, hv + (size_t)2 * N_NODE * 32,
                           aldst_all[2 * N_NODE + d], d, half, col);
        float2 bA = ((const float2*)(b2 + OUTD))[col];
        float2 bB = ((const float2*)(b2 + 2 * OUTD))[col];
        if (half == 0)
            ((uint32*)o_user)[(size_t)d * 32 + col] =
                bf16r(w1.x + w2.x + bA.x + bB.x) | (bf16r(w1.y + w2.y + bA.y + bB.y) << 16);
    }
}

// ---------------- bilinear edge scoring (o tables bf16) ----------------
__global__ void score_k(const int* __restrict__ e0, const int* __restrict__ e1,
                        const int* __restrict__ e2,
                        const ushort16* __restrict__ o_user, const ushort16* __restrict__ o_item,
                        const float* __restrict__ relw, float* __restrict__ out, int L) {
    int g    = blockIdx.x * 4 + (threadIdx.x >> 6);
    int lane = threadIdx.x & 63;
    int r = g / L, l = g - r * L;
    if (r >= 3) return;
    const int* ei = (r == 0) ? e0 : (r == 1) ? e1 : e2;
    int ai = ei[l];
    int bi = ei[L + l];
    const ushort16* A = (r == 1) ? o_item : o_user;
    const ushort16* B = (r == 0) ? o_item : o_user;
    float av = __uint_as_float(((uint32)A[(size_t)ai * OUTD + lane]) << 16);
    float bv = __uint_as_float(((uint32)B[(size_t)bi * OUTD + lane]) << 16);
    float v = av * relw[r * OUTD + lane] * bv;
#pragma unroll
    for (int off = 32; off; off >>= 1) v += __shfl_xor(v, off);
    if (lane == 0) out[r * L + l] = v;
}

extern "C" void kernel_launch(void* const* d_in, const int* in_sizes, int n_in,
                              void* d_out, int out_size, void* d_ws, size_t ws_size,
                              hipStream_t stream) {
    const float* x_user = (const float*)d_in[0];
    const float* x_item = (const float*)d_in[1];
    const float* W1s = (const float*)d_in[2];
    const float* W1d = (const float*)d_in[3];
    const float* a1s = (const float*)d_in[4];
    const float* a1d = (const float*)d_in[5];
    const float* b1  = (const float*)d_in[6];
    const float* W2s = (const float*)d_in[7];
    const float* W2d = (const float*)d_in[8];
    const float* a2s = (const float*)d_in[9];
    const float* a2d = (const float*)d_in[10];
    const float* b2  = (const float*)d_in[11];
    const float* relw= (const float*)d_in[12];
    const int* ei0 = (const int*)d_in[13];
    const int* ei1 = (const int*)d_in[14];
    const int* ei2 = (const int*)d_in[15];
    const int* el0 = (const int*)d_in[16];
    const int* el1 = (const int*)d_in[17];
    const int* el2 = (const int*)d_in[18];
    float* out = (float*)d_out;
    (void)ws_size; (void)n_in; (void)in_sizes; (void)out_size;

    char* ws = (char*)d_ws;
    size_t off = 0;
    auto alloc = [&](size_t bytes) -> void* {
        void* p = ws + off;
        off = (off + bytes + 255) & ~(size_t)255;
        return p;
    };
    int*     rowptr_all = (int*)alloc((size_t)3 * (N_NODE + 1) * 4);
    int*     srcs_all   = (int*)alloc((size_t)3 * NEDGE * 4);
    int*     bh         = (int*)alloc((size_t)3 * NB * NBP1 * 4);
    int*     bkbase     = (int*)alloc((size_t)3 * (NB + 1) * 4);
    uint32*  bucketed   = (uint32*)alloc((size_t)3 * NEDGE * 4);            // packed src|dlocal
    ushort16* hs_bf     = (ushort16*)alloc((size_t)3 * N_NODE * HIDD * 2);  // bf16
    ushort16* WT1       = (ushort16*)alloc((size_t)3 * HIDD * FDIM * 2);    // [r][n][k] bf16
    ushort16* WT2       = (ushort16*)alloc((size_t)3 * OUTD * HIDD * 2);
    ushort16* h_item1   = (ushort16*)alloc((size_t)2 * N_NODE * HIDD * 2);  // bf16
    ushort16* h_user1   = h_item1 + (size_t)N_NODE * HIDD;
    ushort16* o_item    = (ushort16*)alloc((size_t)N_NODE * OUTD * 2);      // bf16
    ushort16* o_user    = (ushort16*)alloc((size_t)N_NODE * OUTD * 2);
    float*   alsrc_all  = (float*)alloc((size_t)3 * N_NODE * 4);
    float*   aldst_all  = (float*)alloc((size_t)3 * N_NODE * 4);
    float*   wd1        = (float*)alloc(3 * FDIM * 4);
    float*   wd2        = (float*)alloc(3 * HIDD * 4);

    prep_k<<<dim3(192, 3), 256, 0, stream>>>(W1s, W2s, W1d, a1d, W2d, a2d,
                                             WT1, WT2, wd1, wd2);

    // ---- CSR build: two-level bucket partition (rowptr via per-bucket local scan) ----
    part_hist<<<dim3(NBP1, 3), 256, 0, stream>>>(ei0, ei1, ei2, bh);
    part_scan<<<3, 256, 0, stream>>>(bh, bkbase);
    part_scatter<<<dim3(NBP1, 3), 256, 0, stream>>>(ei0, ei1, ei2, bh, bucketed);
    bucket_rowptr<<<dim3(NB, 3), 256, 0, stream>>>(bucketed, bkbase, rowptr_all);
    bucket_scatter<<<dim3(NB, 3), 256, 0, stream>>>(bucketed, bkbase, rowptr_all, srcs_all);

    const int ag = (N_NODE + 3) / 4;
    const int gg = (N_NODE + 63) / 64;

    // ---- layer 1 (MFMA gemm; fused al_src + layer-1 al_dst DOT; A = fp32 inputs) ----
    gemm_mfma<128, false, true, false><<<dim3(gg, 3), 256, 0, stream>>>(
        x_user, x_item, x_user, WT1, a1s, hs_bf, alsrc_all, wd1, aldst_all, N_NODE);
    // agg1 also writes layer-2 al_dst into aldst_all in-place (per-block read-then-write)
    agg1_sp<<<dim3(ag, 2), 256, 0, stream>>>(rowptr_all, srcs_all, alsrc_all, aldst_all,
                                             hs_bf, b1, wd2, h_item1, h_user1);

    // ---- layer 2 (MFMA gemm; A = bf16 h, ReLU in staging; hs_bf overwrite safe) ----
    gemm_mfma<64, true, false, true><<<dim3(gg, 3), 256, 0, stream>>>(
        h_user1, h_item1, h_user1, WT2, a2s, hs_bf, alsrc_all, wd2, aldst_all, N_NODE);
    agg2_sp<<<dim3(ag, 2), 256, 0, stream>>>(rowptr_all, srcs_all, alsrc_all, aldst_all,
                                             hs_bf, b2, o_item, o_user);

    // ---- scoring ----
    score_k<<<(3 * NL + 3) / 4, 256, 0, stream>>>(el0, el1, el2, o_user, o_item, relw, out, NL);
}